// Round 15
// baseline (4240.917 us; speedup 1.0000x reference)
//
#include <hip/hip_runtime.h>
#include <hip/hip_bf16.h>

#define BB 8
#define NN 4096
#define KNN 20
#define NPTS (BB*NN)          // 32768
#define NEDGE (NPTS*KNN)      // 655360
#define TKCAP 12
#define LKN 12                // per-lane screen top-K (recall: Binom(19,1/16) >= 12 is ~2e-10)
#define SKN 24                // per-wave merged top-K (>= 19 possible better + slack)
#define FKN 48                // final screened candidates per query (rescored exactly)

typedef unsigned short u16;
typedef unsigned long long u64;
typedef __attribute__((ext_vector_type(8))) short s8v;   // 8 bf16 (4 VGPRs)
typedef __attribute__((ext_vector_type(4))) float f4v;

__device__ __forceinline__ float bf2f(u16 u) {
    return __uint_as_float(((unsigned)u) << 16);
}
__device__ __forceinline__ u16 f2bf_rne(float f) {
  unsigned u = __float_as_uint(f);
  unsigned rb = (u >> 16) & 1;
  u += 0x7FFFu + rb;
  return (u16)(u >> 16);
}
__device__ __forceinline__ float lrelu(float v) { return v > 0.f ? v : 0.2f * v; }
__device__ __forceinline__ double lrelu64(double v) { return v > 0.0 ? v : 0.2 * v; }

// ---- sortable (value,index) packed key (f64): descending value, ties -> lower index ----
__device__ __forceinline__ u64 dkey(double v, int j) {
  u64 u = (u64)__double_as_longlong(v);
  u = (u >> 63) ? ~u : (u | 0x8000000000000000ull);
  return (u & ~0xFFFull) | (u64)(4095 - j);
}

// ---- sortable (value,index) packed key (f32 screen): full f32 bits + 12-bit index ----
__device__ __forceinline__ u64 skey(float v, int j) {
  unsigned s = __float_as_uint(v);
  s = (s >> 31) ? ~s : (s | 0x80000000u);
  return ((u64)s << 12) | (u64)(4095 - j);
}

// ---- generic register top-N insertion (static indices after unroll) ----
template <int N>
__device__ __forceinline__ void tk_insert(u64* bk, u64 k) {
  if (k > bk[N - 1]) {
    bk[N - 1] = k;
#pragma unroll
    for (int p = N - 1; p > 0; --p) {
      if (bk[p] > bk[p - 1]) { u64 tv = bk[p]; bk[p] = bk[p - 1]; bk[p - 1] = tv; }
    }
  }
}

// ---- top-20 insertion on packed u64 keys (macro form used by knn1p/tmerge) ----
#define TOPK_INIT() \
  u64 bk[KNN]; \
  _Pragma("unroll") for (int p_ = 0; p_ < KNN; ++p_) bk[p_] = 0ull;

#define TOPK_INSERT(kk) do { \
    u64 k_ = (kk); \
    if (k_ > bk[KNN-1]) { \
      bk[KNN-1] = k_; \
      _Pragma("unroll") \
      for (int p_ = KNN-1; p_ > 0; --p_) { \
        if (bk[p_] > bk[p_-1]) { u64 tv_ = bk[p_]; bk[p_] = bk[p_-1]; bk[p_-1] = tv_; } \
      } \
    } \
  } while (0)

#define TKBUF_DECL() \
  u64 thr_ = 0ull; u64 cb_[TKCAP]; int cnt_ = 0;
#define TKBUF_PUSH(kk) do { \
    u64 k__ = (kk); \
    if (k__ > thr_) { cb_[cnt_] = k__; ++cnt_; } \
  } while (0)
#define TKBUF_FLUSH() do { \
    for (int l_ = 0; l_ < cnt_; ++l_) TOPK_INSERT(cb_[l_]); \
    cnt_ = 0; thr_ = bk[KNN-1]; \
  } while (0)

// =================== dtype detect + canonicalize to f32 ===================
__global__ void det_k(const void* __restrict__ g1raw, int* __restrict__ flag) {
  const u16* u = (const u16*)g1raw;
  flag[0] = (u[0] == 0x3F80) ? 1 : 0;
}

__global__ __launch_bounds__(256) void conv_k(const void* __restrict__ src,
                                              float* __restrict__ dst, int n,
                                              const int* __restrict__ flag) {
  const int mode = flag[0];
  int i = blockIdx.x * 256 + threadIdx.x;
  const int stride = gridDim.x * 256;
  if (mode) {
    const u16* s = (const u16*)src;
    for (; i < n; i += stride) dst[i] = bf2f(s[i]);
  } else {
    const float* s = (const float*)src;
    for (; i < n; i += stride) dst[i] = s[i];
  }
}

__global__ void zero_k(double* __restrict__ p, int n) {
  int i = blockIdx.x * 256 + threadIdx.x;
  if (i < n) p[i] = 0.0;
}

// =========== knn on raw 3-D points — j-split partials, packed u64 keys ===========
__global__ __launch_bounds__(256) void knn1p_k(const float* __restrict__ x,
                                               u64* __restrict__ pkey) {
  __shared__ float sx[1024], sy[1024], sz[1024];
  __shared__ double sq[1024];
  const int b = blockIdx.x, t = threadIdx.x, seg = blockIdx.z;
  const int j0 = seg * 1024;
  const float* xb = x + b * 3 * NN;
  const int i = blockIdx.y * 256 + t;
  const double px = (double)xb[i], py = (double)xb[NN + i], pz = (double)xb[2 * NN + i];
  const double q = px * px + py * py + pz * pz;
  for (int l = t; l < 1024; l += 256) {
    float jx = xb[j0 + l], jy = xb[NN + j0 + l], jz = xb[2 * NN + j0 + l];
    sx[l] = jx; sy[l] = jy; sz[l] = jz;
    double jxd = jx, jyd = jy, jzd = jz;
    sq[l] = jxd * jxd + jyd * jyd + jzd * jzd;
  }
  __syncthreads();
  TOPK_INIT();
  TKBUF_DECL();
  for (int j = 0; j < 1024; j += 4) {
    double i0 = px * (double)sx[j + 0] + py * (double)sy[j + 0] + pz * (double)sz[j + 0];
    double i1 = px * (double)sx[j + 1] + py * (double)sy[j + 1] + pz * (double)sz[j + 1];
    double i2 = px * (double)sx[j + 2] + py * (double)sy[j + 2] + pz * (double)sz[j + 2];
    double i3 = px * (double)sx[j + 3] + py * (double)sy[j + 3] + pz * (double)sz[j + 3];
    double v0 = (2.0 * i0 - q) - sq[j + 0];
    double v1 = (2.0 * i1 - q) - sq[j + 1];
    double v2 = (2.0 * i2 - q) - sq[j + 2];
    double v3 = (2.0 * i3 - q) - sq[j + 3];
    TKBUF_PUSH(dkey(v0, j0 + j + 0));
    TKBUF_PUSH(dkey(v1, j0 + j + 1));
    TKBUF_PUSH(dkey(v2, j0 + j + 2));
    TKBUF_PUSH(dkey(v3, j0 + j + 3));
    if (__ballot(cnt_ >= TKCAP - 3)) TKBUF_FLUSH();
  }
  TKBUF_FLUSH();
  const size_t base = ((size_t)seg * NPTS + (b * NN + i)) * KNN;
#pragma unroll
  for (int p = 0; p < KNN; ++p) pkey[base + p] = bk[p];
}

// =================== merge 4 partial top-20 key lists -> final indices ===================
__global__ __launch_bounds__(256) void tmerge_k(const u64* __restrict__ pkey,
                                                int* __restrict__ idx) {
  const int pt = blockIdx.x * 256 + threadIdx.x;
  TOPK_INIT();
  for (int seg = 0; seg < 4; ++seg) {
    const size_t base = ((size_t)seg * NPTS + pt) * KNN;
#pragma unroll
    for (int p = 0; p < KNN; ++p) TOPK_INSERT(pkey[base + p]);
  }
  int* op = idx + (size_t)pt * KNN;
#pragma unroll
  for (int p = 0; p < KNN; ++p) op[p] = 4095 - (int)(bk[p] & 0xFFFull);
}

// ==== split f32 features into bf16 hi + bf16 lo (screen operands) ====
__global__ __launch_bounds__(256) void xsplit_k(const float* __restrict__ xp,
                                                u16* __restrict__ Xhi,
                                                u16* __restrict__ Xlo) {
  int i = blockIdx.x * 256 + threadIdx.x;   // NPTS*64 elements
  float x = xp[i];
  u16 h = f2bf_rne(x);
  Xhi[i] = h;
  Xlo[i] = f2bf_rne(x - bf2f(h));
}

// ====== MFMA split-bf16 SCREEN knn v5: per-lane top-12 -> wave top-24 -> top-48 ======
// grid (NN/16, BB), 256 thr = 4 waves. Block = 16 queries x ALL 4096 j; wave w owns
// j in [w*1024, w*1024+1024). Lane l holds score(j=jloc+(l>>4)*4+r, q=i0+(l&15)) in reg.
// Per-lane top-12 suffices for recall: a true top-20 item has <=19 better globally ->
// in-lane count ~ Binom(19,1/16), P(>=12) ~ 2e-10. Wave merge to 24 (>=19+slack, exact).
// LDS: lbuf [8][256] u64 = 16KB (km overlays post-loop). resc_k restores exact f64.
__global__ __launch_bounds__(256) void knnsm_k(const u16* __restrict__ Xhi,
                                               const u16* __restrict__ Xlo,
                                               const float* __restrict__ xxf,
                                               u64* __restrict__ pcand) {
  __shared__ __align__(16) unsigned char smraw[16384];
  u64* lbuf = (u64*)smraw;                    // [8 slots][256 threads] = 16384 B
  u64* km   = (u64*)smraw;                    // [16][97] = 12416 B (post-loop overlay)
  const int t = threadIdx.x;
  const int w = t >> 6, l = t & 63;
  const int b = blockIdx.y;
  const int i0 = blockIdx.x * 16;
  const int gpt0 = b * NN;
  // B fragments (queries), held whole kernel: row = i0 + (l&15); k = kt*32 + (l>>4)*8 + e
  s8v Bhi[2], Blo[2];
#pragma unroll
  for (int kt = 0; kt < 2; ++kt) {
    size_t off = (size_t)(gpt0 + i0 + (l & 15)) * 64 + kt * 32 + ((l >> 4) * 8);
    Bhi[kt] = *(const s8v*)&Xhi[off];
    Blo[kt] = *(const s8v*)&Xlo[off];
  }
  const int q = l & 15, hi = l >> 4;
  const float qif = xxf[gpt0 + i0 + q];
  u64 bk[LKN];
#pragma unroll
  for (int p = 0; p < LKN; ++p) bk[p] = 0ull;
  u64 thr = 0ull; int cnt = 0;
  for (int jt = 0; jt < 64; ++jt) {
    const int jloc = w * 1024 + jt * 16;
    s8v Ahi_[2], Alo_[2];
#pragma unroll
    for (int kt = 0; kt < 2; ++kt) {
      size_t off = (size_t)(gpt0 + jloc + (l & 15)) * 64 + kt * 32 + (hi * 8);
      Ahi_[kt] = *(const s8v*)&Xhi[off];
      Alo_[kt] = *(const s8v*)&Xlo[off];
    }
    f4v acc = {0.f, 0.f, 0.f, 0.f};
#pragma unroll
    for (int kt = 0; kt < 2; ++kt) {
      acc = __builtin_amdgcn_mfma_f32_16x16x32_bf16(Ahi_[kt], Bhi[kt], acc, 0, 0, 0);
      acc = __builtin_amdgcn_mfma_f32_16x16x32_bf16(Ahi_[kt], Blo[kt], acc, 0, 0, 0);
      acc = __builtin_amdgcn_mfma_f32_16x16x32_bf16(Alo_[kt], Bhi[kt], acc, 0, 0, 0);
    }
    // lane's 4 candidates: j = jloc + hi*4 + r, all for its own query q
    float4 qj4 = *(const float4*)&xxf[gpt0 + jloc + hi * 4];   // L2-hot
    const float* qj = (const float*)&qj4;
#pragma unroll
    for (int r = 0; r < 4; ++r) {
      float v = (2.f * acc[r] - qif) - qj[r];
      u64 k0 = skey(v, jloc + hi * 4 + r);
      if (k0 > thr) { lbuf[cnt * 256 + t] = k0; ++cnt; }
    }
    if (__ballot(cnt >= 5)) {
      for (int lf = 0; lf < cnt; ++lf) tk_insert<LKN>(bk, lbuf[lf * 256 + t]);
      cnt = 0; thr = bk[LKN - 1];
    }
  }
  for (int lf = 0; lf < cnt; ++lf) tk_insert<LKN>(bk, lbuf[lf * 256 + t]);
  // expand lane top-12 into wave-merge list (capacity 24)
  u64 wk[SKN];
#pragma unroll
  for (int p = 0; p < LKN; ++p) wk[p] = bk[p];
#pragma unroll
  for (int p = LKN; p < SKN; ++p) wk[p] = 0ull;
  // merge hi-groups: lanes l, l+16, l+32, l+48 hold same query (disjoint j)
#pragma unroll
  for (int p = 0; p < SKN; ++p) {
    u64 o = __shfl_xor((unsigned long long)wk[p], 32);
    if (l < 32) tk_insert<SKN>(wk, o);
  }
#pragma unroll
  for (int p = 0; p < SKN; ++p) {
    u64 o = __shfl_xor((unsigned long long)wk[p], 16);
    if (l < 16) tk_insert<SKN>(wk, o);
  }
  __syncthreads();   // all lbuf reads done before km overlay writes
  if (l < 16) {
#pragma unroll
    for (int p = 0; p < SKN; ++p) km[l * 97 + w * SKN + p] = wk[p];
  }
  __syncthreads();
  // rank-select top-48 of 96 per query (keys unique: disjoint j slices; all 96 real:
  // each wave list merged 48 real candidates into 24)
  {
    const int qq = t & 15, g = t >> 4;   // 16 groups x 6 candidates
    const size_t pb = (size_t)(gpt0 + i0 + qq) * FKN;
    for (int cc = 0; cc < 6; ++cc) {
      u64 mine = km[qq * 97 + g * 6 + cc];
      int rank = 0;
      for (int o = 0; o < 96; ++o) rank += (km[qq * 97 + o] > mine) ? 1 : 0;
      if (rank < FKN) pcand[pb + rank] = mine;
    }
  }
}

// ============ exact f64 rescore of 48 screened candidates -> final top-20 idx ============
__global__ __launch_bounds__(256) void resc_k(const float* __restrict__ xp,
                                              const double* __restrict__ xx,
                                              const u64* __restrict__ pcand,
                                              int* __restrict__ idx) {
  __shared__ float xis[4][64];
  __shared__ u64 keys[4][FKN];
  const int t = threadIdx.x;
  const int w = t >> 6, lane = t & 63;
  const int pt = blockIdx.x * 4 + w;
  const int b12 = pt & ~(NN - 1);
  xis[w][lane] = xp[(size_t)pt * 64 + lane];
  const double q = xx[pt];
  if (lane < FKN) {
    u64 sk = pcand[(size_t)pt * FKN + lane];
    int j = 4095 - (int)(sk & 0xFFFull);
    const float* xj = xp + ((size_t)b12 + j) * 64;
    double a0 = 0.0, a1 = 0.0, a2 = 0.0, a3 = 0.0;
#pragma unroll
    for (int d = 0; d < 16; ++d) {
      a0 += (double)xis[w][d] * (double)xj[d];
      a1 += (double)xis[w][16 + d] * (double)xj[16 + d];
      a2 += (double)xis[w][32 + d] * (double)xj[32 + d];
      a3 += (double)xis[w][48 + d] * (double)xj[48 + d];
    }
    double v = (2.0 * ((a0 + a1) + (a2 + a3)) - q) - xx[b12 + j];
    keys[w][lane] = dkey(v, j);
  }
  if (lane < FKN) {
    u64 mine = keys[w][lane];
    int rank = 0;
    for (int o = 0; o < FKN; ++o) rank += (keys[w][o] > mine) ? 1 : 0;
    if (rank < KNN) idx[(size_t)pt * KNN + rank] = 4095 - (int)(mine & 0xFFFull);
  }
}

// =================== moments of the 6-D edge feature (tiled: 2048 edges/block) ==============
__global__ __launch_bounds__(256) void f1mom_k(const float* __restrict__ x,
                                               const int* __restrict__ idx,
                                               double* __restrict__ stm) {
  __shared__ float red[27][257];
  const int t = threadIdx.x;
  float a[27];
#pragma unroll
  for (int m = 0; m < 27; ++m) a[m] = 0.f;
  for (int r = 0; r < 8; ++r) {
    int e = blockIdx.x * 2048 + r * 256 + t;
    int pt = e / KNN;
    int b = pt >> 12, i = pt & (NN - 1);
    int j = idx[e] & (NN - 1);
    const float* xb = x + b * 3 * NN;
    float xi0 = xb[i], xi1 = xb[NN + i], xi2 = xb[2 * NN + i];
    float f[6];
    f[0] = xb[j] - xi0; f[1] = xb[NN + j] - xi1; f[2] = xb[2 * NN + j] - xi2;
    f[3] = xi0; f[4] = xi1; f[5] = xi2;
#pragma unroll
    for (int d = 0; d < 6; ++d) a[d] += f[d];
    int k = 6;
#pragma unroll
    for (int aa = 0; aa < 6; ++aa)
#pragma unroll
      for (int bb2 = aa; bb2 < 6; ++bb2) a[k++] += f[aa] * f[bb2];
  }
#pragma unroll
  for (int m = 0; m < 27; ++m) red[m][t] = a[m];
  __syncthreads();
  if (t < 27) {
    double s = 0.0;
    for (int l = 0; l < 256; ++l) s += (double)red[t][l];
    atomicAdd(&stm[t], s);
  }
}

__global__ void fin1_k(const double* __restrict__ stm, const float* __restrict__ W1,
                       const float* __restrict__ g, const float* __restrict__ bet,
                       float* __restrict__ sc, float* __restrict__ sh, double invM) {
  int c = threadIdx.x;
  if (c >= 64) return;
  double w[6];
  for (int d = 0; d < 6; ++d) w[d] = (double)W1[c * 6 + d];
  double mean = 0.0;
  for (int d = 0; d < 6; ++d) mean += w[d] * stm[d];
  mean *= invM;
  double e2 = 0.0;
  int k = 6;
  for (int a = 0; a < 6; ++a)
    for (int b = a; b < 6; ++b) {
      double m2 = stm[k++];
      e2 += w[a] * w[b] * m2 * (a == b ? 1.0 : 2.0);
    }
  e2 *= invM;
  double var = e2 - mean * mean;
  if (!(var > 0.0)) var = 0.0;
  double scale = (double)g[c] / sqrt(var + 1e-5);
  sc[c] = (float)scale;
  sh[c] = (float)((double)bet[c] - mean * scale);
}

__global__ void fin_k(const double* __restrict__ st, const float* __restrict__ g,
                      const float* __restrict__ bet, float* __restrict__ sc,
                      float* __restrict__ sh, int C, double invM) {
  int c = blockIdx.x * 256 + threadIdx.x;
  if (c >= C) return;
  double mean = st[c] * invM;
  double var = st[1024 + c] * invM - mean * mean;
  if (!(var > 0.0)) var = 0.0;
  double scale = (double)g[c] / sqrt(var + 1e-5);
  sc[c] = (float)scale;
  sh[c] = (float)((double)bet[c] - mean * scale);
}

// ===== stage-1: h2 stats as tile-GEMM (f6 -> h1 -> BN -> h2 col-stats), 16 tiles/block ======
__global__ __launch_bounds__(256) void e1b_k(const float* __restrict__ x, const int* __restrict__ idx,
    const float* __restrict__ W1, const float* __restrict__ sc1, const float* __restrict__ sh1,
    const float* __restrict__ W2, double* __restrict__ st) {
  __shared__ float f6[64][9];
  __shared__ float W1s[64][8];
  __shared__ float H1[64][68];
  __shared__ float W2s[64][68];
  __shared__ double rPd[16][68];
  const int t = threadIdx.x;
  const int tx = t & 15, ty = t >> 4;
  for (int l = t; l < 384; l += 256) W1s[l / 6][l % 6] = W1[l];
  for (int l = t; l < 4096; l += 256) W2s[l & 63][l >> 6] = W2[l];
  double sL[4], qL[4];
#pragma unroll
  for (int j = 0; j < 4; ++j) { sL[j] = 0.0; qL[j] = 0.0; }
  for (int tile = 0; tile < 16; ++tile) {
    const int e0 = (blockIdx.x * 16 + tile) * 64;
    __syncthreads();
    if (t < 64) {
      int e = e0 + t;
      int pt = e / KNN;
      int b = pt >> 12, i = pt & (NN - 1);
      int j = idx[e] & (NN - 1);
      const float* xb = x + b * 3 * NN;
      float xi0 = xb[i], xi1 = xb[NN + i], xi2 = xb[2 * NN + i];
      f6[t][0] = xb[j] - xi0; f6[t][1] = xb[NN + j] - xi1; f6[t][2] = xb[2 * NN + j] - xi2;
      f6[t][3] = xi0; f6[t][4] = xi1; f6[t][5] = xi2;
    }
    __syncthreads();
    float acc1[4][4];
#pragma unroll
    for (int i = 0; i < 4; ++i)
#pragma unroll
      for (int j = 0; j < 4; ++j) acc1[i][j] = 0.f;
#pragma unroll
    for (int d = 0; d < 6; ++d) {
      float av[4], bv2[4];
#pragma unroll
      for (int i = 0; i < 4; ++i) av[i] = f6[ty * 4 + i][d];
#pragma unroll
      for (int j = 0; j < 4; ++j) bv2[j] = W1s[tx * 4 + j][d];
#pragma unroll
      for (int i = 0; i < 4; ++i)
#pragma unroll
        for (int j = 0; j < 4; ++j) acc1[i][j] = fmaf(av[i], bv2[j], acc1[i][j]);
    }
#pragma unroll
    for (int j = 0; j < 4; ++j) {
      int c = tx * 4 + j;
      float s1 = sc1[c], b1 = sh1[c];
#pragma unroll
      for (int i = 0; i < 4; ++i)
        H1[c][ty * 4 + i] = lrelu(fmaf(s1, acc1[i][j], b1));
    }
    __syncthreads();
    float acc2[4][4];
#pragma unroll
    for (int i = 0; i < 4; ++i)
#pragma unroll
      for (int j = 0; j < 4; ++j) acc2[i][j] = 0.f;
    for (int k = 0; k < 64; ++k) {
      float4 a4 = *(const float4*)&H1[k][ty * 4];
      float4 b4 = *(const float4*)&W2s[k][tx * 4];
      const float* aa = (const float*)&a4;
      const float* bb = (const float*)&b4;
#pragma unroll
      for (int i = 0; i < 4; ++i)
#pragma unroll
        for (int j = 0; j < 4; ++j) acc2[i][j] = fmaf(aa[i], bb[j], acc2[i][j]);
    }
#pragma unroll
    for (int j = 0; j < 4; ++j) {
      sL[j] += (double)acc2[0][j] + (double)acc2[1][j] + (double)acc2[2][j] + (double)acc2[3][j];
      qL[j] += (double)acc2[0][j] * (double)acc2[0][j] + (double)acc2[1][j] * (double)acc2[1][j]
             + (double)acc2[2][j] * (double)acc2[2][j] + (double)acc2[3][j] * (double)acc2[3][j];
    }
  }
  __syncthreads();
#pragma unroll
  for (int j = 0; j < 4; ++j) rPd[ty][tx * 4 + j] = sL[j];
  __syncthreads();
  if (t < 64) {
    double s = 0.0;
#pragma unroll
    for (int w = 0; w < 16; ++w) s += rPd[w][t];
    atomicAdd(&st[t], s);
  }
  __syncthreads();
#pragma unroll
  for (int j = 0; j < 4; ++j) rPd[ty][tx * 4 + j] = qL[j];
  __syncthreads();
  if (t < 64) {
    double s = 0.0;
#pragma unroll
    for (int w = 0; w < 16; ++w) s += rPd[w][t];
    atomicAdd(&st[1024 + t], s);
  }
}

// ====== stage-1 final: f32, phase2 2-ch/thread float4 LDS (bitwise-identical outputs) ======
__global__ __launch_bounds__(256) void e1c_k(const float* __restrict__ x, const int* __restrict__ idx,
    const float* __restrict__ W1, const float* __restrict__ sc1, const float* __restrict__ sh1,
    const float* __restrict__ W2, const float* __restrict__ sc2, const float* __restrict__ sh2,
    float* __restrict__ x1out) {
  __shared__ float f6[80][9];
  __shared__ float h1s[80][68];   // stride 68 floats = 272 B (16B-aligned rows)
  __shared__ float pm[2][4][64];  // [half][point][ch]
  const int t = threadIdx.x;
  const int p0 = blockIdx.x * 4;
  if (t < 80) {
    int e = p0 * KNN + t;
    int pt = e / KNN;
    int b = pt >> 12, i = pt & (NN - 1);
    int j = idx[e] & (NN - 1);
    const float* xb = x + b * 3 * NN;
    float xi0 = xb[i], xi1 = xb[NN + i], xi2 = xb[2 * NN + i];
    f6[t][0] = xb[j] - xi0; f6[t][1] = xb[NN + j] - xi1; f6[t][2] = xb[2 * NN + j] - xi2;
    f6[t][3] = xi0; f6[t][4] = xi1; f6[t][5] = xi2;
  }
  __syncthreads();
  {
    const int c = t & 63;
    const int g4 = t >> 6;
    float w1[6];
#pragma unroll
    for (int d = 0; d < 6; ++d) w1[d] = W1[c * 6 + d];
    const float s1 = sc1[c], b1 = sh1[c];
    float hk[20];
#pragma unroll
    for (int k = 0; k < 20; ++k) hk[k] = 0.f;
#pragma unroll
    for (int d = 0; d < 6; ++d) {
      float w1d = w1[d];
#pragma unroll
      for (int k = 0; k < 20; ++k) hk[k] = fmaf(f6[g4 + k * 4][d], w1d, hk[k]);
    }
#pragma unroll
    for (int k = 0; k < 20; ++k)
      h1s[g4 + k * 4][c] = lrelu(fmaf(s1, hk[k], b1));
  }
  __syncthreads();
  // phase 2: 2 channels (c2, c2+32) x 10 edges per thread
  const int c2 = t & 31;
  const int g8 = t >> 5;            // [0,8)
  const int pp = g8 >> 1, half = g8 & 1;
  const int e0 = pp * 20 + half * 10;
  const float s2a = sc2[c2], b2a = sh2[c2];
  const float s2b = sc2[c2 + 32], b2b = sh2[c2 + 32];
  float aA[10], aB[10];
#pragma unroll
  for (int k = 0; k < 10; ++k) { aA[k] = 0.f; aB[k] = 0.f; }
  for (int d0 = 0; d0 < 64; d0 += 4) {
    float4 wa = *(const float4*)&W2[c2 * 64 + d0];
    float4 wb = *(const float4*)&W2[(c2 + 32) * 64 + d0];
#pragma unroll
    for (int k = 0; k < 10; ++k) {
      float4 hv = *(const float4*)&h1s[e0 + k][d0];
      aA[k] = fmaf(hv.x, wa.x, aA[k]); aA[k] = fmaf(hv.y, wa.y, aA[k]);
      aA[k] = fmaf(hv.z, wa.z, aA[k]); aA[k] = fmaf(hv.w, wa.w, aA[k]);
      aB[k] = fmaf(hv.x, wb.x, aB[k]); aB[k] = fmaf(hv.y, wb.y, aB[k]);
      aB[k] = fmaf(hv.z, wb.z, aB[k]); aB[k] = fmaf(hv.w, wb.w, aB[k]);
    }
  }
  float mA = -3.4e38f, mB = -3.4e38f;
#pragma unroll
  for (int k = 0; k < 10; ++k) {
    mA = fmaxf(mA, lrelu(fmaf(s2a, aA[k], b2a)));
    mB = fmaxf(mB, lrelu(fmaf(s2b, aB[k], b2b)));
  }
  pm[half][pp][c2] = mA;
  pm[half][pp][c2 + 32] = mB;
  __syncthreads();
  {
    int p = t >> 6, cc = t & 63;
    x1out[(p0 + p) * 64 + cc] = fmaxf(pm[0][p][cc], pm[1][p][cc]);
  }
}

// =================== squared norms (f64 + f32 copy for screen) ===================
__global__ void xx_k(const float* __restrict__ Xp, double* __restrict__ xx,
                     float* __restrict__ xxf) {
  const int row = blockIdx.x;
  float v = Xp[(size_t)row * 64 + threadIdx.x];
  double s = (double)v * (double)v;
#pragma unroll
  for (int o = 32; o > 0; o >>= 1) s += __shfl_down(s, o, 64);
  if (threadIdx.x == 0) { xx[row] = s; xxf[row] = (float)s; }
}

// ===== gathered-feature stats as tile-GEMM: col-stats of [xj-xi|xi] x W^T, 16 tiles/block ====
__global__ __launch_bounds__(256) void e2a_k(const float* __restrict__ xp,
                                             const int* __restrict__ idx,
                                             const float* __restrict__ W,
                                             double* __restrict__ st) {
  __shared__ float As[16][68];
  __shared__ float Ws[16][68];
  __shared__ double rPd[16][68];
  const int t = threadIdx.x;
  const int tx = t & 15, ty = t >> 4;
  const int lm = t >> 2, lk = (t & 3) * 4;
  double sL[4], qL[4];
#pragma unroll
  for (int j = 0; j < 4; ++j) { sL[j] = 0.0; qL[j] = 0.0; }
  for (int tile = 0; tile < 16; ++tile) {
    const int m0 = (blockIdx.x * 16 + tile) * 64;
    const int e = m0 + lm;
    const int grow = e / KNN;
    const int gj = ((grow >> 12) << 12) + (idx[e] & (NN - 1));
    float acc[4][4];
#pragma unroll
    for (int i = 0; i < 4; ++i)
#pragma unroll
      for (int j = 0; j < 4; ++j) acc[i][j] = 0.f;
    for (int k0 = 0; k0 < 128; k0 += 16) {
      const int c = k0 + lk;
      float4 a;
      if (c < 64) {
        float4 fj = *(const float4*)&xp[(size_t)gj * 64 + c];
        float4 fi = *(const float4*)&xp[(size_t)grow * 64 + c];
        a = make_float4(fj.x - fi.x, fj.y - fi.y, fj.z - fi.z, fj.w - fi.w);
      } else {
        a = *(const float4*)&xp[(size_t)grow * 64 + (c - 64)];
      }
      As[lk + 0][lm] = a.x; As[lk + 1][lm] = a.y;
      As[lk + 2][lm] = a.z; As[lk + 3][lm] = a.w;
      float4 wv = *(const float4*)&W[(size_t)lm * 128 + c];
      Ws[lk + 0][lm] = wv.x; Ws[lk + 1][lm] = wv.y;
      Ws[lk + 2][lm] = wv.z; Ws[lk + 3][lm] = wv.w;
      __syncthreads();
#pragma unroll
      for (int kk = 0; kk < 16; ++kk) {
        float4 a4 = *(const float4*)&As[kk][ty * 4];
        float4 b4 = *(const float4*)&Ws[kk][tx * 4];
        const float* aa = (const float*)&a4;
        const float* bb = (const float*)&b4;
#pragma unroll
        for (int i = 0; i < 4; ++i)
#pragma unroll
          for (int j = 0; j < 4; ++j)
            acc[i][j] = fmaf(aa[i], bb[j], acc[i][j]);
      }
      __syncthreads();
    }
#pragma unroll
    for (int j = 0; j < 4; ++j) {
      sL[j] += (double)acc[0][j] + (double)acc[1][j] + (double)acc[2][j] + (double)acc[3][j];
      qL[j] += (double)acc[0][j] * (double)acc[0][j] + (double)acc[1][j] * (double)acc[1][j]
             + (double)acc[2][j] * (double)acc[2][j] + (double)acc[3][j] * (double)acc[3][j];
    }
  }
#pragma unroll
  for (int j = 0; j < 4; ++j) rPd[ty][tx * 4 + j] = sL[j];
  __syncthreads();
  if (t < 64) {
    double s = 0.0;
#pragma unroll
    for (int w = 0; w < 16; ++w) s += rPd[w][t];
    atomicAdd(&st[t], s);
  }
  __syncthreads();
#pragma unroll
  for (int j = 0; j < 4; ++j) rPd[ty][tx * 4 + j] = qL[j];
  __syncthreads();
  if (t < 64) {
    double s = 0.0;
#pragma unroll
    for (int w = 0; w < 16; ++w) s += rPd[w][t];
    atomicAdd(&st[1024 + t], s);
  }
}

// ===== stage-2: h4 stats as chained tile-GEMM (gather->h3->BN->h4 col-stats) =====
__global__ __launch_bounds__(256) void e2b_k(const float* __restrict__ xp,
    const int* __restrict__ idx, const float* __restrict__ W3,
    const float* __restrict__ sc3, const float* __restrict__ sh3,
    const float* __restrict__ W4, double* __restrict__ st) {
  __shared__ float As[16][68];
  __shared__ float Ws[16][68];
  __shared__ float H3[64][68];
  __shared__ float W4s[64][68];
  __shared__ double rPd[16][68];
  const int t = threadIdx.x;
  const int tx = t & 15, ty = t >> 4;
  const int lm = t >> 2, lk = (t & 3) * 4;
  for (int l = t; l < 4096; l += 256) W4s[l & 63][l >> 6] = W4[l];
  double sL[4], qL[4];
#pragma unroll
  for (int j = 0; j < 4; ++j) { sL[j] = 0.0; qL[j] = 0.0; }
  for (int tile = 0; tile < 16; ++tile) {
    const int m0 = (blockIdx.x * 16 + tile) * 64;
    const int e = m0 + lm;
    const int grow = e / KNN;
    const int gj = ((grow >> 12) << 12) + (idx[e] & (NN - 1));
    float acc1[4][4];
#pragma unroll
    for (int i = 0; i < 4; ++i)
#pragma unroll
      for (int j = 0; j < 4; ++j) acc1[i][j] = 0.f;
    for (int k0 = 0; k0 < 128; k0 += 16) {
      const int c = k0 + lk;
      float4 a;
      if (c < 64) {
        float4 fj = *(const float4*)&xp[(size_t)gj * 64 + c];
        float4 fi = *(const float4*)&xp[(size_t)grow * 64 + c];
        a = make_float4(fj.x - fi.x, fj.y - fi.y, fj.z - fi.z, fj.w - fi.w);
      } else {
        a = *(const float4*)&xp[(size_t)grow * 64 + (c - 64)];
      }
      As[lk + 0][lm] = a.x; As[lk + 1][lm] = a.y;
      As[lk + 2][lm] = a.z; As[lk + 3][lm] = a.w;
      float4 wv = *(const float4*)&W3[(size_t)lm * 128 + c];
      Ws[lk + 0][lm] = wv.x; Ws[lk + 1][lm] = wv.y;
      Ws[lk + 2][lm] = wv.z; Ws[lk + 3][lm] = wv.w;
      __syncthreads();
#pragma unroll
      for (int kk = 0; kk < 16; ++kk) {
        float4 a4 = *(const float4*)&As[kk][ty * 4];
        float4 b4 = *(const float4*)&Ws[kk][tx * 4];
        const float* aa = (const float*)&a4;
        const float* bb = (const float*)&b4;
#pragma unroll
        for (int i = 0; i < 4; ++i)
#pragma unroll
          for (int j = 0; j < 4; ++j)
            acc1[i][j] = fmaf(aa[i], bb[j], acc1[i][j]);
      }
      __syncthreads();
    }
#pragma unroll
    for (int j = 0; j < 4; ++j) {
      int c = tx * 4 + j;
      float s3 = sc3[c], b3 = sh3[c];
#pragma unroll
      for (int i = 0; i < 4; ++i)
        H3[c][ty * 4 + i] = lrelu(fmaf(s3, acc1[i][j], b3));
    }
    __syncthreads();
    float acc2[4][4];
#pragma unroll
    for (int i = 0; i < 4; ++i)
#pragma unroll
      for (int j = 0; j < 4; ++j) acc2[i][j] = 0.f;
    for (int k = 0; k < 64; ++k) {
      float4 a4 = *(const float4*)&H3[k][ty * 4];
      float4 b4 = *(const float4*)&W4s[k][tx * 4];
      const float* aa = (const float*)&a4;
      const float* bb = (const float*)&b4;
#pragma unroll
      for (int i = 0; i < 4; ++i)
#pragma unroll
        for (int j = 0; j < 4; ++j) acc2[i][j] = fmaf(aa[i], bb[j], acc2[i][j]);
    }
    __syncthreads();
#pragma unroll
    for (int j = 0; j < 4; ++j) {
      sL[j] += (double)acc2[0][j] + (double)acc2[1][j] + (double)acc2[2][j] + (double)acc2[3][j];
      qL[j] += (double)acc2[0][j] * (double)acc2[0][j] + (double)acc2[1][j] * (double)acc2[1][j]
             + (double)acc2[2][j] * (double)acc2[2][j] + (double)acc2[3][j] * (double)acc2[3][j];
    }
  }
#pragma unroll
  for (int j = 0; j < 4; ++j) rPd[ty][tx * 4 + j] = sL[j];
  __syncthreads();
  if (t < 64) {
    double s = 0.0;
#pragma unroll
    for (int w = 0; w < 16; ++w) s += rPd[w][t];
    atomicAdd(&st[t], s);
  }
  __syncthreads();
#pragma unroll
  for (int j = 0; j < 4; ++j) rPd[ty][tx * 4 + j] = qL[j];
  __syncthreads();
  if (t < 64) {
    double s = 0.0;
#pragma unroll
    for (int w = 0; w < 16; ++w) s += rPd[w][t];
    atomicAdd(&st[1024 + t], s);
  }
}

// ==== stage-2 final: f32, 2-ch/thread float4 LDS (bitwise-identical outputs) ====
__global__ __launch_bounds__(256) void e2c_k(const float* __restrict__ xp,
    const int* __restrict__ idx, const float* __restrict__ W3,
    const float* __restrict__ sc3, const float* __restrict__ sh3,
    const float* __restrict__ W4, const float* __restrict__ sc4, const float* __restrict__ sh4,
    float* __restrict__ x2out) {
  __shared__ float fs[40][132];   // stride 132 floats = 528 B (16B-aligned rows)
  __shared__ float h3s[40][68];   // stride 68 floats = 272 B (16B-aligned rows)
  __shared__ float pm[4][2][64];  // [group][point][ch]
  const int t = threadIdx.x;
  const int p0 = blockIdx.x * 2;
  for (int s = 0; s < 5; ++s) {
    int lin = s * 256 + t;
    int e = lin >> 5, v4 = lin & 31;
    int col = v4 * 4;
    int eg = p0 * KNN + e;
    int pt = p0 + e / KNN;
    int jr = ((pt >> 12) << 12) + (idx[eg] & (NN - 1));
    const float* xi = xp + (size_t)pt * 64;
    const float* xj = xp + (size_t)jr * 64;
    float4 a;
    if (col < 64) {
      float4 fj = *(const float4*)&xj[col];
      float4 fi = *(const float4*)&xi[col];
      a = make_float4(fj.x - fi.x, fj.y - fi.y, fj.z - fi.z, fj.w - fi.w);
    } else {
      a = *(const float4*)&xi[col - 64];
    }
    fs[e][col + 0] = a.x; fs[e][col + 1] = a.y; fs[e][col + 2] = a.z; fs[e][col + 3] = a.w;
  }
  __syncthreads();
  const int c2 = t & 31;            // channels c2 and c2+32
  const int g8 = t >> 5;            // [0,8)
  // phase 1: h3 for edges e = g8 + 8k (k<5), both channels
  {
    const float s3a = sc3[c2], b3a = sh3[c2];
    const float s3b = sc3[c2 + 32], b3b = sh3[c2 + 32];
    float hA[5], hB[5];
#pragma unroll
    for (int k = 0; k < 5; ++k) { hA[k] = 0.f; hB[k] = 0.f; }
    for (int d0 = 0; d0 < 128; d0 += 4) {
      float4 wa = *(const float4*)&W3[c2 * 128 + d0];
      float4 wb = *(const float4*)&W3[(c2 + 32) * 128 + d0];
#pragma unroll
      for (int k = 0; k < 5; ++k) {
        float4 fv = *(const float4*)&fs[g8 + k * 8][d0];
        hA[k] = fmaf(fv.x, wa.x, hA[k]); hA[k] = fmaf(fv.y, wa.y, hA[k]);
        hA[k] = fmaf(fv.z, wa.z, hA[k]); hA[k] = fmaf(fv.w, wa.w, hA[k]);
        hB[k] = fmaf(fv.x, wb.x, hB[k]); hB[k] = fmaf(fv.y, wb.y, hB[k]);
        hB[k] = fmaf(fv.z, wb.z, hB[k]); hB[k] = fmaf(fv.w, wb.w, hB[k]);
      }
    }
#pragma unroll
    for (int k = 0; k < 5; ++k) {
      h3s[g8 + k * 8][c2]      = lrelu(fmaf(s3a, hA[k], b3a));
      h3s[g8 + k * 8][c2 + 32] = lrelu(fmaf(s3b, hB[k], b3b));
    }
  }
  __syncthreads();
  // phase 2: h4 for point p = g8&1, edges e = p*20 + (g8>>1)*5 + k
  const int pp = g8 & 1, grp = g8 >> 1;
  const int e0 = pp * 20 + grp * 5;
  const float s4a = sc4[c2], b4a = sh4[c2];
  const float s4b = sc4[c2 + 32], b4b = sh4[c2 + 32];
  float aA[5], aB[5];
#pragma unroll
  for (int k = 0; k < 5; ++k) { aA[k] = 0.f; aB[k] = 0.f; }
  for (int d0 = 0; d0 < 64; d0 += 4) {
    float4 wa = *(const float4*)&W4[c2 * 64 + d0];
    float4 wb = *(const float4*)&W4[(c2 + 32) * 64 + d0];
#pragma unroll
    for (int k = 0; k < 5; ++k) {
      float4 hv = *(const float4*)&h3s[e0 + k][d0];
      aA[k] = fmaf(hv.x, wa.x, aA[k]); aA[k] = fmaf(hv.y, wa.y, aA[k]);
      aA[k] = fmaf(hv.z, wa.z, aA[k]); aA[k] = fmaf(hv.w, wa.w, aA[k]);
      aB[k] = fmaf(hv.x, wb.x, aB[k]); aB[k] = fmaf(hv.y, wb.y, aB[k]);
      aB[k] = fmaf(hv.z, wb.z, aB[k]); aB[k] = fmaf(hv.w, wb.w, aB[k]);
    }
  }
  float mA = -3.4e38f, mB = -3.4e38f;
#pragma unroll
  for (int k = 0; k < 5; ++k) {
    mA = fmaxf(mA, lrelu(fmaf(s4a, aA[k], b4a)));
    mB = fmaxf(mB, lrelu(fmaf(s4b, aB[k], b4b)));
  }
  pm[grp][pp][c2] = mA;
  pm[grp][pp][c2 + 32] = mB;
  __syncthreads();
  if (t < 128) {
    int p = t >> 6, cc = t & 63;
    float m = fmaxf(fmaxf(pm[0][p][cc], pm[1][p][cc]), fmaxf(pm[2][p][cc], pm[3][p][cc]));
    x2out[(p0 + p) * 64 + cc] = m;
  }
}

// ==== stage-3 final: f32, 2-ch/thread float4 LDS (bitwise-identical outputs) ====
__global__ __launch_bounds__(256) void e3c_k(const float* __restrict__ xp,
    const int* __restrict__ idx, const float* __restrict__ W5,
    const float* __restrict__ sc5, const float* __restrict__ sh5,
    float* __restrict__ x3out) {
  __shared__ float fs[80][132];   // stride 132 floats = 528 B (16B-aligned rows)
  __shared__ float pm[2][4][64];  // [half][point][ch]
  const int t = threadIdx.x;
  const int p0 = blockIdx.x * 4;
  for (int s = 0; s < 10; ++s) {
    int lin = s * 256 + t;
    int e = lin >> 5, v4 = lin & 31;
    int col = v4 * 4;
    int eg = p0 * KNN + e;
    int pt = p0 + e / KNN;
    int jr = ((pt >> 12) << 12) + (idx[eg] & (NN - 1));
    const float* xi = xp + (size_t)pt * 64;
    const float* xj = xp + (size_t)jr * 64;
    float4 a;
    if (col < 64) {
      float4 fj = *(const float4*)&xj[col];
      float4 fi = *(const float4*)&xi[col];
      a = make_float4(fj.x - fi.x, fj.y - fi.y, fj.z - fi.z, fj.w - fi.w);
    } else {
      a = *(const float4*)&xi[col - 64];
    }
    fs[e][col + 0] = a.x; fs[e][col + 1] = a.y; fs[e][col + 2] = a.z; fs[e][col + 3] = a.w;
  }
  __syncthreads();
  const int c2 = t & 31;
  const int g8 = t >> 5;
  const int pp = g8 >> 1, half = g8 & 1;
  const int e0 = pp * 20 + half * 10;
  const float s5a = sc5[c2], b5a = sh5[c2];
  const float s5b = sc5[c2 + 32], b5b = sh5[c2 + 32];
  float aA[10], aB[10];
#pragma unroll
  for (int k = 0; k < 10; ++k) { aA[k] = 0.f; aB[k] = 0.f; }
  for (int d0 = 0; d0 < 128; d0 += 4) {
    float4 wa = *(const float4*)&W5[c2 * 128 + d0];
    float4 wb = *(const float4*)&W5[(c2 + 32) * 128 + d0];
#pragma unroll
    for (int k = 0; k < 10; ++k) {
      float4 fv = *(const float4*)&fs[e0 + k][d0];
      aA[k] += fv.x * wa.x; aA[k] += fv.y * wa.y;
      aA[k] += fv.z * wa.z; aA[k] += fv.w * wa.w;
      aB[k] += fv.x * wb.x; aB[k] += fv.y * wb.y;
      aB[k] += fv.z * wb.z; aB[k] += fv.w * wb.w;
    }
  }
  float mA = -3.4e38f, mB = -3.4e38f;
#pragma unroll
  for (int k = 0; k < 10; ++k) {
    mA = fmaxf(mA, lrelu(s5a * aA[k] + b5a));
    mB = fmaxf(mB, lrelu(s5b * aB[k] + b5b));
  }
  pm[half][pp][c2] = mA;
  pm[half][pp][c2 + 32] = mB;
  __syncthreads();
  {
    int p = t >> 6, cc = t & 63;
    x3out[(p0 + p) * 64 + cc] = fmaxf(pm[0][p][cc], pm[1][p][cc]);
  }
}

// ==== fused h6 stats + per-column max/min of pre-BN h6 ====
__global__ __launch_bounds__(256) void g6stats_k(
    const float* __restrict__ x1p, const float* __restrict__ x2p,
    const float* __restrict__ x3p, const float* __restrict__ W6,
    double* __restrict__ st, float* __restrict__ gpmax, float* __restrict__ gpmin) {
  __shared__ float As[16][68];
  __shared__ float Ws[16][68];
  __shared__ float rP[16][64];
  const int t = threadIdx.x;
  const int m0 = blockIdx.x * 64, n0 = blockIdx.y * 64;
  const int tx = t & 15, ty = t >> 4;
  const int lm = t >> 2, lk = (t & 3) * 4;
  const int m = m0 + lm, wn = n0 + lm;
  float acc[4][4];
#pragma unroll
  for (int i = 0; i < 4; ++i)
#pragma unroll
    for (int j = 0; j < 4; ++j) acc[i][j] = 0.f;
  for (int k0 = 0; k0 < 192; k0 += 16) {
    const int c = k0 + lk;
    const float* src = (c < 64)  ? &x1p[(size_t)m * 64 + c]
                     : (c < 128) ? &x2p[(size_t)m * 64 + (c - 64)]
                                 : &x3p[(size_t)m * 64 + (c - 128)];
    float4 av = *(const float4*)src;
    As[lk + 0][lm] = av.x; As[lk + 1][lm] = av.y;
    As[lk + 2][lm] = av.z; As[lk + 3][lm] = av.w;
    float4 wv = *(const float4*)&W6[(size_t)wn * 192 + c];
    Ws[lk + 0][lm] = wv.x; Ws[lk + 1][lm] = wv.y;
    Ws[lk + 2][lm] = wv.z; Ws[lk + 3][lm] = wv.w;
    __syncthreads();
#pragma unroll
    for (int kk = 0; kk < 16; ++kk) {
      float4 a4 = *(const float4*)&As[kk][ty * 4];
      float4 b4 = *(const float4*)&Ws[kk][tx * 4];
      const float* aa = (const float*)&a4;
      const float* bb = (const float*)&b4;
#pragma unroll
      for (int i = 0; i < 4; ++i)
#pragma unroll
        for (int j = 0; j < 4; ++j)
          acc[i][j] = fmaf(aa[i], bb[j], acc[i][j]);
    }
    __syncthreads();
  }
#pragma unroll
  for (int j = 0; j < 4; ++j)
    rP[ty][tx * 4 + j] = acc[0][j] + acc[1][j] + acc[2][j] + acc[3][j];
  __syncthreads();
  if (t < 64) {
    float ssum = 0.f;
#pragma unroll
    for (int w = 0; w < 16; ++w) ssum += rP[w][t];
    atomicAdd(&st[n0 + t], (double)ssum);
  }
  __syncthreads();
#pragma unroll
  for (int j = 0; j < 4; ++j)
    rP[ty][tx * 4 + j] = acc[0][j] * acc[0][j] + acc[1][j] * acc[1][j]
                       + acc[2][j] * acc[2][j] + acc[3][j] * acc[3][j];
  __syncthreads();
  if (t < 64) {
    float qsum = 0.f;
#pragma unroll
    for (int w = 0; w < 16; ++w) qsum += rP[w][t];
    atomicAdd(&st[1024 + n0 + t], (double)qsum);
  }
  __syncthreads();
#pragma unroll
  for (int j = 0; j < 4; ++j)
    rP[ty][tx * 4 + j] = fmaxf(fmaxf(acc[0][j], acc[1][j]), fmaxf(acc[2][j], acc[3][j]));
  __syncthreads();
  if (t < 64) {
    float mx = -3.4e38f;
#pragma unroll
    for (int w = 0; w < 16; ++w) mx = fmaxf(mx, rP[w][t]);
    gpmax[(size_t)blockIdx.x * 1024 + n0 + t] = mx;
  }
  __syncthreads();
#pragma unroll
  for (int j = 0; j < 4; ++j)
    rP[ty][tx * 4 + j] = fminf(fminf(acc[0][j], acc[1][j]), fminf(acc[2][j], acc[3][j]));
  __syncthreads();
  if (t < 64) {
    float mn = 3.4e38f;
#pragma unroll
    for (int w = 0; w < 16; ++w) mn = fminf(mn, rP[w][t]);
    gpmin[(size_t)blockIdx.x * 1024 + n0 + t] = mn;
  }
}

__global__ void gmax_red2_k(const float* __restrict__ gpmax, const float* __restrict__ gpmin,
                            const float* __restrict__ sc6, const float* __restrict__ sh6,
                            float* __restrict__ gm) {
  const int b = blockIdx.x;
  const int c = blockIdx.y * 256 + threadIdx.x;
  float mx = -3.4e38f, mn = 3.4e38f;
  for (int rb = 0; rb < 64; ++rb) {
    mx = fmaxf(mx, gpmax[(size_t)(b * 64 + rb) * 1024 + c]);
    mn = fminf(mn, gpmin[(size_t)(b * 64 + rb) * 1024 + c]);
  }
  float s6 = sc6[c], b6 = sh6[c];
  float h = (s6 >= 0.f) ? mx : mn;
  gm[b * 1024 + c] = lrelu(s6 * h + b6);
}

__global__ void wpack_k(const float* __restrict__ W7, float* __restrict__ W7r) {
  int i = blockIdx.x * 256 + threadIdx.x;
  if (i < 512 * 192) {
    int n = i / 192, c = i - n * 192;
    W7r[i] = W7[(size_t)n * 1216 + 1024 + c];
  }
}

__global__ __launch_bounds__(256) void gw_k(const float* __restrict__ gm,
                                            const float* __restrict__ W7,
                                            float* __restrict__ gW) {
  int idx = blockIdx.x * 256 + threadIdx.x;
  int b = idx >> 9, n = idx & 511;
  const float* g = gm + b * 1024;
  const float* w = W7 + (size_t)n * 1216;
  float s0 = 0.f, s1 = 0.f, s2 = 0.f, s3 = 0.f;
  for (int c = 0; c < 1024; c += 4) {
    float4 gv = *(const float4*)&g[c];
    float4 wv = *(const float4*)&w[c];
    s0 = fmaf(gv.x, wv.x, s0); s1 = fmaf(gv.y, wv.y, s1);
    s2 = fmaf(gv.z, wv.z, s2); s3 = fmaf(gv.w, wv.w, s3);
  }
  gW[idx] = (s0 + s1) + (s2 + s3);
}

// ==== h7 = gW + x123 . W7r^T : K=192 GEMM, stats + store ====
template <int H7F32>
__global__ __launch_bounds__(256) void g7stats_k(
    const float* __restrict__ x1p, const float* __restrict__ x2p,
    const float* __restrict__ x3p, const float* __restrict__ W7r,
    const float* __restrict__ gW, void* __restrict__ Hout, double* __restrict__ st) {
  __shared__ float As[16][68];
  __shared__ float Ws[16][68];
  __shared__ float rP[16][64];
  const int t = threadIdx.x;
  const int m0 = blockIdx.x * 64, n0 = blockIdx.y * 64;
  const int tx = t & 15, ty = t >> 4;
  const int lm = t >> 2, lk = (t & 3) * 4;
  const int m = m0 + lm, wn = n0 + lm;
  const int b = m0 >> 12;
  float acc[4][4];
#pragma unroll
  for (int j = 0; j < 4; ++j) {
    float g0 = gW[b * 512 + n0 + tx * 4 + j];
#pragma unroll
    for (int i = 0; i < 4; ++i) acc[i][j] = g0;
  }
  for (int k0 = 0; k0 < 192; k0 += 16) {
    const int c = k0 + lk;
    const float* src = (c < 64)  ? &x1p[(size_t)m * 64 + c]
                     : (c < 128) ? &x2p[(size_t)m * 64 + (c - 64)]
                                 : &x3p[(size_t)m * 64 + (c - 128)];
    float4 av = *(const float4*)src;
    As[lk + 0][lm] = av.x; As[lk + 1][lm] = av.y;
    As[lk + 2][lm] = av.z; As[lk + 3][lm] = av.w;
    float4 wv = *(const float4*)&W7r[(size_t)wn * 192 + c];
    Ws[lk + 0][lm] = wv.x; Ws[lk + 1][lm] = wv.y;
    Ws[lk + 2][lm] = wv.z; Ws[lk + 3][lm] = wv.w;
    __syncthreads();
#pragma unroll
    for (int kk = 0; kk < 16; ++kk) {
      float4 a4 = *(const float4*)&As[kk][ty * 4];
      float4 b4 = *(const float4*)&Ws[kk][tx * 4];
      const float* aa = (const float*)&a4;
      const float* bb = (const float*)&b4;
#pragma unroll
      for (int i = 0; i < 4; ++i)
#pragma unroll
        for (int j = 0; j < 4; ++j)
          acc[i][j] = fmaf(aa[i], bb[j], acc[i][j]);
    }
    __syncthreads();
  }
#pragma unroll
  for (int j = 0; j < 4; ++j)
    rP[ty][tx * 4 + j] = acc[0][j] + acc[1][j] + acc[2][j] + acc[3][j];
  __syncthreads();
  if (t < 64) {
    float ssum = 0.f;
#pragma unroll
    for (int w = 0; w < 16; ++w) ssum += rP[w][t];
    atomicAdd(&st[n0 + t], (double)ssum);
  }
  __syncthreads();
#pragma unroll
  for (int j = 0; j < 4; ++j)
    rP[ty][tx * 4 + j] = acc[0][j] * acc[0][j] + acc[1][j] * acc[1][j]
                       + acc[2][j] * acc[2][j] + acc[3][j] * acc[3][j];
  __syncthreads();
  if (t < 64) {
    float qsum = 0.f;
#pragma unroll
    for (int w = 0; w < 16; ++w) qsum += rP[w][t];
    atomicAdd(&st[1024 + n0 + t], (double)qsum);
  }
#pragma unroll
  for (int i = 0; i < 4; ++i) {
    int r = m0 + ty * 4 + i;
#pragma unroll
    for (int j = 0; j < 4; ++j) {
      if (H7F32)
        ((float*)Hout)[(size_t)r * 512 + n0 + tx * 4 + j] = acc[i][j];
      else
        ((u16*)Hout)[(size_t)r * 512 + n0 + tx * 4 + j] = f2bf_rne(acc[i][j]);
    }
  }
}

// =================== tile GEMM + fused BN-stats (h7 -> h8 stats; AMODE 4 path) ===================
template <int AMODE, int STORE, int H7F32>
__global__ __launch_bounds__(256) void gstats_k(
    const void* __restrict__ Ain, const float* __restrict__ Wp, const int K, const int Nout,
    const float* __restrict__ x1p, const float* __restrict__ x2p,
    const float* __restrict__ x3p, const float* __restrict__ gmp,
    const float* __restrict__ scA, const float* __restrict__ shA,
    void* __restrict__ Hout, double* __restrict__ st) {
  __shared__ float As[16][68];
  __shared__ float Ws[16][68];
  __shared__ float rP[16][64];
  const int t = threadIdx.x;
  const int m0 = blockIdx.x * 64, n0 = blockIdx.y * 64;
  const int tx = t & 15, ty = t >> 4;
  const int lm = t >> 2, lk = (t & 3) * 4;
  const int m = m0 + lm, wn = n0 + lm;
  float acc[4][4];
#pragma unroll
  for (int i = 0; i < 4; ++i)
#pragma unroll
    for (int j = 0; j < 4; ++j) acc[i][j] = 0.f;

  for (int k0 = 0; k0 < K; k0 += 16) {
    const int c = k0 + lk;
    float4 av;
    if (AMODE == 2) {
      const float* src = (c < 64)  ? &x1p[(size_t)m * 64 + c]
                       : (c < 128) ? &x2p[(size_t)m * 64 + (c - 64)]
                                   : &x3p[(size_t)m * 64 + (c - 128)];
      av = *(const float4*)src;
    } else if (AMODE == 3) {
      if (c < 1024) {
        av = *(const float4*)&gmp[(size_t)(m >> 12) * 1024 + c];
      } else {
        int cc = c - 1024;
        const float* src = (cc < 64)  ? &x1p[(size_t)m * 64 + cc]
                         : (cc < 128) ? &x2p[(size_t)m * 64 + (cc - 64)]
                                      : &x3p[(size_t)m * 64 + (cc - 128)];
        av = *(const float4*)src;
      }
    } else {
      if (H7F32) {
        av = *(const float4*)&((const float*)Ain)[(size_t)m * K + c];
      } else {
        ushort4 u4 = *(const ushort4*)&((const u16*)Ain)[(size_t)m * K + c];
        av = make_float4(bf2f(u4.x), bf2f(u4.y), bf2f(u4.z), bf2f(u4.w));
      }
      av.x = lrelu(scA[c + 0] * av.x + shA[c + 0]);
      av.y = lrelu(scA[c + 1] * av.y + shA[c + 1]);
      av.z = lrelu(scA[c + 2] * av.z + shA[c + 2]);
      av.w = lrelu(scA[c + 3] * av.w + shA[c + 3]);
    }
    As[lk + 0][lm] = av.x; As[lk + 1][lm] = av.y;
    As[lk + 2][lm] = av.z; As[lk + 3][lm] = av.w;
    float4 wv = *(const float4*)&Wp[(size_t)wn * K + c];
    Ws[lk + 0][lm] = wv.x; Ws[lk + 1][lm] = wv.y;
    Ws[lk + 2][lm] = wv.z; Ws[lk + 3][lm] = wv.w;
    __syncthreads();
#pragma unroll
    for (int kk = 0; kk < 16; ++kk) {
      float4 a4 = *(const float4*)&As[kk][ty * 4];
      float4 b4 = *(const float4*)&Ws[kk][tx * 4];
      const float* aa = (const float*)&a4;
      const float* bb = (const float*)&b4;
#pragma unroll
      for (int i = 0; i < 4; ++i)
#pragma unroll
        for (int j = 0; j < 4; ++j)
          acc[i][j] = fmaf(aa[i], bb[j], acc[i][j]);
    }
    __syncthreads();
  }
#pragma unroll
  for (int j = 0; j < 4; ++j)
    rP[ty][tx * 4 + j] = acc[0][j] + acc[1][j] + acc[2][j] + acc[3][j];
  __syncthreads();
  if (t < 64) {
    float ssum = 0.f;
#pragma unroll
    for (int w = 0; w < 16; ++w) ssum += rP[w][t];
    atomicAdd(&st[n0 + t], (double)ssum);
  }
  __syncthreads();
#pragma unroll
  for (int j = 0; j < 4; ++j)
    rP[ty][tx * 4 + j] = acc[0][j] * acc[0][j] + acc[1][j] * acc[1][j]
                       + acc[2][j] * acc[2][j] + acc[3][j] * acc[3][j];
  __syncthreads();
  if (t < 64) {
    float qsum = 0.f;
#pragma unroll
    for (int w = 0; w < 16; ++w) qsum += rP[w][t];
    atomicAdd(&st[1024 + n0 + t], (double)qsum);
  }
  if (STORE) {
#pragma unroll
    for (int i = 0; i < 4; ++i) {
      int r = m0 + ty * 4 + i;
#pragma unroll
      for (int j = 0; j < 4; ++j) {
        if (H7F32)
          ((float*)Hout)[(size_t)r * Nout + n0 + tx * 4 + j] = acc[i][j];
        else
          ((u16*)Hout)[(size_t)r * Nout + n0 + tx * 4 + j] = f2bf_rne(acc[i][j]);
      }
    }
  }
}

// =================== final: h7'->h8 -> BN -> xW9^T -> out (rP padded: 585) ===================
template <int H7F32>
__global__ __launch_bounds__(256) void final_k(
    const void* __restrict__ h7, const float* __restrict__ sc7, const float* __restrict__ sh7,
    const float* __restrict__ W8, const float* __restrict__ sc8, const float* __restrict__ sh8,
    const float* __restrict__ W9, void* __restrict__ outp_raw,
    const int* __restrict__ flag) {
  __shared__ float As[16][68];
  __shared__ float Ws[16][68];
  __shared__ float w9s[9][256];
  __shared__ float rP[16][585];
  const int t = threadIdx.x;
  const int m0 = blockIdx.x * 64;
  const int tx = t & 15, ty = t >> 4;
  const int lm = t >> 2, lk = (t & 3) * 4;
  for (int l = t; l < 2304; l += 256) w9s[l >> 8][l & 255] = W9[l];
  float outp[4][9];
#pragma unroll
  for (int i = 0; i < 4; ++i)
#pragma unroll
    for (int o = 0; o < 9; ++o) outp[i][o] = 0.f;
  for (int nt = 0; nt < 4; ++nt) {
    const int n0 = nt * 64;
    float acc[4][4];
#pragma unroll
    for (int i = 0; i < 4; ++i)
#pragma unroll
      for (int j = 0; j < 4; ++j) acc[i][j] = 0.f;
    for (int k0 = 0; k0 < 512; k0 += 16) {
      const int c = k0 + lk;
      float4 hv;
      if (H7F32) {
        hv = *(const float4*)&((const float*)h7)[(size_t)(m0 + lm) * 512 + c];
      } else {
        ushort4 u4 = *(const ushort4*)&((const u16*)h7)[(size_t)(m0 + lm) * 512 + c];
        hv = make_float4(bf2f(u4.x), bf2f(u4.y), bf2f(u4.z), bf2f(u4.w));
      }
      As[lk + 0][lm] = lrelu(sc7[c + 0] * hv.x + sh7[c + 0]);
      As[lk + 1][lm] = lrelu(sc7[c + 1] * hv.y + sh7[c + 1]);
      As[lk + 2][lm] = lrelu(sc7[c + 2] * hv.z + sh7[c + 2]);
      As[lk + 3][lm] = lrelu(sc7[c + 3] * hv.w + sh7[c + 3]);
      float4 wv = *(const float4*)&W8[(size_t)(n0 + lm) * 512 + c];
      Ws[lk + 0][lm] = wv.x; Ws[lk + 1][lm] = wv.y;
      Ws[lk + 2][lm] = wv.z; Ws[lk + 3][lm] = wv.w;
      __syncthreads();
#pragma unroll
      for (int kk = 0; kk < 16; ++kk) {
        float4 a4 = *(const float4*)&As[kk][ty * 4];
        float4 b4 = *(const float4*)&Ws[kk][tx * 4];
        const float* aa = (const float*)&a4;
        const float* bb = (const float*)&b4;
#pragma unroll
        for (int i = 0; i < 4; ++i)
#pragma unroll
          for (int j = 0; j < 4; ++j)
            acc[i][j] = fmaf(aa[i], bb[j], acc[i][j]);
      }
      __syncthreads();
    }
#pragma unroll
    for (int j = 0; j < 4; ++j) {
      int c = n0 + tx * 4 + j;
      float s8 = sc8[c], b8 = sh8[c];
#pragma unroll
      for (int i = 0; i < 4; ++i) {
        float v = lrelu(s8 * acc[i][j] + b8);
#pragma unroll
        for (int o = 0; o < 9; ++o) outp[i][o] += v * w9s[o][c];
      }
    }
  }
#pragma unroll
  for (int i = 0; i < 4; ++i)
#pragma unroll
    for (int o = 0; o < 9; ++o) rP[tx][(ty * 4 + i) * 9 + o] = outp[i][o];
  __syncthreads();
  const int mode = flag[0];
  for (int l = t; l < 576; l += 256) {
    float sum = 0.f;
#pragma unroll
    for (int w = 0; w < 16; ++w) sum += rP[w][l];
    if (mode) {
      ((__hip_bfloat16*)outp_raw)[(size_t)m0 * 9 + l] = __float2bfloat16(sum);
    } else {
      ((float*)outp_raw)[(size_t)m0 * 9 + l] = sum;
    }
  }
}

// =================== host ===================
extern "C" void kernel_launch(void* const* d_in, const int* in_sizes, int n_in,
                              void* d_out, int out_size, void* d_ws, size_t ws_size,
                              hipStream_t stream) {
  (void)in_sizes; (void)out_size;
  if (n_in < 27) return;

  char* p = (char*)d_ws;
  size_t used = 0;
  auto alloc = [&](size_t bytes) {
    char* r = p;
    size_t rb = (bytes + 255) & ~(size_t)255;
    p += rb; used += rb;
    return r;
  };
  int* flag    = (int*)alloc(256);
  float* xF    = (float*)alloc((size_t)98304 * 4);
  float* W1f   = (float*)alloc((size_t)384 * 4);
  float* W2f   = (float*)alloc((size_t)4096 * 4);
  float* W3f   = (float*)alloc((size_t)8192 * 4);
  float* W4f   = (float*)alloc((size_t)4096 * 4);
  float* W5f   = (float*)alloc((size_t)8192 * 4);
  float* W6f   = (float*)alloc((size_t)196608 * 4);
  float* W7f   = (float*)alloc((size_t)622592 * 4);
  float* W8f   = (float*)alloc((size_t)131072 * 4);
  float* W9f   = (float*)alloc((size_t)2304 * 4);
  float* gF    = (float*)alloc((size_t)2112 * 4);
  float* bF    = (float*)alloc((size_t)2112 * 4);
  int* idxb    = (int*)alloc((size_t)NEDGE * 4);
  double* xx   = (double*)alloc((size_t)NPTS * 8);
  float* xxfb  = (float*)alloc((size_t)NPTS * 4);
  u16* Xhi     = (u16*)alloc((size_t)NPTS * 64 * 2);
  u16* Xlo     = (u16*)alloc((size_t)NPTS * 64 * 2);
  float* x1    = (float*)alloc((size_t)NPTS * 64 * 4);
  float* x2    = (float*)alloc((size_t)NPTS * 64 * 4);
  float* x3    = (float*)alloc((size_t)NPTS * 64 * 4);
  float* gm    = (float*)alloc((size_t)BB * 1024 * 4);
  float* gpmax = (float*)alloc((size_t)512 * 1024 * 4);
  float* gpmin = (float*)alloc((size_t)512 * 1024 * 4);
  float* gW    = (float*)alloc((size_t)4096 * 4);
  float* W7r   = (float*)alloc((size_t)98304 * 4);
  double* st   = (double*)alloc((size_t)2048 * 8);
  double* stm  = (double*)alloc((size_t)32 * 8);
  float* scb   = (float*)alloc((size_t)8 * 1024 * 4);
  float* shb   = (float*)alloc((size_t)8 * 1024 * 4);
  const int h7f32 = (ws_size >= used + (size_t)NPTS * 512 * 4 + 256) ? 1 : 0;
  void* h7 = alloc((size_t)NPTS * 512 * (h7f32 ? 4 : 2));
  if (ws_size < used) return;
  // kNN scratch overlays h7 (consumed before h7's real use):
  //   pkey : 4 segs x NPTS x 20 u64 = 21.0 MB (3-D knn partials)
  //   pcand: NPTS x 48 u64 = 12.6 MB          (screen candidates)
  u64* pkey  = (u64*)h7;
  u64* pcand = (u64*)h7;

  // ---- canonicalize all inputs to f32 ----
  det_k<<<1, 1, 0, stream>>>(d_in[11], flag);
  auto conv = [&](const void* src, float* dst, int n) {
    conv_k<<<(n + 255) / 256, 256, 0, stream>>>(src, dst, n, flag);
  };
  conv(d_in[0], xF, 98304);
  conv(d_in[2], W1f, 384);    conv(d_in[3], W2f, 4096);
  conv(d_in[4], W3f, 8192);   conv(d_in[5], W4f, 4096);
  conv(d_in[6], W5f, 8192);   conv(d_in[7], W6f, 196608);
  conv(d_in[8], W7f, 622592); conv(d_in[9], W8f, 131072);
  conv(d_in[10], W9f, 2304);
  const int gsz[8] = {64, 64, 64, 64, 64, 1024, 512, 256};
  int goff[8]; int acc_ = 0;
  for (int i = 0; i < 8; ++i) { goff[i] = acc_; acc_ += gsz[i]; }
  for (int i = 0; i < 8; ++i) {
    conv(d_in[11 + 2 * i], gF + goff[i], gsz[i]);
    conv(d_in[12 + 2 * i], bF + goff[i], gsz[i]);
  }
  wpack_k<<<384, 256, 0, stream>>>(W7f, W7r);
  auto SC = [&](int l) { return scb + (size_t)(l - 1) * 1024; };
  auto SH = [&](int l) { return shb + (size_t)(l - 1) * 1024; };
  auto G  = [&](int l) { return gF + goff[l - 1]; };
  auto Bt = [&](int l) { return bF + goff[l - 1]; };

  // ---- stage 1 ----
  knn1p_k<<<dim3(BB, 16, 4), 256, 0, stream>>>(xF, pkey);
  tmerge_k<<<NPTS / 256, 256, 0, stream>>>(pkey, idxb);
  zero_k<<<1, 256, 0, stream>>>(stm, 32);
  f1mom_k<<<320, 256, 0, stream>>>(xF, idxb, stm);
  fin1_k<<<1, 64, 0, stream>>>(stm, W1f, G(1), Bt(1), SC(1), SH(1), 1.0 / NEDGE);
  zero_k<<<8, 256, 0, stream>>>(st, 2048);
  e1b_k<<<NEDGE / 1024, 256, 0, stream>>>(xF, idxb, W1f, SC(1), SH(1), W2f, st);
  fin_k<<<1, 256, 0, stream>>>(st, G(2), Bt(2), SC(2), SH(2), 64, 1.0 / NEDGE);
  e1c_k<<<NPTS / 4, 256, 0, stream>>>(xF, idxb, W1f, SC(1), SH(1), W2f, SC(2), SH(2), x1);

  // ---- knn on x1: barrier-free MFMA split-bf16 screen + exact f64 rescore ----
  xx_k<<<NPTS, 64, 0, stream>>>(x1, xx, xxfb);
  xsplit_k<<<NPTS * 64 / 256, 256, 0, stream>>>(x1, Xhi, Xlo);
  knnsm_k<<<dim3(NN / 16, BB), 256, 0, stream>>>(Xhi, Xlo, xxfb, pcand);
  resc_k<<<NPTS / 4, 256, 0, stream>>>(x1, xx, pcand, idxb);

  // ---- stage 2 ----
  zero_k<<<8, 256, 0, stream>>>(st, 2048);
  e2a_k<<<NEDGE / 1024, 256, 0, stream>>>(x1, idxb, W3f, st);
  fin_k<<<1, 256, 0, stream>>>(st, G(3), Bt(3), SC(3), SH(3), 64, 1.0 / NEDGE);
  zero_k<<<8, 256, 0, stream>>>(st, 2048);
  e2b_k<<<NEDGE / 1024, 256, 0, stream>>>(x1, idxb, W3f, SC(3), SH(3), W4f, st);
  fin_k<<<1, 256, 0, stream>>>(st, G(4), Bt(4), SC(4), SH(4), 64, 1.0 / NEDGE);
  e2c_k<<<NPTS / 2, 256, 0, stream>>>(x1, idxb, W3f, SC(3), SH(3), W4f, SC(4), SH(4), x2);

  // ---- knn on x2: barrier-free MFMA split-bf16 screen + exact f64 rescore ----
  xx_k<<<NPTS, 64, 0, stream>>>(x2, xx, xxfb);
  xsplit_k<<<NPTS * 64 / 256, 256, 0, stream>>>(x2, Xhi, Xlo);
  knnsm_k<<<dim3(NN / 16, BB), 256, 0, stream>>>(Xhi, Xlo, xxfb, pcand);
  resc_k<<<NPTS / 4, 256, 0, stream>>>(x2, xx, pcand, idxb);

  // ---- stage 3 ----
  zero_k<<<8, 256, 0, stream>>>(st, 2048);
  e2a_k<<<NEDGE / 1024, 256, 0, stream>>>(x2, idxb, W5f, st);
  fin_k<<<1, 256, 0, stream>>>(st, G(5), Bt(5), SC(5), SH(5), 64, 1.0 / NEDGE);
  e3c_k<<<NPTS / 4, 256, 0, stream>>>(x2, idxb, W5f, SC(5), SH(5), x3);

  // ---- point pipeline ----
  zero_k<<<8, 256, 0, stream>>>(st, 2048);
  g6stats_k<<<dim3(NPTS / 64, 16), 256, 0, stream>>>(x1, x2, x3, W6f, st, gpmax, gpmin);
  fin_k<<<4, 256, 0, stream>>>(st, G(6), Bt(6), SC(6), SH(6), 1024, 1.0 / NPTS);
  gmax_red2_k<<<dim3(BB, 4), 256, 0, stream>>>(gpmax, gpmin, SC(6), SH(6), gm);

  gw_k<<<16, 256, 0, stream>>>(gm, W7f, gW);
  zero_k<<<8, 256, 0, stream>>>(st, 2048);
  if (h7f32) {
    g7stats_k<1><<<dim3(NPTS / 64, 8), 256, 0, stream>>>(x1, x2, x3, W7r, gW, h7, st);
  } else {
    g7stats_k<0><<<dim3(NPTS / 64, 8), 256, 0, stream>>>(x1, x2, x3, W7r, gW, h7, st);
  }
  fin_k<<<2, 256, 0, stream>>>(st, G(7), Bt(7), SC(7), SH(7), 512, 1.0 / NPTS);

  zero_k<<<8, 256, 0, stream>>>(st, 2048);
  if (h7f32) {
    gstats_k<4, 0, 1><<<dim3(NPTS / 64, 4), 256, 0, stream>>>(
        h7, W8f, 512, 256, nullptr, nullptr, nullptr, nullptr, SC(7), SH(7), nullptr, st);
  } else {
    gstats_k<4, 0, 0><<<dim3(NPTS / 64, 4), 256, 0, stream>>>(
        h7, W8f, 512, 256, nullptr, nullptr, nullptr, nullptr, SC(7), SH(7), nullptr, st);
  }
  fin_k<<<1, 256, 0, stream>>>(st, G(8), Bt(8), SC(8), SH(8), 256, 1.0 / NPTS);

  if (h7f32) {
    final_k<1><<<NPTS / 64, 256, 0, stream>>>(h7, SC(7), SH(7), W8f, SC(8), SH(8), W9f,
                                              d_out, flag);
  } else {
    final_k<0><<<NPTS / 64, 256, 0, stream>>>(h7, SC(7), SH(7), W8f, SC(8), SH(8), W9f,
                                              d_out, flag);
  }
}

// Round 16
// 3788.459 us; speedup vs baseline: 1.1194x; 1.1194x over previous
//
#include <hip/hip_runtime.h>
#include <hip/hip_bf16.h>

#define BB 8
#define NN 4096
#define KNN 20
#define NPTS (BB*NN)          // 32768
#define NEDGE (NPTS*KNN)      // 655360
#define TKCAP 12
#define LKN 12                // per-lane screen top-K (recall: Binom(19,1/16) >= 12 is ~2e-10)
#define SKN 24                // per-wave merged top-K (>= 19 possible better + slack)
#define FKN 48                // final screened candidates per query (rescored exactly)

typedef unsigned short u16;
typedef unsigned long long u64;
typedef __attribute__((ext_vector_type(8))) short s8v;   // 8 bf16 (4 VGPRs)
typedef __attribute__((ext_vector_type(4))) float f4v;

__device__ __forceinline__ float bf2f(u16 u) {
    return __uint_as_float(((unsigned)u) << 16);
}
__device__ __forceinline__ u16 f2bf_rne(float f) {
  unsigned u = __float_as_uint(f);
  unsigned rb = (u >> 16) & 1;
  u += 0x7FFFu + rb;
  return (u16)(u >> 16);
}
__device__ __forceinline__ float lrelu(float v) { return v > 0.f ? v : 0.2f * v; }
__device__ __forceinline__ double lrelu64(double v) { return v > 0.0 ? v : 0.2 * v; }

// ---- sortable (value,index) packed key (f64): descending value, ties -> lower index ----
__device__ __forceinline__ u64 dkey(double v, int j) {
  u64 u = (u64)__double_as_longlong(v);
  u = (u >> 63) ? ~u : (u | 0x8000000000000000ull);
  return (u & ~0xFFFull) | (u64)(4095 - j);
}

// ---- sortable (value,index) packed key (f32 screen): full f32 bits + 12-bit index ----
__device__ __forceinline__ u64 skey(float v, int j) {
  unsigned s = __float_as_uint(v);
  s = (s >> 31) ? ~s : (s | 0x80000000u);
  return ((u64)s << 12) | (u64)(4095 - j);
}

// ---- generic register top-N insertion (static indices after unroll) ----
template <int N>
__device__ __forceinline__ void tk_insert(u64* bk, u64 k) {
  if (k > bk[N - 1]) {
    bk[N - 1] = k;
#pragma unroll
    for (int p = N - 1; p > 0; --p) {
      if (bk[p] > bk[p - 1]) { u64 tv = bk[p]; bk[p] = bk[p - 1]; bk[p - 1] = tv; }
    }
  }
}

// ---- top-20 insertion on packed u64 keys (macro form used by knn1p/tmerge) ----
#define TOPK_INIT() \
  u64 bk[KNN]; \
  _Pragma("unroll") for (int p_ = 0; p_ < KNN; ++p_) bk[p_] = 0ull;

#define TOPK_INSERT(kk) do { \
    u64 k_ = (kk); \
    if (k_ > bk[KNN-1]) { \
      bk[KNN-1] = k_; \
      _Pragma("unroll") \
      for (int p_ = KNN-1; p_ > 0; --p_) { \
        if (bk[p_] > bk[p_-1]) { u64 tv_ = bk[p_]; bk[p_] = bk[p_-1]; bk[p_-1] = tv_; } \
      } \
    } \
  } while (0)

#define TKBUF_DECL() \
  u64 thr_ = 0ull; u64 cb_[TKCAP]; int cnt_ = 0;
#define TKBUF_PUSH(kk) do { \
    u64 k__ = (kk); \
    if (k__ > thr_) { cb_[cnt_] = k__; ++cnt_; } \
  } while (0)
#define TKBUF_FLUSH() do { \
    for (int l_ = 0; l_ < cnt_; ++l_) TOPK_INSERT(cb_[l_]); \
    cnt_ = 0; thr_ = bk[KNN-1]; \
  } while (0)

// =================== dtype detect + canonicalize to f32 ===================
__global__ void det_k(const void* __restrict__ g1raw, int* __restrict__ flag) {
  const u16* u = (const u16*)g1raw;
  flag[0] = (u[0] == 0x3F80) ? 1 : 0;
}

__global__ __launch_bounds__(256) void conv_k(const void* __restrict__ src,
                                              float* __restrict__ dst, int n,
                                              const int* __restrict__ flag) {
  const int mode = flag[0];
  int i = blockIdx.x * 256 + threadIdx.x;
  const int stride = gridDim.x * 256;
  if (mode) {
    const u16* s = (const u16*)src;
    for (; i < n; i += stride) dst[i] = bf2f(s[i]);
  } else {
    const float* s = (const float*)src;
    for (; i < n; i += stride) dst[i] = s[i];
  }
}

__global__ void zero_k(double* __restrict__ p, int n) {
  int i = blockIdx.x * 256 + threadIdx.x;
  if (i < n) p[i] = 0.0;
}

// =========== knn on raw 3-D points — j-split partials, packed u64 keys ===========
__global__ __launch_bounds__(256) void knn1p_k(const float* __restrict__ x,
                                               u64* __restrict__ pkey) {
  __shared__ float sx[1024], sy[1024], sz[1024];
  __shared__ double sq[1024];
  const int b = blockIdx.x, t = threadIdx.x, seg = blockIdx.z;
  const int j0 = seg * 1024;
  const float* xb = x + b * 3 * NN;
  const int i = blockIdx.y * 256 + t;
  const double px = (double)xb[i], py = (double)xb[NN + i], pz = (double)xb[2 * NN + i];
  const double q = px * px + py * py + pz * pz;
  for (int l = t; l < 1024; l += 256) {
    float jx = xb[j0 + l], jy = xb[NN + j0 + l], jz = xb[2 * NN + j0 + l];
    sx[l] = jx; sy[l] = jy; sz[l] = jz;
    double jxd = jx, jyd = jy, jzd = jz;
    sq[l] = jxd * jxd + jyd * jyd + jzd * jzd;
  }
  __syncthreads();
  TOPK_INIT();
  TKBUF_DECL();
  for (int j = 0; j < 1024; j += 4) {
    double i0 = px * (double)sx[j + 0] + py * (double)sy[j + 0] + pz * (double)sz[j + 0];
    double i1 = px * (double)sx[j + 1] + py * (double)sy[j + 1] + pz * (double)sz[j + 1];
    double i2 = px * (double)sx[j + 2] + py * (double)sy[j + 2] + pz * (double)sz[j + 2];
    double i3 = px * (double)sx[j + 3] + py * (double)sy[j + 3] + pz * (double)sz[j + 3];
    double v0 = (2.0 * i0 - q) - sq[j + 0];
    double v1 = (2.0 * i1 - q) - sq[j + 1];
    double v2 = (2.0 * i2 - q) - sq[j + 2];
    double v3 = (2.0 * i3 - q) - sq[j + 3];
    TKBUF_PUSH(dkey(v0, j0 + j + 0));
    TKBUF_PUSH(dkey(v1, j0 + j + 1));
    TKBUF_PUSH(dkey(v2, j0 + j + 2));
    TKBUF_PUSH(dkey(v3, j0 + j + 3));
    if (__ballot(cnt_ >= TKCAP - 3)) TKBUF_FLUSH();
  }
  TKBUF_FLUSH();
  const size_t base = ((size_t)seg * NPTS + (b * NN + i)) * KNN;
#pragma unroll
  for (int p = 0; p < KNN; ++p) pkey[base + p] = bk[p];
}

// =================== merge 4 partial top-20 key lists -> final indices ===================
__global__ __launch_bounds__(256) void tmerge_k(const u64* __restrict__ pkey,
                                                int* __restrict__ idx) {
  const int pt = blockIdx.x * 256 + threadIdx.x;
  TOPK_INIT();
  for (int seg = 0; seg < 4; ++seg) {
    const size_t base = ((size_t)seg * NPTS + pt) * KNN;
#pragma unroll
    for (int p = 0; p < KNN; ++p) TOPK_INSERT(pkey[base + p]);
  }
  int* op = idx + (size_t)pt * KNN;
#pragma unroll
  for (int p = 0; p < KNN; ++p) op[p] = 4095 - (int)(bk[p] & 0xFFFull);
}

// ==== split f32 features into bf16 hi + bf16 lo (screen operands) ====
__global__ __launch_bounds__(256) void xsplit_k(const float* __restrict__ xp,
                                                u16* __restrict__ Xhi,
                                                u16* __restrict__ Xlo) {
  int i = blockIdx.x * 256 + threadIdx.x;   // NPTS*64 elements
  float x = xp[i];
  u16 h = f2bf_rne(x);
  Xhi[i] = h;
  Xlo[i] = f2bf_rne(x - bf2f(h));
}

// ====== MFMA split-bf16 SCREEN knn v5: per-lane top-12 -> wave top-24 -> top-48 ======
// grid (NN/16, BB), 256 thr = 4 waves. Block = 16 queries x ALL 4096 j; wave w owns
// j in [w*1024, w*1024+1024). Lane l holds score(j=jloc+(l>>4)*4+r, q=i0+(l&15)) in reg.
// Per-lane top-12 suffices for recall: a true top-20 item has <=19 better globally ->
// in-lane count ~ Binom(19,1/16), P(>=12) ~ 2e-10. Wave merge to 24 (>=19+slack, exact).
// LDS: lbuf [8][256] u64 = 16KB (km overlays post-loop). resc_k restores exact f64.
__global__ __launch_bounds__(256) void knnsm_k(const u16* __restrict__ Xhi,
                                               const u16* __restrict__ Xlo,
                                               const float* __restrict__ xxf,
                                               u64* __restrict__ pcand) {
  __shared__ __align__(16) unsigned char smraw[16384];
  u64* lbuf = (u64*)smraw;                    // [8 slots][256 threads] = 16384 B
  u64* km   = (u64*)smraw;                    // [16][97] = 12416 B (post-loop overlay)
  const int t = threadIdx.x;
  const int w = t >> 6, l = t & 63;
  const int b = blockIdx.y;
  const int i0 = blockIdx.x * 16;
  const int gpt0 = b * NN;
  // B fragments (queries), held whole kernel: row = i0 + (l&15); k = kt*32 + (l>>4)*8 + e
  s8v Bhi[2], Blo[2];
#pragma unroll
  for (int kt = 0; kt < 2; ++kt) {
    size_t off = (size_t)(gpt0 + i0 + (l & 15)) * 64 + kt * 32 + ((l >> 4) * 8);
    Bhi[kt] = *(const s8v*)&Xhi[off];
    Blo[kt] = *(const s8v*)&Xlo[off];
  }
  const int q = l & 15, hi = l >> 4;
  const float qif = xxf[gpt0 + i0 + q];
  u64 bk[LKN];
#pragma unroll
  for (int p = 0; p < LKN; ++p) bk[p] = 0ull;
  u64 thr = 0ull; int cnt = 0;
  for (int jt = 0; jt < 64; ++jt) {
    const int jloc = w * 1024 + jt * 16;
    s8v Ahi_[2], Alo_[2];
#pragma unroll
    for (int kt = 0; kt < 2; ++kt) {
      size_t off = (size_t)(gpt0 + jloc + (l & 15)) * 64 + kt * 32 + (hi * 8);
      Ahi_[kt] = *(const s8v*)&Xhi[off];
      Alo_[kt] = *(const s8v*)&Xlo[off];
    }
    f4v acc = {0.f, 0.f, 0.f, 0.f};
#pragma unroll
    for (int kt = 0; kt < 2; ++kt) {
      acc = __builtin_amdgcn_mfma_f32_16x16x32_bf16(Ahi_[kt], Bhi[kt], acc, 0, 0, 0);
      acc = __builtin_amdgcn_mfma_f32_16x16x32_bf16(Ahi_[kt], Blo[kt], acc, 0, 0, 0);
      acc = __builtin_amdgcn_mfma_f32_16x16x32_bf16(Alo_[kt], Bhi[kt], acc, 0, 0, 0);
    }
    // lane's 4 candidates: j = jloc + hi*4 + r, all for its own query q
    float4 qj4 = *(const float4*)&xxf[gpt0 + jloc + hi * 4];   // L2-hot
    const float* qj = (const float*)&qj4;
#pragma unroll
    for (int r = 0; r < 4; ++r) {
      float v = (2.f * acc[r] - qif) - qj[r];
      u64 k0 = skey(v, jloc + hi * 4 + r);
      if (k0 > thr) { lbuf[cnt * 256 + t] = k0; ++cnt; }
    }
    if (__ballot(cnt >= 5)) {
      for (int lf = 0; lf < cnt; ++lf) tk_insert<LKN>(bk, lbuf[lf * 256 + t]);
      cnt = 0; thr = bk[LKN - 1];
    }
  }
  for (int lf = 0; lf < cnt; ++lf) tk_insert<LKN>(bk, lbuf[lf * 256 + t]);
  // expand lane top-12 into wave-merge list (capacity 24)
  u64 wk[SKN];
#pragma unroll
  for (int p = 0; p < LKN; ++p) wk[p] = bk[p];
#pragma unroll
  for (int p = LKN; p < SKN; ++p) wk[p] = 0ull;
  // merge hi-groups: lanes l, l+16, l+32, l+48 hold same query (disjoint j)
#pragma unroll
  for (int p = 0; p < SKN; ++p) {
    u64 o = __shfl_xor((unsigned long long)wk[p], 32);
    if (l < 32) tk_insert<SKN>(wk, o);
  }
#pragma unroll
  for (int p = 0; p < SKN; ++p) {
    u64 o = __shfl_xor((unsigned long long)wk[p], 16);
    if (l < 16) tk_insert<SKN>(wk, o);
  }
  __syncthreads();   // all lbuf reads done before km overlay writes
  if (l < 16) {
#pragma unroll
    for (int p = 0; p < SKN; ++p) km[l * 97 + w * SKN + p] = wk[p];
  }
  __syncthreads();
  // rank-select top-48 of 96 per query (keys unique: disjoint j slices; all 96 real:
  // each wave list merged 48 real candidates into 24)
  {
    const int qq = t & 15, g = t >> 4;   // 16 groups x 6 candidates
    const size_t pb = (size_t)(gpt0 + i0 + qq) * FKN;
    for (int cc = 0; cc < 6; ++cc) {
      u64 mine = km[qq * 97 + g * 6 + cc];
      int rank = 0;
      for (int o = 0; o < 96; ++o) rank += (km[qq * 97 + o] > mine) ? 1 : 0;
      if (rank < FKN) pcand[pb + rank] = mine;
    }
  }
}

// ============ exact f64 rescore of 48 screened candidates -> final top-20 idx ============
__global__ __launch_bounds__(256) void resc_k(const float* __restrict__ xp,
                                              const double* __restrict__ xx,
                                              const u64* __restrict__ pcand,
                                              int* __restrict__ idx) {
  __shared__ float xis[4][64];
  __shared__ u64 keys[4][FKN];
  const int t = threadIdx.x;
  const int w = t >> 6, lane = t & 63;
  const int pt = blockIdx.x * 4 + w;
  const int b12 = pt & ~(NN - 1);
  xis[w][lane] = xp[(size_t)pt * 64 + lane];
  const double q = xx[pt];
  if (lane < FKN) {
    u64 sk = pcand[(size_t)pt * FKN + lane];
    int j = 4095 - (int)(sk & 0xFFFull);
    const float* xj = xp + ((size_t)b12 + j) * 64;
    double a0 = 0.0, a1 = 0.0, a2 = 0.0, a3 = 0.0;
#pragma unroll
    for (int d = 0; d < 16; ++d) {
      a0 += (double)xis[w][d] * (double)xj[d];
      a1 += (double)xis[w][16 + d] * (double)xj[16 + d];
      a2 += (double)xis[w][32 + d] * (double)xj[32 + d];
      a3 += (double)xis[w][48 + d] * (double)xj[48 + d];
    }
    double v = (2.0 * ((a0 + a1) + (a2 + a3)) - q) - xx[b12 + j];
    keys[w][lane] = dkey(v, j);
  }
  if (lane < FKN) {
    u64 mine = keys[w][lane];
    int rank = 0;
    for (int o = 0; o < FKN; ++o) rank += (keys[w][o] > mine) ? 1 : 0;
    if (rank < KNN) idx[(size_t)pt * KNN + rank] = 4095 - (int)(mine & 0xFFFull);
  }
}

// =================== moments of the 6-D edge feature (tiled: 2048 edges/block) ==============
__global__ __launch_bounds__(256) void f1mom_k(const float* __restrict__ x,
                                               const int* __restrict__ idx,
                                               double* __restrict__ stm) {
  __shared__ float red[27][257];
  const int t = threadIdx.x;
  float a[27];
#pragma unroll
  for (int m = 0; m < 27; ++m) a[m] = 0.f;
  for (int r = 0; r < 8; ++r) {
    int e = blockIdx.x * 2048 + r * 256 + t;
    int pt = e / KNN;
    int b = pt >> 12, i = pt & (NN - 1);
    int j = idx[e] & (NN - 1);
    const float* xb = x + b * 3 * NN;
    float xi0 = xb[i], xi1 = xb[NN + i], xi2 = xb[2 * NN + i];
    float f[6];
    f[0] = xb[j] - xi0; f[1] = xb[NN + j] - xi1; f[2] = xb[2 * NN + j] - xi2;
    f[3] = xi0; f[4] = xi1; f[5] = xi2;
#pragma unroll
    for (int d = 0; d < 6; ++d) a[d] += f[d];
    int k = 6;
#pragma unroll
    for (int aa = 0; aa < 6; ++aa)
#pragma unroll
      for (int bb2 = aa; bb2 < 6; ++bb2) a[k++] += f[aa] * f[bb2];
  }
#pragma unroll
  for (int m = 0; m < 27; ++m) red[m][t] = a[m];
  __syncthreads();
  if (t < 27) {
    double s = 0.0;
    for (int l = 0; l < 256; ++l) s += (double)red[t][l];
    atomicAdd(&stm[t], s);
  }
}

__global__ void fin1_k(const double* __restrict__ stm, const float* __restrict__ W1,
                       const float* __restrict__ g, const float* __restrict__ bet,
                       float* __restrict__ sc, float* __restrict__ sh, double invM) {
  int c = threadIdx.x;
  if (c >= 64) return;
  double w[6];
  for (int d = 0; d < 6; ++d) w[d] = (double)W1[c * 6 + d];
  double mean = 0.0;
  for (int d = 0; d < 6; ++d) mean += w[d] * stm[d];
  mean *= invM;
  double e2 = 0.0;
  int k = 6;
  for (int a = 0; a < 6; ++a)
    for (int b = a; b < 6; ++b) {
      double m2 = stm[k++];
      e2 += w[a] * w[b] * m2 * (a == b ? 1.0 : 2.0);
    }
  e2 *= invM;
  double var = e2 - mean * mean;
  if (!(var > 0.0)) var = 0.0;
  double scale = (double)g[c] / sqrt(var + 1e-5);
  sc[c] = (float)scale;
  sh[c] = (float)((double)bet[c] - mean * scale);
}

__global__ void fin_k(const double* __restrict__ st, const float* __restrict__ g,
                      const float* __restrict__ bet, float* __restrict__ sc,
                      float* __restrict__ sh, int C, double invM) {
  int c = blockIdx.x * 256 + threadIdx.x;
  if (c >= C) return;
  double mean = st[c] * invM;
  double var = st[1024 + c] * invM - mean * mean;
  if (!(var > 0.0)) var = 0.0;
  double scale = (double)g[c] / sqrt(var + 1e-5);
  sc[c] = (float)scale;
  sh[c] = (float)((double)bet[c] - mean * scale);
}

// ===== stage-1: h2 stats as tile-GEMM (f6 -> h1 -> BN -> h2 col-stats), 16 tiles/block ======
__global__ __launch_bounds__(256) void e1b_k(const float* __restrict__ x, const int* __restrict__ idx,
    const float* __restrict__ W1, const float* __restrict__ sc1, const float* __restrict__ sh1,
    const float* __restrict__ W2, double* __restrict__ st) {
  __shared__ float f6[64][9];
  __shared__ float W1s[64][8];
  __shared__ float H1[64][68];
  __shared__ float W2s[64][68];
  __shared__ double rPd[16][68];
  const int t = threadIdx.x;
  const int tx = t & 15, ty = t >> 4;
  for (int l = t; l < 384; l += 256) W1s[l / 6][l % 6] = W1[l];
  for (int l = t; l < 4096; l += 256) W2s[l & 63][l >> 6] = W2[l];
  double sL[4], qL[4];
#pragma unroll
  for (int j = 0; j < 4; ++j) { sL[j] = 0.0; qL[j] = 0.0; }
  for (int tile = 0; tile < 16; ++tile) {
    const int e0 = (blockIdx.x * 16 + tile) * 64;
    __syncthreads();
    if (t < 64) {
      int e = e0 + t;
      int pt = e / KNN;
      int b = pt >> 12, i = pt & (NN - 1);
      int j = idx[e] & (NN - 1);
      const float* xb = x + b * 3 * NN;
      float xi0 = xb[i], xi1 = xb[NN + i], xi2 = xb[2 * NN + i];
      f6[t][0] = xb[j] - xi0; f6[t][1] = xb[NN + j] - xi1; f6[t][2] = xb[2 * NN + j] - xi2;
      f6[t][3] = xi0; f6[t][4] = xi1; f6[t][5] = xi2;
    }
    __syncthreads();
    float acc1[4][4];
#pragma unroll
    for (int i = 0; i < 4; ++i)
#pragma unroll
      for (int j = 0; j < 4; ++j) acc1[i][j] = 0.f;
#pragma unroll
    for (int d = 0; d < 6; ++d) {
      float av[4], bv2[4];
#pragma unroll
      for (int i = 0; i < 4; ++i) av[i] = f6[ty * 4 + i][d];
#pragma unroll
      for (int j = 0; j < 4; ++j) bv2[j] = W1s[tx * 4 + j][d];
#pragma unroll
      for (int i = 0; i < 4; ++i)
#pragma unroll
        for (int j = 0; j < 4; ++j) acc1[i][j] = fmaf(av[i], bv2[j], acc1[i][j]);
    }
#pragma unroll
    for (int j = 0; j < 4; ++j) {
      int c = tx * 4 + j;
      float s1 = sc1[c], b1 = sh1[c];
#pragma unroll
      for (int i = 0; i < 4; ++i)
        H1[c][ty * 4 + i] = lrelu(fmaf(s1, acc1[i][j], b1));
    }
    __syncthreads();
    float acc2[4][4];
#pragma unroll
    for (int i = 0; i < 4; ++i)
#pragma unroll
      for (int j = 0; j < 4; ++j) acc2[i][j] = 0.f;
    for (int k = 0; k < 64; ++k) {
      float4 a4 = *(const float4*)&H1[k][ty * 4];
      float4 b4 = *(const float4*)&W2s[k][tx * 4];
      const float* aa = (const float*)&a4;
      const float* bb = (const float*)&b4;
#pragma unroll
      for (int i = 0; i < 4; ++i)
#pragma unroll
        for (int j = 0; j < 4; ++j) acc2[i][j] = fmaf(aa[i], bb[j], acc2[i][j]);
    }
#pragma unroll
    for (int j = 0; j < 4; ++j) {
      sL[j] += (double)acc2[0][j] + (double)acc2[1][j] + (double)acc2[2][j] + (double)acc2[3][j];
      qL[j] += (double)acc2[0][j] * (double)acc2[0][j] + (double)acc2[1][j] * (double)acc2[1][j]
             + (double)acc2[2][j] * (double)acc2[2][j] + (double)acc2[3][j] * (double)acc2[3][j];
    }
  }
  __syncthreads();
#pragma unroll
  for (int j = 0; j < 4; ++j) rPd[ty][tx * 4 + j] = sL[j];
  __syncthreads();
  if (t < 64) {
    double s = 0.0;
#pragma unroll
    for (int w = 0; w < 16; ++w) s += rPd[w][t];
    atomicAdd(&st[t], s);
  }
  __syncthreads();
#pragma unroll
  for (int j = 0; j < 4; ++j) rPd[ty][tx * 4 + j] = qL[j];
  __syncthreads();
  if (t < 64) {
    double s = 0.0;
#pragma unroll
    for (int w = 0; w < 16; ++w) s += rPd[w][t];
    atomicAdd(&st[1024 + t], s);
  }
}

// =================== stage-1 final: f32 compute -> x1 (f32), float4 LDS reads ===================
__global__ __launch_bounds__(256) void e1c_k(const float* __restrict__ x, const int* __restrict__ idx,
    const float* __restrict__ W1, const float* __restrict__ sc1, const float* __restrict__ sh1,
    const float* __restrict__ W2, const float* __restrict__ sc2, const float* __restrict__ sh2,
    float* __restrict__ x1out) {
  __shared__ float f6[80][9];
  __shared__ float h1s[80][68];   // stride 68 floats = 272 B (16B-aligned rows)
  const int t = threadIdx.x;
  const int p0 = blockIdx.x * 4;
  if (t < 80) {
    int e = p0 * KNN + t;
    int pt = e / KNN;
    int b = pt >> 12, i = pt & (NN - 1);
    int j = idx[e] & (NN - 1);
    const float* xb = x + b * 3 * NN;
    float xi0 = xb[i], xi1 = xb[NN + i], xi2 = xb[2 * NN + i];
    f6[t][0] = xb[j] - xi0; f6[t][1] = xb[NN + j] - xi1; f6[t][2] = xb[2 * NN + j] - xi2;
    f6[t][3] = xi0; f6[t][4] = xi1; f6[t][5] = xi2;
  }
  __syncthreads();
  const int c = t & 63;
  const int g4 = t >> 6;
  float w1[6];
#pragma unroll
  for (int d = 0; d < 6; ++d) w1[d] = W1[c * 6 + d];
  const float s1 = sc1[c], b1 = sh1[c];
  {
    float hk[20];
#pragma unroll
    for (int k = 0; k < 20; ++k) hk[k] = 0.f;
#pragma unroll
    for (int d = 0; d < 6; ++d) {
      float w1d = w1[d];
#pragma unroll
      for (int k = 0; k < 20; ++k) hk[k] = fmaf(f6[g4 + k * 4][d], w1d, hk[k]);
    }
#pragma unroll
    for (int k = 0; k < 20; ++k)
      h1s[g4 + k * 4][c] = lrelu(fmaf(s1, hk[k], b1));
  }
  __syncthreads();
  const float s2 = sc2[c], b2 = sh2[c];
  float acc[20];
#pragma unroll
  for (int k = 0; k < 20; ++k) acc[k] = 0.f;
  for (int d0 = 0; d0 < 64; d0 += 4) {
    float4 wv = *(const float4*)&W2[c * 64 + d0];
#pragma unroll
    for (int k = 0; k < 20; ++k) {
      float4 hv = *(const float4*)&h1s[g4 * 20 + k][d0];
      acc[k] = fmaf(hv.x, wv.x, acc[k]);
      acc[k] = fmaf(hv.y, wv.y, acc[k]);
      acc[k] = fmaf(hv.z, wv.z, acc[k]);
      acc[k] = fmaf(hv.w, wv.w, acc[k]);
    }
  }
  float m = -3.4e38f;
#pragma unroll
  for (int k = 0; k < 20; ++k) {
    float v = lrelu(fmaf(s2, acc[k], b2));
    m = fmaxf(m, v);
  }
  x1out[(p0 + g4) * 64 + c] = m;
}

// =================== squared norms (f64 + f32 copy for screen) ===================
__global__ void xx_k(const float* __restrict__ Xp, double* __restrict__ xx,
                     float* __restrict__ xxf) {
  const int row = blockIdx.x;
  float v = Xp[(size_t)row * 64 + threadIdx.x];
  double s = (double)v * (double)v;
#pragma unroll
  for (int o = 32; o > 0; o >>= 1) s += __shfl_down(s, o, 64);
  if (threadIdx.x == 0) { xx[row] = s; xxf[row] = (float)s; }
}

// ===== gathered-feature stats as tile-GEMM: col-stats of [xj-xi|xi] x W^T, 16 tiles/block ====
__global__ __launch_bounds__(256) void e2a_k(const float* __restrict__ xp,
                                             const int* __restrict__ idx,
                                             const float* __restrict__ W,
                                             double* __restrict__ st) {
  __shared__ float As[16][68];
  __shared__ float Ws[16][68];
  __shared__ double rPd[16][68];
  const int t = threadIdx.x;
  const int tx = t & 15, ty = t >> 4;
  const int lm = t >> 2, lk = (t & 3) * 4;
  double sL[4], qL[4];
#pragma unroll
  for (int j = 0; j < 4; ++j) { sL[j] = 0.0; qL[j] = 0.0; }
  for (int tile = 0; tile < 16; ++tile) {
    const int m0 = (blockIdx.x * 16 + tile) * 64;
    const int e = m0 + lm;
    const int grow = e / KNN;
    const int gj = ((grow >> 12) << 12) + (idx[e] & (NN - 1));
    float acc[4][4];
#pragma unroll
    for (int i = 0; i < 4; ++i)
#pragma unroll
      for (int j = 0; j < 4; ++j) acc[i][j] = 0.f;
    for (int k0 = 0; k0 < 128; k0 += 16) {
      const int c = k0 + lk;
      float4 a;
      if (c < 64) {
        float4 fj = *(const float4*)&xp[(size_t)gj * 64 + c];
        float4 fi = *(const float4*)&xp[(size_t)grow * 64 + c];
        a = make_float4(fj.x - fi.x, fj.y - fi.y, fj.z - fi.z, fj.w - fi.w);
      } else {
        a = *(const float4*)&xp[(size_t)grow * 64 + (c - 64)];
      }
      As[lk + 0][lm] = a.x; As[lk + 1][lm] = a.y;
      As[lk + 2][lm] = a.z; As[lk + 3][lm] = a.w;
      float4 wv = *(const float4*)&W[(size_t)lm * 128 + c];
      Ws[lk + 0][lm] = wv.x; Ws[lk + 1][lm] = wv.y;
      Ws[lk + 2][lm] = wv.z; Ws[lk + 3][lm] = wv.w;
      __syncthreads();
#pragma unroll
      for (int kk = 0; kk < 16; ++kk) {
        float4 a4 = *(const float4*)&As[kk][ty * 4];
        float4 b4 = *(const float4*)&Ws[kk][tx * 4];
        const float* aa = (const float*)&a4;
        const float* bb = (const float*)&b4;
#pragma unroll
        for (int i = 0; i < 4; ++i)
#pragma unroll
          for (int j = 0; j < 4; ++j)
            acc[i][j] = fmaf(aa[i], bb[j], acc[i][j]);
      }
      __syncthreads();
    }
#pragma unroll
    for (int j = 0; j < 4; ++j) {
      sL[j] += (double)acc[0][j] + (double)acc[1][j] + (double)acc[2][j] + (double)acc[3][j];
      qL[j] += (double)acc[0][j] * (double)acc[0][j] + (double)acc[1][j] * (double)acc[1][j]
             + (double)acc[2][j] * (double)acc[2][j] + (double)acc[3][j] * (double)acc[3][j];
    }
  }
#pragma unroll
  for (int j = 0; j < 4; ++j) rPd[ty][tx * 4 + j] = sL[j];
  __syncthreads();
  if (t < 64) {
    double s = 0.0;
#pragma unroll
    for (int w = 0; w < 16; ++w) s += rPd[w][t];
    atomicAdd(&st[t], s);
  }
  __syncthreads();
#pragma unroll
  for (int j = 0; j < 4; ++j) rPd[ty][tx * 4 + j] = qL[j];
  __syncthreads();
  if (t < 64) {
    double s = 0.0;
#pragma unroll
    for (int w = 0; w < 16; ++w) s += rPd[w][t];
    atomicAdd(&st[1024 + t], s);
  }
}

// ===== stage-2: h4 stats as chained tile-GEMM (gather->h3->BN->h4 col-stats) =====
__global__ __launch_bounds__(256) void e2b_k(const float* __restrict__ xp,
    const int* __restrict__ idx, const float* __restrict__ W3,
    const float* __restrict__ sc3, const float* __restrict__ sh3,
    const float* __restrict__ W4, double* __restrict__ st) {
  __shared__ float As[16][68];
  __shared__ float Ws[16][68];
  __shared__ float H3[64][68];
  __shared__ float W4s[64][68];
  __shared__ double rPd[16][68];
  const int t = threadIdx.x;
  const int tx = t & 15, ty = t >> 4;
  const int lm = t >> 2, lk = (t & 3) * 4;
  for (int l = t; l < 4096; l += 256) W4s[l & 63][l >> 6] = W4[l];
  double sL[4], qL[4];
#pragma unroll
  for (int j = 0; j < 4; ++j) { sL[j] = 0.0; qL[j] = 0.0; }
  for (int tile = 0; tile < 16; ++tile) {
    const int m0 = (blockIdx.x * 16 + tile) * 64;
    const int e = m0 + lm;
    const int grow = e / KNN;
    const int gj = ((grow >> 12) << 12) + (idx[e] & (NN - 1));
    float acc1[4][4];
#pragma unroll
    for (int i = 0; i < 4; ++i)
#pragma unroll
      for (int j = 0; j < 4; ++j) acc1[i][j] = 0.f;
    for (int k0 = 0; k0 < 128; k0 += 16) {
      const int c = k0 + lk;
      float4 a;
      if (c < 64) {
        float4 fj = *(const float4*)&xp[(size_t)gj * 64 + c];
        float4 fi = *(const float4*)&xp[(size_t)grow * 64 + c];
        a = make_float4(fj.x - fi.x, fj.y - fi.y, fj.z - fi.z, fj.w - fi.w);
      } else {
        a = *(const float4*)&xp[(size_t)grow * 64 + (c - 64)];
      }
      As[lk + 0][lm] = a.x; As[lk + 1][lm] = a.y;
      As[lk + 2][lm] = a.z; As[lk + 3][lm] = a.w;
      float4 wv = *(const float4*)&W3[(size_t)lm * 128 + c];
      Ws[lk + 0][lm] = wv.x; Ws[lk + 1][lm] = wv.y;
      Ws[lk + 2][lm] = wv.z; Ws[lk + 3][lm] = wv.w;
      __syncthreads();
#pragma unroll
      for (int kk = 0; kk < 16; ++kk) {
        float4 a4 = *(const float4*)&As[kk][ty * 4];
        float4 b4 = *(const float4*)&Ws[kk][tx * 4];
        const float* aa = (const float*)&a4;
        const float* bb = (const float*)&b4;
#pragma unroll
        for (int i = 0; i < 4; ++i)
#pragma unroll
          for (int j = 0; j < 4; ++j)
            acc1[i][j] = fmaf(aa[i], bb[j], acc1[i][j]);
      }
      __syncthreads();
    }
#pragma unroll
    for (int j = 0; j < 4; ++j) {
      int c = tx * 4 + j;
      float s3 = sc3[c], b3 = sh3[c];
#pragma unroll
      for (int i = 0; i < 4; ++i)
        H3[c][ty * 4 + i] = lrelu(fmaf(s3, acc1[i][j], b3));
    }
    __syncthreads();
    float acc2[4][4];
#pragma unroll
    for (int i = 0; i < 4; ++i)
#pragma unroll
      for (int j = 0; j < 4; ++j) acc2[i][j] = 0.f;
    for (int k = 0; k < 64; ++k) {
      float4 a4 = *(const float4*)&H3[k][ty * 4];
      float4 b4 = *(const float4*)&W4s[k][tx * 4];
      const float* aa = (const float*)&a4;
      const float* bb = (const float*)&b4;
#pragma unroll
      for (int i = 0; i < 4; ++i)
#pragma unroll
        for (int j = 0; j < 4; ++j) acc2[i][j] = fmaf(aa[i], bb[j], acc2[i][j]);
    }
    __syncthreads();
#pragma unroll
    for (int j = 0; j < 4; ++j) {
      sL[j] += (double)acc2[0][j] + (double)acc2[1][j] + (double)acc2[2][j] + (double)acc2[3][j];
      qL[j] += (double)acc2[0][j] * (double)acc2[0][j] + (double)acc2[1][j] * (double)acc2[1][j]
             + (double)acc2[2][j] * (double)acc2[2][j] + (double)acc2[3][j] * (double)acc2[3][j];
    }
  }
#pragma unroll
  for (int j = 0; j < 4; ++j) rPd[ty][tx * 4 + j] = sL[j];
  __syncthreads();
  if (t < 64) {
    double s = 0.0;
#pragma unroll
    for (int w = 0; w < 16; ++w) s += rPd[w][t];
    atomicAdd(&st[t], s);
  }
  __syncthreads();
#pragma unroll
  for (int j = 0; j < 4; ++j) rPd[ty][tx * 4 + j] = qL[j];
  __syncthreads();
  if (t < 64) {
    double s = 0.0;
#pragma unroll
    for (int w = 0; w < 16; ++w) s += rPd[w][t];
    atomicAdd(&st[1024 + t], s);
  }
}

// ========= stage-2 final: f32 compute -> x2 (f32), ILP-10, float4 LDS reads =========
__global__ __launch_bounds__(256) void e2c_k(const float* __restrict__ xp,
    const int* __restrict__ idx, const float* __restrict__ W3,
    const float* __restrict__ sc3, const float* __restrict__ sh3,
    const float* __restrict__ W4, const float* __restrict__ sc4, const float* __restrict__ sh4,
    float* __restrict__ x2out) {
  __shared__ float fs[40][132];   // stride 132 floats = 528 B (16B-aligned rows)
  __shared__ float h3s[40][68];   // stride 68 floats = 272 B (16B-aligned rows)
  __shared__ float pmax[2][2][64];
  const int t = threadIdx.x;
  const int p0 = blockIdx.x * 2;
  for (int s = 0; s < 5; ++s) {
    int lin = s * 256 + t;
    int e = lin >> 5, v4 = lin & 31;
    int col = v4 * 4;
    int eg = p0 * KNN + e;
    int pt = p0 + e / KNN;
    int jr = ((pt >> 12) << 12) + (idx[eg] & (NN - 1));
    const float* xi = xp + (size_t)pt * 64;
    const float* xj = xp + (size_t)jr * 64;
    float4 a;
    if (col < 64) {
      float4 fj = *(const float4*)&xj[col];
      float4 fi = *(const float4*)&xi[col];
      a = make_float4(fj.x - fi.x, fj.y - fi.y, fj.z - fi.z, fj.w - fi.w);
    } else {
      a = *(const float4*)&xi[col - 64];
    }
    fs[e][col + 0] = a.x; fs[e][col + 1] = a.y; fs[e][col + 2] = a.z; fs[e][col + 3] = a.w;
  }
  __syncthreads();
  const int c = t & 63;
  const int g4 = t >> 6;
  const float s3 = sc3[c], b3 = sh3[c];
  {
    float hk[10];
#pragma unroll
    for (int k = 0; k < 10; ++k) hk[k] = 0.f;
    for (int d0 = 0; d0 < 128; d0 += 4) {
      float4 wv = *(const float4*)&W3[c * 128 + d0];
#pragma unroll
      for (int k = 0; k < 10; ++k) {
        float4 fv = *(const float4*)&fs[g4 + k * 4][d0];
        hk[k] = fmaf(fv.x, wv.x, hk[k]);
        hk[k] = fmaf(fv.y, wv.y, hk[k]);
        hk[k] = fmaf(fv.z, wv.z, hk[k]);
        hk[k] = fmaf(fv.w, wv.w, hk[k]);
      }
    }
#pragma unroll
    for (int k = 0; k < 10; ++k)
      h3s[g4 + k * 4][c] = lrelu(fmaf(s3, hk[k], b3));
  }
  __syncthreads();
  const int point = g4 & 1, khalf = g4 >> 1;
  const float s4 = sc4[c], b4 = sh4[c];
  float acc[10];
#pragma unroll
  for (int k = 0; k < 10; ++k) acc[k] = 0.f;
  for (int d0 = 0; d0 < 64; d0 += 4) {
    float4 wv = *(const float4*)&W4[c * 64 + d0];
#pragma unroll
    for (int k = 0; k < 10; ++k) {
      float4 hv = *(const float4*)&h3s[point * 20 + khalf * 10 + k][d0];
      acc[k] = fmaf(hv.x, wv.x, acc[k]);
      acc[k] = fmaf(hv.y, wv.y, acc[k]);
      acc[k] = fmaf(hv.z, wv.z, acc[k]);
      acc[k] = fmaf(hv.w, wv.w, acc[k]);
    }
  }
  float m = -3.4e38f;
#pragma unroll
  for (int k = 0; k < 10; ++k) {
    float v = lrelu(fmaf(s4, acc[k], b4));
    m = fmaxf(m, v);
  }
  pmax[khalf][point][c] = m;
  __syncthreads();
  if (t < 128) {
    int pp = t >> 6, cc = t & 63;
    x2out[(p0 + pp) * 64 + cc] = fmaxf(pmax[0][pp][cc], pmax[1][pp][cc]);
  }
}

// ========= stage-3 final: f32 (downstream of last knn), float4 LDS reads =========
__global__ __launch_bounds__(256) void e3c_k(const float* __restrict__ xp,
    const int* __restrict__ idx, const float* __restrict__ W5,
    const float* __restrict__ sc5, const float* __restrict__ sh5,
    float* __restrict__ x3out) {
  __shared__ float fs[80][132];   // stride 132 floats = 528 B (16B-aligned rows)
  const int t = threadIdx.x;
  const int p0 = blockIdx.x * 4;
  for (int s = 0; s < 10; ++s) {
    int lin = s * 256 + t;
    int e = lin >> 5, v4 = lin & 31;
    int col = v4 * 4;
    int eg = p0 * KNN + e;
    int pt = p0 + e / KNN;
    int jr = ((pt >> 12) << 12) + (idx[eg] & (NN - 1));
    const float* xi = xp + (size_t)pt * 64;
    const float* xj = xp + (size_t)jr * 64;
    float4 a;
    if (col < 64) {
      float4 fj = *(const float4*)&xj[col];
      float4 fi = *(const float4*)&xi[col];
      a = make_float4(fj.x - fi.x, fj.y - fi.y, fj.z - fi.z, fj.w - fi.w);
    } else {
      a = *(const float4*)&xi[col - 64];
    }
    fs[e][col + 0] = a.x; fs[e][col + 1] = a.y; fs[e][col + 2] = a.z; fs[e][col + 3] = a.w;
  }
  __syncthreads();
  const int c = t & 63;
  const int g4 = t >> 6;
  const float s5 = sc5[c], b5 = sh5[c];
  float acc[20];
#pragma unroll
  for (int k = 0; k < 20; ++k) acc[k] = 0.f;
  for (int d0 = 0; d0 < 128; d0 += 4) {
    float4 wv = *(const float4*)&W5[c * 128 + d0];
#pragma unroll
    for (int k = 0; k < 20; ++k) {
      float4 fv = *(const float4*)&fs[g4 * 20 + k][d0];
      acc[k] += fv.x * wv.x;
      acc[k] += fv.y * wv.y;
      acc[k] += fv.z * wv.z;
      acc[k] += fv.w * wv.w;
    }
  }
  float m = -3.4e38f;
#pragma unroll
  for (int k = 0; k < 20; ++k) m = fmaxf(m, lrelu(s5 * acc[k] + b5));
  x3out[(p0 + g4) * 64 + c] = m;
}

// ==== fused h6 stats + per-column max/min of pre-BN h6 ====
__global__ __launch_bounds__(256) void g6stats_k(
    const float* __restrict__ x1p, const float* __restrict__ x2p,
    const float* __restrict__ x3p, const float* __restrict__ W6,
    double* __restrict__ st, float* __restrict__ gpmax, float* __restrict__ gpmin) {
  __shared__ float As[16][68];
  __shared__ float Ws[16][68];
  __shared__ float rP[16][64];
  const int t = threadIdx.x;
  const int m0 = blockIdx.x * 64, n0 = blockIdx.y * 64;
  const int tx = t & 15, ty = t >> 4;
  const int lm = t >> 2, lk = (t & 3) * 4;
  const int m = m0 + lm, wn = n0 + lm;
  float acc[4][4];
#pragma unroll
  for (int i = 0; i < 4; ++i)
#pragma unroll
    for (int j = 0; j < 4; ++j) acc[i][j] = 0.f;
  for (int k0 = 0; k0 < 192; k0 += 16) {
    const int c = k0 + lk;
    const float* src = (c < 64)  ? &x1p[(size_t)m * 64 + c]
                     : (c < 128) ? &x2p[(size_t)m * 64 + (c - 64)]
                                 : &x3p[(size_t)m * 64 + (c - 128)];
    float4 av = *(const float4*)src;
    As[lk + 0][lm] = av.x; As[lk + 1][lm] = av.y;
    As[lk + 2][lm] = av.z; As[lk + 3][lm] = av.w;
    float4 wv = *(const float4*)&W6[(size_t)wn * 192 + c];
    Ws[lk + 0][lm] = wv.x; Ws[lk + 1][lm] = wv.y;
    Ws[lk + 2][lm] = wv.z; Ws[lk + 3][lm] = wv.w;
    __syncthreads();
#pragma unroll
    for (int kk = 0; kk < 16; ++kk) {
      float4 a4 = *(const float4*)&As[kk][ty * 4];
      float4 b4 = *(const float4*)&Ws[kk][tx * 4];
      const float* aa = (const float*)&a4;
      const float* bb = (const float*)&b4;
#pragma unroll
      for (int i = 0; i < 4; ++i)
#pragma unroll
        for (int j = 0; j < 4; ++j)
          acc[i][j] = fmaf(aa[i], bb[j], acc[i][j]);
    }
    __syncthreads();
  }
#pragma unroll
  for (int j = 0; j < 4; ++j)
    rP[ty][tx * 4 + j] = acc[0][j] + acc[1][j] + acc[2][j] + acc[3][j];
  __syncthreads();
  if (t < 64) {
    float ssum = 0.f;
#pragma unroll
    for (int w = 0; w < 16; ++w) ssum += rP[w][t];
    atomicAdd(&st[n0 + t], (double)ssum);
  }
  __syncthreads();
#pragma unroll
  for (int j = 0; j < 4; ++j)
    rP[ty][tx * 4 + j] = acc[0][j] * acc[0][j] + acc[1][j] * acc[1][j]
                       + acc[2][j] * acc[2][j] + acc[3][j] * acc[3][j];
  __syncthreads();
  if (t < 64) {
    float qsum = 0.f;
#pragma unroll
    for (int w = 0; w < 16; ++w) qsum += rP[w][t];
    atomicAdd(&st[1024 + n0 + t], (double)qsum);
  }
  __syncthreads();
#pragma unroll
  for (int j = 0; j < 4; ++j)
    rP[ty][tx * 4 + j] = fmaxf(fmaxf(acc[0][j], acc[1][j]), fmaxf(acc[2][j], acc[3][j]));
  __syncthreads();
  if (t < 64) {
    float mx = -3.4e38f;
#pragma unroll
    for (int w = 0; w < 16; ++w) mx = fmaxf(mx, rP[w][t]);
    gpmax[(size_t)blockIdx.x * 1024 + n0 + t] = mx;
  }
  __syncthreads();
#pragma unroll
  for (int j = 0; j < 4; ++j)
    rP[ty][tx * 4 + j] = fminf(fminf(acc[0][j], acc[1][j]), fminf(acc[2][j], acc[3][j]));
  __syncthreads();
  if (t < 64) {
    float mn = 3.4e38f;
#pragma unroll
    for (int w = 0; w < 16; ++w) mn = fminf(mn, rP[w][t]);
    gpmin[(size_t)blockIdx.x * 1024 + n0 + t] = mn;
  }
}

__global__ void gmax_red2_k(const float* __restrict__ gpmax, const float* __restrict__ gpmin,
                            const float* __restrict__ sc6, const float* __restrict__ sh6,
                            float* __restrict__ gm) {
  const int b = blockIdx.x;
  const int c = blockIdx.y * 256 + threadIdx.x;
  float mx = -3.4e38f, mn = 3.4e38f;
  for (int rb = 0; rb < 64; ++rb) {
    mx = fmaxf(mx, gpmax[(size_t)(b * 64 + rb) * 1024 + c]);
    mn = fminf(mn, gpmin[(size_t)(b * 64 + rb) * 1024 + c]);
  }
  float s6 = sc6[c], b6 = sh6[c];
  float h = (s6 >= 0.f) ? mx : mn;
  gm[b * 1024 + c] = lrelu(s6 * h + b6);
}

__global__ void wpack_k(const float* __restrict__ W7, float* __restrict__ W7r) {
  int i = blockIdx.x * 256 + threadIdx.x;
  if (i < 512 * 192) {
    int n = i / 192, c = i - n * 192;
    W7r[i] = W7[(size_t)n * 1216 + 1024 + c];
  }
}

__global__ __launch_bounds__(256) void gw_k(const float* __restrict__ gm,
                                            const float* __restrict__ W7,
                                            float* __restrict__ gW) {
  int idx = blockIdx.x * 256 + threadIdx.x;
  int b = idx >> 9, n = idx & 511;
  const float* g = gm + b * 1024;
  const float* w = W7 + (size_t)n * 1216;
  float s0 = 0.f, s1 = 0.f, s2 = 0.f, s3 = 0.f;
  for (int c = 0; c < 1024; c += 4) {
    float4 gv = *(const float4*)&g[c];
    float4 wv = *(const float4*)&w[c];
    s0 = fmaf(gv.x, wv.x, s0); s1 = fmaf(gv.y, wv.y, s1);
    s2 = fmaf(gv.z, wv.z, s2); s3 = fmaf(gv.w, wv.w, s3);
  }
  gW[idx] = (s0 + s1) + (s2 + s3);
}

// ==== h7 = gW + x123 . W7r^T : K=192 GEMM, stats + store ====
template <int H7F32>
__global__ __launch_bounds__(256) void g7stats_k(
    const float* __restrict__ x1p, const float* __restrict__ x2p,
    const float* __restrict__ x3p, const float* __restrict__ W7r,
    const float* __restrict__ gW, void* __restrict__ Hout, double* __restrict__ st) {
  __shared__ float As[16][68];
  __shared__ float Ws[16][68];
  __shared__ float rP[16][64];
  const int t = threadIdx.x;
  const int m0 = blockIdx.x * 64, n0 = blockIdx.y * 64;
  const int tx = t & 15, ty = t >> 4;
  const int lm = t >> 2, lk = (t & 3) * 4;
  const int m = m0 + lm, wn = n0 + lm;
  const int b = m0 >> 12;
  float acc[4][4];
#pragma unroll
  for (int j = 0; j < 4; ++j) {
    float g0 = gW[b * 512 + n0 + tx * 4 + j];
#pragma unroll
    for (int i = 0; i < 4; ++i) acc[i][j] = g0;
  }
  for (int k0 = 0; k0 < 192; k0 += 16) {
    const int c = k0 + lk;
    const float* src = (c < 64)  ? &x1p[(size_t)m * 64 + c]
                     : (c < 128) ? &x2p[(size_t)m * 64 + (c - 64)]
                                 : &x3p[(size_t)m * 64 + (c - 128)];
    float4 av = *(const float4*)src;
    As[lk + 0][lm] = av.x; As[lk + 1][lm] = av.y;
    As[lk + 2][lm] = av.z; As[lk + 3][lm] = av.w;
    float4 wv = *(const float4*)&W7r[(size_t)wn * 192 + c];
    Ws[lk + 0][lm] = wv.x; Ws[lk + 1][lm] = wv.y;
    Ws[lk + 2][lm] = wv.z; Ws[lk + 3][lm] = wv.w;
    __syncthreads();
#pragma unroll
    for (int kk = 0; kk < 16; ++kk) {
      float4 a4 = *(const float4*)&As[kk][ty * 4];
      float4 b4 = *(const float4*)&Ws[kk][tx * 4];
      const float* aa = (const float*)&a4;
      const float* bb = (const float*)&b4;
#pragma unroll
      for (int i = 0; i < 4; ++i)
#pragma unroll
        for (int j = 0; j < 4; ++j)
          acc[i][j] = fmaf(aa[i], bb[j], acc[i][j]);
    }
    __syncthreads();
  }
#pragma unroll
  for (int j = 0; j < 4; ++j)
    rP[ty][tx * 4 + j] = acc[0][j] + acc[1][j] + acc[2][j] + acc[3][j];
  __syncthreads();
  if (t < 64) {
    float ssum = 0.f;
#pragma unroll
    for (int w = 0; w < 16; ++w) ssum += rP[w][t];
    atomicAdd(&st[n0 + t], (double)ssum);
  }
  __syncthreads();
#pragma unroll
  for (int j = 0; j < 4; ++j)
    rP[ty][tx * 4 + j] = acc[0][j] * acc[0][j] + acc[1][j] * acc[1][j]
                       + acc[2][j] * acc[2][j] + acc[3][j] * acc[3][j];
  __syncthreads();
  if (t < 64) {
    float qsum = 0.f;
#pragma unroll
    for (int w = 0; w < 16; ++w) qsum += rP[w][t];
    atomicAdd(&st[1024 + n0 + t], (double)qsum);
  }
#pragma unroll
  for (int i = 0; i < 4; ++i) {
    int r = m0 + ty * 4 + i;
#pragma unroll
    for (int j = 0; j < 4; ++j) {
      if (H7F32)
        ((float*)Hout)[(size_t)r * 512 + n0 + tx * 4 + j] = acc[i][j];
      else
        ((u16*)Hout)[(size_t)r * 512 + n0 + tx * 4 + j] = f2bf_rne(acc[i][j]);
    }
  }
}

// =================== tile GEMM + fused BN-stats (h7 -> h8 stats; AMODE 4 path) ===================
template <int AMODE, int STORE, int H7F32>
__global__ __launch_bounds__(256) void gstats_k(
    const void* __restrict__ Ain, const float* __restrict__ Wp, const int K, const int Nout,
    const float* __restrict__ x1p, const float* __restrict__ x2p,
    const float* __restrict__ x3p, const float* __restrict__ gmp,
    const float* __restrict__ scA, const float* __restrict__ shA,
    void* __restrict__ Hout, double* __restrict__ st) {
  __shared__ float As[16][68];
  __shared__ float Ws[16][68];
  __shared__ float rP[16][64];
  const int t = threadIdx.x;
  const int m0 = blockIdx.x * 64, n0 = blockIdx.y * 64;
  const int tx = t & 15, ty = t >> 4;
  const int lm = t >> 2, lk = (t & 3) * 4;
  const int m = m0 + lm, wn = n0 + lm;
  float acc[4][4];
#pragma unroll
  for (int i = 0; i < 4; ++i)
#pragma unroll
    for (int j = 0; j < 4; ++j) acc[i][j] = 0.f;

  for (int k0 = 0; k0 < K; k0 += 16) {
    const int c = k0 + lk;
    float4 av;
    if (AMODE == 2) {
      const float* src = (c < 64)  ? &x1p[(size_t)m * 64 + c]
                       : (c < 128) ? &x2p[(size_t)m * 64 + (c - 64)]
                                   : &x3p[(size_t)m * 64 + (c - 128)];
      av = *(const float4*)src;
    } else if (AMODE == 3) {
      if (c < 1024) {
        av = *(const float4*)&gmp[(size_t)(m >> 12) * 1024 + c];
      } else {
        int cc = c - 1024;
        const float* src = (cc < 64)  ? &x1p[(size_t)m * 64 + cc]
                         : (cc < 128) ? &x2p[(size_t)m * 64 + (cc - 64)]
                                      : &x3p[(size_t)m * 64 + (cc - 128)];
        av = *(const float4*)src;
      }
    } else {
      if (H7F32) {
        av = *(const float4*)&((const float*)Ain)[(size_t)m * K + c];
      } else {
        ushort4 u4 = *(const ushort4*)&((const u16*)Ain)[(size_t)m * K + c];
        av = make_float4(bf2f(u4.x), bf2f(u4.y), bf2f(u4.z), bf2f(u4.w));
      }
      av.x = lrelu(scA[c + 0] * av.x + shA[c + 0]);
      av.y = lrelu(scA[c + 1] * av.y + shA[c + 1]);
      av.z = lrelu(scA[c + 2] * av.z + shA[c + 2]);
      av.w = lrelu(scA[c + 3] * av.w + shA[c + 3]);
    }
    As[lk + 0][lm] = av.x; As[lk + 1][lm] = av.y;
    As[lk + 2][lm] = av.z; As[lk + 3][lm] = av.w;
    float4 wv = *(const float4*)&Wp[(size_t)wn * K + c];
    Ws[lk + 0][lm] = wv.x; Ws[lk + 1][lm] = wv.y;
    Ws[lk + 2][lm] = wv.z; Ws[lk + 3][lm] = wv.w;
    __syncthreads();
#pragma unroll
    for (int kk = 0; kk < 16; ++kk) {
      float4 a4 = *(const float4*)&As[kk][ty * 4];
      float4 b4 = *(const float4*)&Ws[kk][tx * 4];
      const float* aa = (const float*)&a4;
      const float* bb = (const float*)&b4;
#pragma unroll
      for (int i = 0; i < 4; ++i)
#pragma unroll
        for (int j = 0; j < 4; ++j)
          acc[i][j] = fmaf(aa[i], bb[j], acc[i][j]);
    }
    __syncthreads();
  }
#pragma unroll
  for (int j = 0; j < 4; ++j)
    rP[ty][tx * 4 + j] = acc[0][j] + acc[1][j] + acc[2][j] + acc[3][j];
  __syncthreads();
  if (t < 64) {
    float ssum = 0.f;
#pragma unroll
    for (int w = 0; w < 16; ++w) ssum += rP[w][t];
    atomicAdd(&st[n0 + t], (double)ssum);
  }
  __syncthreads();
#pragma unroll
  for (int j = 0; j < 4; ++j)
    rP[ty][tx * 4 + j] = acc[0][j] * acc[0][j] + acc[1][j] * acc[1][j]
                       + acc[2][j] * acc[2][j] + acc[3][j] * acc[3][j];
  __syncthreads();
  if (t < 64) {
    float qsum = 0.f;
#pragma unroll
    for (int w = 0; w < 16; ++w) qsum += rP[w][t];
    atomicAdd(&st[1024 + n0 + t], (double)qsum);
  }
  if (STORE) {
#pragma unroll
    for (int i = 0; i < 4; ++i) {
      int r = m0 + ty * 4 + i;
#pragma unroll
      for (int j = 0; j < 4; ++j) {
        if (H7F32)
          ((float*)Hout)[(size_t)r * Nout + n0 + tx * 4 + j] = acc[i][j];
        else
          ((u16*)Hout)[(size_t)r * Nout + n0 + tx * 4 + j] = f2bf_rne(acc[i][j]);
      }
    }
  }
}

// =================== final: h7'->h8 -> BN -> xW9^T -> out (rP padded: 585) ===================
template <int H7F32>
__global__ __launch_bounds__(256) void final_k(
    const void* __restrict__ h7, const float* __restrict__ sc7, const float* __restrict__ sh7,
    const float* __restrict__ W8, const float* __restrict__ sc8, const float* __restrict__ sh8,
    const float* __restrict__ W9, void* __restrict__ outp_raw,
    const int* __restrict__ flag) {
  __shared__ float As[16][68];
  __shared__ float Ws[16][68];
  __shared__ float w9s[9][256];
  __shared__ float rP[16][585];
  const int t = threadIdx.x;
  const int m0 = blockIdx.x * 64;
  const int tx = t & 15, ty = t >> 4;
  const int lm = t >> 2, lk = (t & 3) * 4;
  for (int l = t; l < 2304; l += 256) w9s[l >> 8][l & 255] = W9[l];
  float outp[4][9];
#pragma unroll
  for (int i = 0; i < 4; ++i)
#pragma unroll
    for (int o = 0; o < 9; ++o) outp[i][o] = 0.f;
  for (int nt = 0; nt < 4; ++nt) {
    const int n0 = nt * 64;
    float acc[4][4];
#pragma unroll
    for (int i = 0; i < 4; ++i)
#pragma unroll
      for (int j = 0; j < 4; ++j) acc[i][j] = 0.f;
    for (int k0 = 0; k0 < 512; k0 += 16) {
      const int c = k0 + lk;
      float4 hv;
      if (H7F32) {
        hv = *(const float4*)&((const float*)h7)[(size_t)(m0 + lm) * 512 + c];
      } else {
        ushort4 u4 = *(const ushort4*)&((const u16*)h7)[(size_t)(m0 + lm) * 512 + c];
        hv = make_float4(bf2f(u4.x), bf2f(u4.y), bf2f(u4.z), bf2f(u4.w));
      }
      As[lk + 0][lm] = lrelu(sc7[c + 0] * hv.x + sh7[c + 0]);
      As[lk + 1][lm] = lrelu(sc7[c + 1] * hv.y + sh7[c + 1]);
      As[lk + 2][lm] = lrelu(sc7[c + 2] * hv.z + sh7[c + 2]);
      As[lk + 3][lm] = lrelu(sc7[c + 3] * hv.w + sh7[c + 3]);
      float4 wv = *(const float4*)&W8[(size_t)(n0 + lm) * 512 + c];
      Ws[lk + 0][lm] = wv.x; Ws[lk + 1][lm] = wv.y;
      Ws[lk + 2][lm] = wv.z; Ws[lk + 3][lm] = wv.w;
      __syncthreads();
#pragma unroll
      for (int kk = 0; kk < 16; ++kk) {
        float4 a4 = *(const float4*)&As[kk][ty * 4];
        float4 b4 = *(const float4*)&Ws[kk][tx * 4];
        const float* aa = (const float*)&a4;
        const float* bb = (const float*)&b4;
#pragma unroll
        for (int i = 0; i < 4; ++i)
#pragma unroll
          for (int j = 0; j < 4; ++j)
            acc[i][j] = fmaf(aa[i], bb[j], acc[i][j]);
      }
      __syncthreads();
    }
#pragma unroll
    for (int j = 0; j < 4; ++j) {
      int c = n0 + tx * 4 + j;
      float s8 = sc8[c], b8 = sh8[c];
#pragma unroll
      for (int i = 0; i < 4; ++i) {
        float v = lrelu(s8 * acc[i][j] + b8);
#pragma unroll
        for (int o = 0; o < 9; ++o) outp[i][o] += v * w9s[o][c];
      }
    }
  }
#pragma unroll
  for (int i = 0; i < 4; ++i)
#pragma unroll
    for (int o = 0; o < 9; ++o) rP[tx][(ty * 4 + i) * 9 + o] = outp[i][o];
  __syncthreads();
  const int mode = flag[0];
  for (int l = t; l < 576; l += 256) {
    float sum = 0.f;
#pragma unroll
    for (int w = 0; w < 16; ++w) sum += rP[w][l];
    if (mode) {
      ((__hip_bfloat16*)outp_raw)[(size_t)m0 * 9 + l] = __float2bfloat16(sum);
    } else {
      ((float*)outp_raw)[(size_t)m0 * 9 + l] = sum;
    }
  }
}

// =================== host ===================
extern "C" void kernel_launch(void* const* d_in, const int* in_sizes, int n_in,
                              void* d_out, int out_size, void* d_ws, size_t ws_size,
                              hipStream_t stream) {
  (void)in_sizes; (void)out_size;
  if (n_in < 27) return;

  char* p = (char*)d_ws;
  size_t used = 0;
  auto alloc = [&](size_t bytes) {
    char* r = p;
    size_t rb = (bytes + 255) & ~(size_t)255;
    p += rb; used += rb;
    return r;
  };
  int* flag    = (int*)alloc(256);
  float* xF    = (float*)alloc((size_t)98304 * 4);
  float* W1f   = (float*)alloc((size_t)384 * 4);
  float* W2f   = (float*)alloc((size_t)4096 * 4);
  float* W3f   = (float*)alloc((size_t)8192 * 4);
  float* W4f   = (float*)alloc((size_t)4096 * 4);
  float* W5f   = (float*)alloc((size_t)8192 * 4);
  float* W6f   = (float*)alloc((size_t)196608 * 4);
  float* W7f   = (float*)alloc((size_t)622592 * 4);
  float* W8f   = (float*)alloc((size_t)131072 * 4);
  float* W9f   = (float*)alloc((size_t)2304 * 4);
  float* gF    = (float*)alloc((size_t)2112 * 4);
  float* bF    = (float*)alloc((size_t)2112 * 4);
  int* idxb    = (int*)alloc((size_t)NEDGE * 4);
  double* xx   = (double*)alloc((size_t)NPTS * 8);
  float* xxfb  = (float*)alloc((size_t)NPTS * 4);
  u16* Xhi     = (u16*)alloc((size_t)NPTS * 64 * 2);
  u16* Xlo     = (u16*)alloc((size_t)NPTS * 64 * 2);
  float* x1    = (float*)alloc((size_t)NPTS * 64 * 4);
  float* x2    = (float*)alloc((size_t)NPTS * 64 * 4);
  float* x3    = (float*)alloc((size_t)NPTS * 64 * 4);
  float* gm    = (float*)alloc((size_t)BB * 1024 * 4);
  float* gpmax = (float*)alloc((size_t)512 * 1024 * 4);
  float* gpmin = (float*)alloc((size_t)512 * 1024 * 4);
  float* gW    = (float*)alloc((size_t)4096 * 4);
  float* W7r   = (float*)alloc((size_t)98304 * 4);
  double* st   = (double*)alloc((size_t)2048 * 8);
  double* stm  = (double*)alloc((size_t)32 * 8);
  float* scb   = (float*)alloc((size_t)8 * 1024 * 4);
  float* shb   = (float*)alloc((size_t)8 * 1024 * 4);
  const int h7f32 = (ws_size >= used + (size_t)NPTS * 512 * 4 + 256) ? 1 : 0;
  void* h7 = alloc((size_t)NPTS * 512 * (h7f32 ? 4 : 2));
  if (ws_size < used) return;
  // kNN scratch overlays h7 (consumed before h7's real use):
  //   pkey : 4 segs x NPTS x 20 u64 = 21.0 MB (3-D knn partials)
  //   pcand: NPTS x 48 u64 = 12.6 MB          (screen candidates)
  u64* pkey  = (u64*)h7;
  u64* pcand = (u64*)h7;

  // ---- canonicalize all inputs to f32 ----
  det_k<<<1, 1, 0, stream>>>(d_in[11], flag);
  auto conv = [&](const void* src, float* dst, int n) {
    conv_k<<<(n + 255) / 256, 256, 0, stream>>>(src, dst, n, flag);
  };
  conv(d_in[0], xF, 98304);
  conv(d_in[2], W1f, 384);    conv(d_in[3], W2f, 4096);
  conv(d_in[4], W3f, 8192);   conv(d_in[5], W4f, 4096);
  conv(d_in[6], W5f, 8192);   conv(d_in[7], W6f, 196608);
  conv(d_in[8], W7f, 622592); conv(d_in[9], W8f, 131072);
  conv(d_in[10], W9f, 2304);
  const int gsz[8] = {64, 64, 64, 64, 64, 1024, 512, 256};
  int goff[8]; int acc_ = 0;
  for (int i = 0; i < 8; ++i) { goff[i] = acc_; acc_ += gsz[i]; }
  for (int i = 0; i < 8; ++i) {
    conv(d_in[11 + 2 * i], gF + goff[i], gsz[i]);
    conv(d_in[12 + 2 * i], bF + goff[i], gsz[i]);
  }
  wpack_k<<<384, 256, 0, stream>>>(W7f, W7r);
  auto SC = [&](int l) { return scb + (size_t)(l - 1) * 1024; };
  auto SH = [&](int l) { return shb + (size_t)(l - 1) * 1024; };
  auto G  = [&](int l) { return gF + goff[l - 1]; };
  auto Bt = [&](int l) { return bF + goff[l - 1]; };

  // ---- stage 1 ----
  knn1p_k<<<dim3(BB, 16, 4), 256, 0, stream>>>(xF, pkey);
  tmerge_k<<<NPTS / 256, 256, 0, stream>>>(pkey, idxb);
  zero_k<<<1, 256, 0, stream>>>(stm, 32);
  f1mom_k<<<320, 256, 0, stream>>>(xF, idxb, stm);
  fin1_k<<<1, 64, 0, stream>>>(stm, W1f, G(1), Bt(1), SC(1), SH(1), 1.0 / NEDGE);
  zero_k<<<8, 256, 0, stream>>>(st, 2048);
  e1b_k<<<NEDGE / 1024, 256, 0, stream>>>(xF, idxb, W1f, SC(1), SH(1), W2f, st);
  fin_k<<<1, 256, 0, stream>>>(st, G(2), Bt(2), SC(2), SH(2), 64, 1.0 / NEDGE);
  e1c_k<<<NPTS / 4, 256, 0, stream>>>(xF, idxb, W1f, SC(1), SH(1), W2f, SC(2), SH(2), x1);

  // ---- knn on x1: barrier-free MFMA split-bf16 screen + exact f64 rescore ----
  xx_k<<<NPTS, 64, 0, stream>>>(x1, xx, xxfb);
  xsplit_k<<<NPTS * 64 / 256, 256, 0, stream>>>(x1, Xhi, Xlo);
  knnsm_k<<<dim3(NN / 16, BB), 256, 0, stream>>>(Xhi, Xlo, xxfb, pcand);
  resc_k<<<NPTS / 4, 256, 0, stream>>>(x1, xx, pcand, idxb);

  // ---- stage 2 ----
  zero_k<<<8, 256, 0, stream>>>(st, 2048);
  e2a_k<<<NEDGE / 1024, 256, 0, stream>>>(x1, idxb, W3f, st);
  fin_k<<<1, 256, 0, stream>>>(st, G(3), Bt(3), SC(3), SH(3), 64, 1.0 / NEDGE);
  zero_k<<<8, 256, 0, stream>>>(st, 2048);
  e2b_k<<<NEDGE / 1024, 256, 0, stream>>>(x1, idxb, W3f, SC(3), SH(3), W4f, st);
  fin_k<<<1, 256, 0, stream>>>(st, G(4), Bt(4), SC(4), SH(4), 64, 1.0 / NEDGE);
  e2c_k<<<NPTS / 2, 256, 0, stream>>>(x1, idxb, W3f, SC(3), SH(3), W4f, SC(4), SH(4), x2);

  // ---- knn on x2: barrier-free MFMA split-bf16 screen + exact f64 rescore ----
  xx_k<<<NPTS, 64, 0, stream>>>(x2, xx, xxfb);
  xsplit_k<<<NPTS * 64 / 256, 256, 0, stream>>>(x2, Xhi, Xlo);
  knnsm_k<<<dim3(NN / 16, BB), 256, 0, stream>>>(Xhi, Xlo, xxfb, pcand);
  resc_k<<<NPTS / 4, 256, 0, stream>>>(x2, xx, pcand, idxb);

  // ---- stage 3 ----
  zero_k<<<8, 256, 0, stream>>>(st, 2048);
  e2a_k<<<NEDGE / 1024, 256, 0, stream>>>(x2, idxb, W5f, st);
  fin_k<<<1, 256, 0, stream>>>(st, G(5), Bt(5), SC(5), SH(5), 64, 1.0 / NEDGE);
  e3c_k<<<NPTS / 4, 256, 0, stream>>>(x2, idxb, W5f, SC(5), SH(5), x3);

  // ---- point pipeline ----
  zero_k<<<8, 256, 0, stream>>>(st, 2048);
  g6stats_k<<<dim3(NPTS / 64, 16), 256, 0, stream>>>(x1, x2, x3, W6f, st, gpmax, gpmin);
  fin_k<<<4, 256, 0, stream>>>(st, G(6), Bt(6), SC(6), SH(6), 1024, 1.0 / NPTS);
  gmax_red2_k<<<dim3(BB, 4), 256, 0, stream>>>(gpmax, gpmin, SC(6), SH(6), gm);

  gw_k<<<16, 256, 0, stream>>>(gm, W7f, gW);
  zero_k<<<8, 256, 0, stream>>>(st, 2048);
  if (h7f32) {
    g7stats_k<1><<<dim3(NPTS / 64, 8), 256, 0, stream>>>(x1, x2, x3, W7r, gW, h7, st);
  } else {
    g7stats_k<0><<<dim3(NPTS / 64, 8), 256, 0, stream>>>(x1, x2, x3, W7r, gW, h7, st);
  }
  fin_k<<<2, 256, 0, stream>>>(st, G(7), Bt(7), SC(7), SH(7), 512, 1.0 / NPTS);

  zero_k<<<8, 256, 0, stream>>>(st, 2048);
  if (h7f32) {
    gstats_k<4, 0, 1><<<dim3(NPTS / 64, 4), 256, 0, stream>>>(
        h7, W8f, 512, 256, nullptr, nullptr, nullptr, nullptr, SC(7), SH(7), nullptr, st);
  } else {
    gstats_k<4, 0, 0><<<dim3(NPTS / 64, 4), 256, 0, stream>>>(
        h7, W8f, 512, 256, nullptr, nullptr, nullptr, nullptr, SC(7), SH(7), nullptr, st);
  }
  fin_k<<<1, 256, 0, stream>>>(st, G(8), Bt(8), SC(8), SH(8), 256, 1.0 / NPTS);

  if (h7f32) {
    final_k<1><<<NPTS / 64, 256, 0, stream>>>(h7, SC(7), SH(7), W8f, SC(8), SH(8), W9f,
                                              d_out, flag);
  } else {
    final_k<0><<<NPTS / 64, 256, 0, stream>>>(h7, SC(7), SH(7), W8f, SC(8), SH(8), W9f,
                                              d_out, flag);
  }
}

// Round 17
// 3332.280 us; speedup vs baseline: 1.2727x; 1.1369x over previous
//
#include <hip/hip_runtime.h>
#include <hip/hip_bf16.h>

#define BB 8
#define NN 4096
#define KNN 20
#define NPTS (BB*NN)          // 32768
#define NEDGE (NPTS*KNN)      // 655360
#define TKCAP 12
#define LKN 12                // per-lane screen top-K (recall: Binom(19,1/16) >= 12 is ~2e-10)
#define SKN 24                // per-wave merged top-K (>= 19 possible better + slack)
#define FKN 48                // final screened candidates per query (rescored exactly)

typedef unsigned short u16;
typedef unsigned long long u64;
typedef __attribute__((ext_vector_type(8))) short s8v;   // 8 bf16 (4 VGPRs)
typedef __attribute__((ext_vector_type(4))) float f4v;

__device__ __forceinline__ float bf2f(u16 u) {
    return __uint_as_float(((unsigned)u) << 16);
}
__device__ __forceinline__ u16 f2bf_rne(float f) {
  unsigned u = __float_as_uint(f);
  unsigned rb = (u >> 16) & 1;
  u += 0x7FFFu + rb;
  return (u16)(u >> 16);
}
__device__ __forceinline__ float lrelu(float v) { return v > 0.f ? v : 0.2f * v; }

// ---- sortable (value,index) packed key (f64): descending value, ties -> lower index ----
__device__ __forceinline__ u64 dkey(double v, int j) {
  u64 u = (u64)__double_as_longlong(v);
  u = (u >> 63) ? ~u : (u | 0x8000000000000000ull);
  return (u & ~0xFFFull) | (u64)(4095 - j);
}

// ---- sortable (value,index) packed key (f32 screen): full f32 bits + 12-bit index ----
__device__ __forceinline__ u64 skey(float v, int j) {
  unsigned s = __float_as_uint(v);
  s = (s >> 31) ? ~s : (s | 0x80000000u);
  return ((u64)s << 12) | (u64)(4095 - j);
}

// ---- generic register top-N insertion (static indices after unroll) ----
template <int N>
__device__ __forceinline__ void tk_insert(u64* bk, u64 k) {
  if (k > bk[N - 1]) {
    bk[N - 1] = k;
#pragma unroll
    for (int p = N - 1; p > 0; --p) {
      if (bk[p] > bk[p - 1]) { u64 tv = bk[p]; bk[p] = bk[p - 1]; bk[p - 1] = tv; }
    }
  }
}

// ---- top-20 insertion on packed u64 keys (macro form used by knn1p/tmerge) ----
#define TOPK_INIT() \
  u64 bk[KNN]; \
  _Pragma("unroll") for (int p_ = 0; p_ < KNN; ++p_) bk[p_] = 0ull;

#define TOPK_INSERT(kk) do { \
    u64 k_ = (kk); \
    if (k_ > bk[KNN-1]) { \
      bk[KNN-1] = k_; \
      _Pragma("unroll") \
      for (int p_ = KNN-1; p_ > 0; --p_) { \
        if (bk[p_] > bk[p_-1]) { u64 tv_ = bk[p_]; bk[p_] = bk[p_-1]; bk[p_-1] = tv_; } \
      } \
    } \
  } while (0)

#define TKBUF_DECL() \
  u64 thr_ = 0ull; u64 cb_[TKCAP]; int cnt_ = 0;
#define TKBUF_PUSH(kk) do { \
    u64 k__ = (kk); \
    if (k__ > thr_) { cb_[cnt_] = k__; ++cnt_; } \
  } while (0)
#define TKBUF_FLUSH() do { \
    for (int l_ = 0; l_ < cnt_; ++l_) TOPK_INSERT(cb_[l_]); \
    cnt_ = 0; thr_ = bk[KNN-1]; \
  } while (0)

// =================== dtype detect + canonicalize to f32 ===================
__global__ void det_k(const void* __restrict__ g1raw, int* __restrict__ flag) {
  const u16* u = (const u16*)g1raw;
  flag[0] = (u[0] == 0x3F80) ? 1 : 0;
}

__global__ __launch_bounds__(256) void conv_k(const void* __restrict__ src,
                                              float* __restrict__ dst, int n,
                                              const int* __restrict__ flag) {
  const int mode = flag[0];
  int i = blockIdx.x * 256 + threadIdx.x;
  const int stride = gridDim.x * 256;
  if (mode) {
    const u16* s = (const u16*)src;
    for (; i < n; i += stride) dst[i] = bf2f(s[i]);
  } else {
    const float* s = (const float*)src;
    for (; i < n; i += stride) dst[i] = s[i];
  }
}

__global__ void zero_k(double* __restrict__ p, int n) {
  int i = blockIdx.x * 256 + threadIdx.x;
  if (i < n) p[i] = 0.0;
}

// =========== knn on raw 3-D points — j-split partials, packed u64 keys ===========
__global__ __launch_bounds__(256) void knn1p_k(const float* __restrict__ x,
                                               u64* __restrict__ pkey) {
  __shared__ float sx[1024], sy[1024], sz[1024];
  __shared__ double sq[1024];
  const int b = blockIdx.x, t = threadIdx.x, seg = blockIdx.z;
  const int j0 = seg * 1024;
  const float* xb = x + b * 3 * NN;
  const int i = blockIdx.y * 256 + t;
  const double px = (double)xb[i], py = (double)xb[NN + i], pz = (double)xb[2 * NN + i];
  const double q = px * px + py * py + pz * pz;
  for (int l = t; l < 1024; l += 256) {
    float jx = xb[j0 + l], jy = xb[NN + j0 + l], jz = xb[2 * NN + j0 + l];
    sx[l] = jx; sy[l] = jy; sz[l] = jz;
    double jxd = jx, jyd = jy, jzd = jz;
    sq[l] = jxd * jxd + jyd * jyd + jzd * jzd;
  }
  __syncthreads();
  TOPK_INIT();
  TKBUF_DECL();
  for (int j = 0; j < 1024; j += 4) {
    double i0 = px * (double)sx[j + 0] + py * (double)sy[j + 0] + pz * (double)sz[j + 0];
    double i1 = px * (double)sx[j + 1] + py * (double)sy[j + 1] + pz * (double)sz[j + 1];
    double i2 = px * (double)sx[j + 2] + py * (double)sy[j + 2] + pz * (double)sz[j + 2];
    double i3 = px * (double)sx[j + 3] + py * (double)sy[j + 3] + pz * (double)sz[j + 3];
    double v0 = (2.0 * i0 - q) - sq[j + 0];
    double v1 = (2.0 * i1 - q) - sq[j + 1];
    double v2 = (2.0 * i2 - q) - sq[j + 2];
    double v3 = (2.0 * i3 - q) - sq[j + 3];
    TKBUF_PUSH(dkey(v0, j0 + j + 0));
    TKBUF_PUSH(dkey(v1, j0 + j + 1));
    TKBUF_PUSH(dkey(v2, j0 + j + 2));
    TKBUF_PUSH(dkey(v3, j0 + j + 3));
    if (__ballot(cnt_ >= TKCAP - 3)) TKBUF_FLUSH();
  }
  TKBUF_FLUSH();
  const size_t base = ((size_t)seg * NPTS + (b * NN + i)) * KNN;
#pragma unroll
  for (int p = 0; p < KNN; ++p) pkey[base + p] = bk[p];
}

// =================== merge 4 partial top-20 key lists -> final indices ===================
__global__ __launch_bounds__(256) void tmerge_k(const u64* __restrict__ pkey,
                                                int* __restrict__ idx) {
  const int pt = blockIdx.x * 256 + threadIdx.x;
  TOPK_INIT();
  for (int seg = 0; seg < 4; ++seg) {
    const size_t base = ((size_t)seg * NPTS + pt) * KNN;
#pragma unroll
    for (int p = 0; p < KNN; ++p) TOPK_INSERT(pkey[base + p]);
  }
  int* op = idx + (size_t)pt * KNN;
#pragma unroll
  for (int p = 0; p < KNN; ++p) op[p] = 4095 - (int)(bk[p] & 0xFFFull);
}

// ==== split f32 features into bf16 hi + bf16 lo (screen operands) ====
__global__ __launch_bounds__(256) void xsplit_k(const float* __restrict__ xp,
                                                u16* __restrict__ Xhi,
                                                u16* __restrict__ Xlo) {
  int i = blockIdx.x * 256 + threadIdx.x;   // NPTS*64 elements
  float x = xp[i];
  u16 h = f2bf_rne(x);
  Xhi[i] = h;
  Xlo[i] = f2bf_rne(x - bf2f(h));
}

// ====== MFMA split-bf16 SCREEN knn v5: per-lane top-12 -> wave top-24 -> top-48 ======
__global__ __launch_bounds__(256) void knnsm_k(const u16* __restrict__ Xhi,
                                               const u16* __restrict__ Xlo,
                                               const float* __restrict__ xxf,
                                               u64* __restrict__ pcand) {
  __shared__ __align__(16) unsigned char smraw[16384];
  u64* lbuf = (u64*)smraw;                    // [8 slots][256 threads] = 16384 B
  u64* km   = (u64*)smraw;                    // [16][97] = 12416 B (post-loop overlay)
  const int t = threadIdx.x;
  const int w = t >> 6, l = t & 63;
  const int b = blockIdx.y;
  const int i0 = blockIdx.x * 16;
  const int gpt0 = b * NN;
  s8v Bhi[2], Blo[2];
#pragma unroll
  for (int kt = 0; kt < 2; ++kt) {
    size_t off = (size_t)(gpt0 + i0 + (l & 15)) * 64 + kt * 32 + ((l >> 4) * 8);
    Bhi[kt] = *(const s8v*)&Xhi[off];
    Blo[kt] = *(const s8v*)&Xlo[off];
  }
  const int q = l & 15, hi = l >> 4;
  const float qif = xxf[gpt0 + i0 + q];
  u64 bk[LKN];
#pragma unroll
  for (int p = 0; p < LKN; ++p) bk[p] = 0ull;
  u64 thr = 0ull; int cnt = 0;
  for (int jt = 0; jt < 64; ++jt) {
    const int jloc = w * 1024 + jt * 16;
    s8v Ahi_[2], Alo_[2];
#pragma unroll
    for (int kt = 0; kt < 2; ++kt) {
      size_t off = (size_t)(gpt0 + jloc + (l & 15)) * 64 + kt * 32 + (hi * 8);
      Ahi_[kt] = *(const s8v*)&Xhi[off];
      Alo_[kt] = *(const s8v*)&Xlo[off];
    }
    f4v acc = {0.f, 0.f, 0.f, 0.f};
#pragma unroll
    for (int kt = 0; kt < 2; ++kt) {
      acc = __builtin_amdgcn_mfma_f32_16x16x32_bf16(Ahi_[kt], Bhi[kt], acc, 0, 0, 0);
      acc = __builtin_amdgcn_mfma_f32_16x16x32_bf16(Ahi_[kt], Blo[kt], acc, 0, 0, 0);
      acc = __builtin_amdgcn_mfma_f32_16x16x32_bf16(Alo_[kt], Bhi[kt], acc, 0, 0, 0);
    }
    float4 qj4 = *(const float4*)&xxf[gpt0 + jloc + hi * 4];   // L2-hot
    const float* qj = (const float*)&qj4;
#pragma unroll
    for (int r = 0; r < 4; ++r) {
      float v = (2.f * acc[r] - qif) - qj[r];
      u64 k0 = skey(v, jloc + hi * 4 + r);
      if (k0 > thr) { lbuf[cnt * 256 + t] = k0; ++cnt; }
    }
    if (__ballot(cnt >= 5)) {
      for (int lf = 0; lf < cnt; ++lf) tk_insert<LKN>(bk, lbuf[lf * 256 + t]);
      cnt = 0; thr = bk[LKN - 1];
    }
  }
  for (int lf = 0; lf < cnt; ++lf) tk_insert<LKN>(bk, lbuf[lf * 256 + t]);
  u64 wk[SKN];
#pragma unroll
  for (int p = 0; p < LKN; ++p) wk[p] = bk[p];
#pragma unroll
  for (int p = LKN; p < SKN; ++p) wk[p] = 0ull;
#pragma unroll
  for (int p = 0; p < SKN; ++p) {
    u64 o = __shfl_xor((unsigned long long)wk[p], 32);
    if (l < 32) tk_insert<SKN>(wk, o);
  }
#pragma unroll
  for (int p = 0; p < SKN; ++p) {
    u64 o = __shfl_xor((unsigned long long)wk[p], 16);
    if (l < 16) tk_insert<SKN>(wk, o);
  }
  __syncthreads();   // all lbuf reads done before km overlay writes
  if (l < 16) {
#pragma unroll
    for (int p = 0; p < SKN; ++p) km[l * 97 + w * SKN + p] = wk[p];
  }
  __syncthreads();
  {
    const int qq = t & 15, g = t >> 4;   // 16 groups x 6 candidates
    const size_t pb = (size_t)(gpt0 + i0 + qq) * FKN;
    for (int cc = 0; cc < 6; ++cc) {
      u64 mine = km[qq * 97 + g * 6 + cc];
      int rank = 0;
      for (int o = 0; o < 96; ++o) rank += (km[qq * 97 + o] > mine) ? 1 : 0;
      if (rank < FKN) pcand[pb + rank] = mine;
    }
  }
}

// ============ exact f64 rescore of 48 screened candidates -> final top-20 idx ============
__global__ __launch_bounds__(256) void resc_k(const float* __restrict__ xp,
                                              const double* __restrict__ xx,
                                              const u64* __restrict__ pcand,
                                              int* __restrict__ idx) {
  __shared__ float xis[4][64];
  __shared__ u64 keys[4][FKN];
  const int t = threadIdx.x;
  const int w = t >> 6, lane = t & 63;
  const int pt = blockIdx.x * 4 + w;
  const int b12 = pt & ~(NN - 1);
  xis[w][lane] = xp[(size_t)pt * 64 + lane];
  const double q = xx[pt];
  if (lane < FKN) {
    u64 sk = pcand[(size_t)pt * FKN + lane];
    int j = 4095 - (int)(sk & 0xFFFull);
    const float* xj = xp + ((size_t)b12 + j) * 64;
    double a0 = 0.0, a1 = 0.0, a2 = 0.0, a3 = 0.0;
#pragma unroll
    for (int d = 0; d < 16; ++d) {
      a0 += (double)xis[w][d] * (double)xj[d];
      a1 += (double)xis[w][16 + d] * (double)xj[16 + d];
      a2 += (double)xis[w][32 + d] * (double)xj[32 + d];
      a3 += (double)xis[w][48 + d] * (double)xj[48 + d];
    }
    double v = (2.0 * ((a0 + a1) + (a2 + a3)) - q) - xx[b12 + j];
    keys[w][lane] = dkey(v, j);
  }
  if (lane < FKN) {
    u64 mine = keys[w][lane];
    int rank = 0;
    for (int o = 0; o < FKN; ++o) rank += (keys[w][o] > mine) ? 1 : 0;
    if (rank < KNN) idx[(size_t)pt * KNN + rank] = 4095 - (int)(mine & 0xFFFull);
  }
}

// =================== moments of the 6-D edge feature (tiled: 2048 edges/block) ==============
__global__ __launch_bounds__(256) void f1mom_k(const float* __restrict__ x,
                                               const int* __restrict__ idx,
                                               double* __restrict__ stm) {
  __shared__ float red[27][257];
  const int t = threadIdx.x;
  float a[27];
#pragma unroll
  for (int m = 0; m < 27; ++m) a[m] = 0.f;
  for (int r = 0; r < 8; ++r) {
    int e = blockIdx.x * 2048 + r * 256 + t;
    int pt = e / KNN;
    int b = pt >> 12, i = pt & (NN - 1);
    int j = idx[e] & (NN - 1);
    const float* xb = x + b * 3 * NN;
    float xi0 = xb[i], xi1 = xb[NN + i], xi2 = xb[2 * NN + i];
    float f[6];
    f[0] = xb[j] - xi0; f[1] = xb[NN + j] - xi1; f[2] = xb[2 * NN + j] - xi2;
    f[3] = xi0; f[4] = xi1; f[5] = xi2;
#pragma unroll
    for (int d = 0; d < 6; ++d) a[d] += f[d];
    int k = 6;
#pragma unroll
    for (int aa = 0; aa < 6; ++aa)
#pragma unroll
      for (int bb2 = aa; bb2 < 6; ++bb2) a[k++] += f[aa] * f[bb2];
  }
#pragma unroll
  for (int m = 0; m < 27; ++m) red[m][t] = a[m];
  __syncthreads();
  if (t < 27) {
    double s = 0.0;
    for (int l = 0; l < 256; ++l) s += (double)red[t][l];
    atomicAdd(&stm[t], s);
  }
}

__global__ void fin1_k(const double* __restrict__ stm, const float* __restrict__ W1,
                       const float* __restrict__ g, const float* __restrict__ bet,
                       float* __restrict__ sc, float* __restrict__ sh, double invM) {
  int c = threadIdx.x;
  if (c >= 64) return;
  double w[6];
  for (int d = 0; d < 6; ++d) w[d] = (double)W1[c * 6 + d];
  double mean = 0.0;
  for (int d = 0; d < 6; ++d) mean += w[d] * stm[d];
  mean *= invM;
  double e2 = 0.0;
  int k = 6;
  for (int a = 0; a < 6; ++a)
    for (int b = a; b < 6; ++b) {
      double m2 = stm[k++];
      e2 += w[a] * w[b] * m2 * (a == b ? 1.0 : 2.0);
    }
  e2 *= invM;
  double var = e2 - mean * mean;
  if (!(var > 0.0)) var = 0.0;
  double scale = (double)g[c] / sqrt(var + 1e-5);
  sc[c] = (float)scale;
  sh[c] = (float)((double)bet[c] - mean * scale);
}

__global__ void fin_k(const double* __restrict__ st, const float* __restrict__ g,
                      const float* __restrict__ bet, float* __restrict__ sc,
                      float* __restrict__ sh, int C, double invM) {
  int c = blockIdx.x * 256 + threadIdx.x;
  if (c >= C) return;
  double mean = st[c] * invM;
  double var = st[1024 + c] * invM - mean * mean;
  if (!(var > 0.0)) var = 0.0;
  double scale = (double)g[c] / sqrt(var + 1e-5);
  sc[c] = (float)scale;
  sh[c] = (float)((double)bet[c] - mean * scale);
}

// ===== stage-1: h2 stats as tile-GEMM (f6 -> h1 -> BN -> h2 col-stats), 16 tiles/block ======
__global__ __launch_bounds__(256) void e1b_k(const float* __restrict__ x, const int* __restrict__ idx,
    const float* __restrict__ W1, const float* __restrict__ sc1, const float* __restrict__ sh1,
    const float* __restrict__ W2, double* __restrict__ st) {
  __shared__ float f6[64][9];
  __shared__ float W1s[64][8];
  __shared__ float H1[64][68];
  __shared__ float W2s[64][68];
  __shared__ double rPd[16][68];
  const int t = threadIdx.x;
  const int tx = t & 15, ty = t >> 4;
  for (int l = t; l < 384; l += 256) W1s[l / 6][l % 6] = W1[l];
  for (int l = t; l < 4096; l += 256) W2s[l & 63][l >> 6] = W2[l];
  double sL[4], qL[4];
#pragma unroll
  for (int j = 0; j < 4; ++j) { sL[j] = 0.0; qL[j] = 0.0; }
  for (int tile = 0; tile < 16; ++tile) {
    const int e0 = (blockIdx.x * 16 + tile) * 64;
    __syncthreads();
    if (t < 64) {
      int e = e0 + t;
      int pt = e / KNN;
      int b = pt >> 12, i = pt & (NN - 1);
      int j = idx[e] & (NN - 1);
      const float* xb = x + b * 3 * NN;
      float xi0 = xb[i], xi1 = xb[NN + i], xi2 = xb[2 * NN + i];
      f6[t][0] = xb[j] - xi0; f6[t][1] = xb[NN + j] - xi1; f6[t][2] = xb[2 * NN + j] - xi2;
      f6[t][3] = xi0; f6[t][4] = xi1; f6[t][5] = xi2;
    }
    __syncthreads();
    float acc1[4][4];
#pragma unroll
    for (int i = 0; i < 4; ++i)
#pragma unroll
      for (int j = 0; j < 4; ++j) acc1[i][j] = 0.f;
#pragma unroll
    for (int d = 0; d < 6; ++d) {
      float av[4], bv2[4];
#pragma unroll
      for (int i = 0; i < 4; ++i) av[i] = f6[ty * 4 + i][d];
#pragma unroll
      for (int j = 0; j < 4; ++j) bv2[j] = W1s[tx * 4 + j][d];
#pragma unroll
      for (int i = 0; i < 4; ++i)
#pragma unroll
        for (int j = 0; j < 4; ++j) acc1[i][j] = fmaf(av[i], bv2[j], acc1[i][j]);
    }
#pragma unroll
    for (int j = 0; j < 4; ++j) {
      int c = tx * 4 + j;
      float s1 = sc1[c], b1 = sh1[c];
#pragma unroll
      for (int i = 0; i < 4; ++i)
        H1[c][ty * 4 + i] = lrelu(fmaf(s1, acc1[i][j], b1));
    }
    __syncthreads();
    float acc2[4][4];
#pragma unroll
    for (int i = 0; i < 4; ++i)
#pragma unroll
      for (int j = 0; j < 4; ++j) acc2[i][j] = 0.f;
    for (int k = 0; k < 64; ++k) {
      float4 a4 = *(const float4*)&H1[k][ty * 4];
      float4 b4 = *(const float4*)&W2s[k][tx * 4];
      const float* aa = (const float*)&a4;
      const float* bb = (const float*)&b4;
#pragma unroll
      for (int i = 0; i < 4; ++i)
#pragma unroll
        for (int j = 0; j < 4; ++j) acc2[i][j] = fmaf(aa[i], bb[j], acc2[i][j]);
    }
#pragma unroll
    for (int j = 0; j < 4; ++j) {
      sL[j] += (double)acc2[0][j] + (double)acc2[1][j] + (double)acc2[2][j] + (double)acc2[3][j];
      qL[j] += (double)acc2[0][j] * (double)acc2[0][j] + (double)acc2[1][j] * (double)acc2[1][j]
             + (double)acc2[2][j] * (double)acc2[2][j] + (double)acc2[3][j] * (double)acc2[3][j];
    }
  }
  __syncthreads();
#pragma unroll
  for (int j = 0; j < 4; ++j) rPd[ty][tx * 4 + j] = sL[j];
  __syncthreads();
  if (t < 64) {
    double s = 0.0;
#pragma unroll
    for (int w = 0; w < 16; ++w) s += rPd[w][t];
    atomicAdd(&st[t], s);
  }
  __syncthreads();
#pragma unroll
  for (int j = 0; j < 4; ++j) rPd[ty][tx * 4 + j] = qL[j];
  __syncthreads();
  if (t < 64) {
    double s = 0.0;
#pragma unroll
    for (int w = 0; w < 16; ++w) s += rPd[w][t];
    atomicAdd(&st[1024 + t], s);
  }
}

// =================== stage-1 final: f32 compute -> x1 (f32), float4 LDS reads ===================
__global__ __launch_bounds__(256) void e1c_k(const float* __restrict__ x, const int* __restrict__ idx,
    const float* __restrict__ W1, const float* __restrict__ sc1, const float* __restrict__ sh1,
    const float* __restrict__ W2, const float* __restrict__ sc2, const float* __restrict__ sh2,
    float* __restrict__ x1out) {
  __shared__ float f6[80][9];
  __shared__ float h1s[80][68];   // stride 68 floats = 272 B (16B-aligned rows)
  const int t = threadIdx.x;
  const int p0 = blockIdx.x * 4;
  if (t < 80) {
    int e = p0 * KNN + t;
    int pt = e / KNN;
    int b = pt >> 12, i = pt & (NN - 1);
    int j = idx[e] & (NN - 1);
    const float* xb = x + b * 3 * NN;
    float xi0 = xb[i], xi1 = xb[NN + i], xi2 = xb[2 * NN + i];
    f6[t][0] = xb[j] - xi0; f6[t][1] = xb[NN + j] - xi1; f6[t][2] = xb[2 * NN + j] - xi2;
    f6[t][3] = xi0; f6[t][4] = xi1; f6[t][5] = xi2;
  }
  __syncthreads();
  const int c = t & 63;
  const int g4 = t >> 6;
  float w1[6];
#pragma unroll
  for (int d = 0; d < 6; ++d) w1[d] = W1[c * 6 + d];
  const float s1 = sc1[c], b1 = sh1[c];
  {
    float hk[20];
#pragma unroll
    for (int k = 0; k < 20; ++k) hk[k] = 0.f;
#pragma unroll
    for (int d = 0; d < 6; ++d) {
      float w1d = w1[d];
#pragma unroll
      for (int k = 0; k < 20; ++k) hk[k] = fmaf(f6[g4 + k * 4][d], w1d, hk[k]);
    }
#pragma unroll
    for (int k = 0; k < 20; ++k)
      h1s[g4 + k * 4][c] = lrelu(fmaf(s1, hk[k], b1));
  }
  __syncthreads();
  const float s2 = sc2[c], b2 = sh2[c];
  float acc[20];
#pragma unroll
  for (int k = 0; k < 20; ++k) acc[k] = 0.f;
  for (int d0 = 0; d0 < 64; d0 += 4) {
    float4 wv = *(const float4*)&W2[c * 64 + d0];
#pragma unroll
    for (int k = 0; k < 20; ++k) {
      float4 hv = *(const float4*)&h1s[g4 * 20 + k][d0];
      acc[k] = fmaf(hv.x, wv.x, acc[k]);
      acc[k] = fmaf(hv.y, wv.y, acc[k]);
      acc[k] = fmaf(hv.z, wv.z, acc[k]);
      acc[k] = fmaf(hv.w, wv.w, acc[k]);
    }
  }
  float m = -3.4e38f;
#pragma unroll
  for (int k = 0; k < 20; ++k) {
    float v = lrelu(fmaf(s2, acc[k], b2));
    m = fmaxf(m, v);
  }
  x1out[(p0 + g4) * 64 + c] = m;
}

// =================== squared norms (f64 + f32 copy for screen) ===================
__global__ void xx_k(const float* __restrict__ Xp, double* __restrict__ xx,
                     float* __restrict__ xxf) {
  const int row = blockIdx.x;
  float v = Xp[(size_t)row * 64 + threadIdx.x];
  double s = (double)v * (double)v;
#pragma unroll
  for (int o = 32; o > 0; o >>= 1) s += __shfl_down(s, o, 64);
  if (threadIdx.x == 0) { xx[row] = s; xxf[row] = (float)s; }
}

// ======== EDGE-CONV DECOMPOSITION: h(e) = A[j] + B[i] ========
// Wd[c][d] = W[c][64+d] - W[c][d]   (W row-major 64x128)
__global__ void wd_k(const float* __restrict__ W, float* __restrict__ Wd) {
  int i = blockIdx.x * 256 + threadIdx.x;
  if (i < 4096) {
    int c = i >> 6, d = i & 63;
    Wd[i] = W[c * 128 + 64 + d] - W[c * 128 + d];
  }
}

// O[p][c] = sum_{d<64} X[p][d] * W[c*ldw + d], p in [0,NPTS), c<64 (tile GEMM, K=64)
__global__ __launch_bounds__(256) void pgemm_k(const float* __restrict__ X,
                                               const float* __restrict__ W, int ldw,
                                               float* __restrict__ O) {
  __shared__ float As[16][68];
  __shared__ float Ws[16][68];
  const int t = threadIdx.x;
  const int m0 = blockIdx.x * 64;
  const int tx = t & 15, ty = t >> 4;
  const int lm = t >> 2, lk = (t & 3) * 4;
  float acc[4][4];
#pragma unroll
  for (int i = 0; i < 4; ++i)
#pragma unroll
    for (int j = 0; j < 4; ++j) acc[i][j] = 0.f;
  for (int k0 = 0; k0 < 64; k0 += 16) {
    const int c = k0 + lk;
    float4 av = *(const float4*)&X[(size_t)(m0 + lm) * 64 + c];
    As[lk + 0][lm] = av.x; As[lk + 1][lm] = av.y;
    As[lk + 2][lm] = av.z; As[lk + 3][lm] = av.w;
    float4 wv = *(const float4*)&W[(size_t)lm * ldw + c];
    Ws[lk + 0][lm] = wv.x; Ws[lk + 1][lm] = wv.y;
    Ws[lk + 2][lm] = wv.z; Ws[lk + 3][lm] = wv.w;
    __syncthreads();
#pragma unroll
    for (int kk = 0; kk < 16; ++kk) {
      float4 a4 = *(const float4*)&As[kk][ty * 4];
      float4 b4 = *(const float4*)&Ws[kk][tx * 4];
      const float* aa = (const float*)&a4;
      const float* bb = (const float*)&b4;
#pragma unroll
      for (int i = 0; i < 4; ++i)
#pragma unroll
        for (int j = 0; j < 4; ++j)
          acc[i][j] = fmaf(aa[i], bb[j], acc[i][j]);
    }
    __syncthreads();
  }
#pragma unroll
  for (int i = 0; i < 4; ++i)
#pragma unroll
    for (int j = 0; j < 4; ++j)
      O[(size_t)(m0 + ty * 4 + i) * 64 + tx * 4 + j] = acc[i][j];
}

// ==== stats (sum, sumsq) of h3pre(e)[c] = A[j(e)][c] + B[i(e)][c] over all edges ====
// 2048 edges/block; thread = (channel c, edge-group g4); f64 accumulate; LDS reduce.
__global__ __launch_bounds__(256) void eastats_k(const float* __restrict__ A,
                                                 const float* __restrict__ Bm,
                                                 const int* __restrict__ idx,
                                                 double* __restrict__ st) {
  __shared__ double rs[4][64], rq[4][64];
  const int t = threadIdx.x;
  const int c = t & 63, g4 = t >> 6;
  const int e0 = blockIdx.x * 2048;
  double s = 0.0, q = 0.0;
  for (int e = e0 + g4; e < e0 + 2048; e += 4) {
    int pt = e / KNN;
    int j = ((pt >> 12) << 12) + (idx[e] & (NN - 1));
    float v = A[(size_t)j * 64 + c] + Bm[(size_t)pt * 64 + c];
    s += (double)v;
    q += (double)v * (double)v;
  }
  rs[g4][c] = s; rq[g4][c] = q;
  __syncthreads();
  if (t < 64) {
    double ss = rs[0][t] + rs[1][t] + rs[2][t] + rs[3][t];
    double qq = rq[0][t] + rq[1][t] + rq[2][t] + rq[3][t];
    atomicAdd(&st[t], ss);
    atomicAdd(&st[1024 + t], qq);
  }
}

// ==== h4 stats: h3 = lrelu(BN3(A[j]+B[i])) per tile -> K=64 GEMM col-stats of h4 ====
__global__ __launch_bounds__(256) void ebstats_k(const float* __restrict__ A,
    const float* __restrict__ Bm, const int* __restrict__ idx,
    const float* __restrict__ sc3, const float* __restrict__ sh3,
    const float* __restrict__ W4, double* __restrict__ st) {
  __shared__ float H3[64][68];
  __shared__ float W4s[64][68];
  __shared__ double rPd[16][68];
  const int t = threadIdx.x;
  const int tx = t & 15, ty = t >> 4;
  const int c = t & 63, g4 = t >> 6;
  for (int l = t; l < 4096; l += 256) W4s[l & 63][l >> 6] = W4[l];
  const float s3 = sc3[c], b3 = sh3[c];
  double sL[4], qL[4];
#pragma unroll
  for (int j = 0; j < 4; ++j) { sL[j] = 0.0; qL[j] = 0.0; }
  for (int tile = 0; tile < 16; ++tile) {
    const int e0 = (blockIdx.x * 16 + tile) * 64;
    __syncthreads();   // guard H3 reuse (and W4s on first tile)
    for (int es = g4; es < 64; es += 4) {
      int e = e0 + es;
      int pt = e / KNN;
      int j = ((pt >> 12) << 12) + (idx[e] & (NN - 1));
      float v = A[(size_t)j * 64 + c] + Bm[(size_t)pt * 64 + c];
      H3[c][es] = lrelu(fmaf(s3, v, b3));
    }
    __syncthreads();
    float acc2[4][4];
#pragma unroll
    for (int i = 0; i < 4; ++i)
#pragma unroll
      for (int j = 0; j < 4; ++j) acc2[i][j] = 0.f;
    for (int k = 0; k < 64; ++k) {
      float4 a4 = *(const float4*)&H3[k][ty * 4];
      float4 b4 = *(const float4*)&W4s[k][tx * 4];
      const float* aa = (const float*)&a4;
      const float* bb = (const float*)&b4;
#pragma unroll
      for (int i = 0; i < 4; ++i)
#pragma unroll
        for (int j = 0; j < 4; ++j) acc2[i][j] = fmaf(aa[i], bb[j], acc2[i][j]);
    }
#pragma unroll
    for (int j = 0; j < 4; ++j) {
      sL[j] += (double)acc2[0][j] + (double)acc2[1][j] + (double)acc2[2][j] + (double)acc2[3][j];
      qL[j] += (double)acc2[0][j] * (double)acc2[0][j] + (double)acc2[1][j] * (double)acc2[1][j]
             + (double)acc2[2][j] * (double)acc2[2][j] + (double)acc2[3][j] * (double)acc2[3][j];
    }
  }
  __syncthreads();
#pragma unroll
  for (int j = 0; j < 4; ++j) rPd[ty][tx * 4 + j] = sL[j];
  __syncthreads();
  if (t < 64) {
    double s = 0.0;
#pragma unroll
    for (int w = 0; w < 16; ++w) s += rPd[w][t];
    atomicAdd(&st[t], s);
  }
  __syncthreads();
#pragma unroll
  for (int j = 0; j < 4; ++j) rPd[ty][tx * 4 + j] = qL[j];
  __syncthreads();
  if (t < 64) {
    double s = 0.0;
#pragma unroll
    for (int w = 0; w < 16; ++w) s += rPd[w][t];
    atomicAdd(&st[1024 + t], s);
  }
}

// ==== stage-2 final: h3 = lrelu(BN3(A[j]+B[i])); h4 K=64 float4; max -> x2 ====
__global__ __launch_bounds__(256) void e2c_k(const float* __restrict__ A,
    const float* __restrict__ Bm, const int* __restrict__ idx,
    const float* __restrict__ sc3, const float* __restrict__ sh3,
    const float* __restrict__ W4, const float* __restrict__ sc4, const float* __restrict__ sh4,
    float* __restrict__ x2out) {
  __shared__ float h3s[40][68];   // [edge][ch], stride 68 (16B-aligned rows)
  __shared__ float pmax[2][2][64];
  const int t = threadIdx.x;
  const int p0 = blockIdx.x * 2;
  const int c = t & 63;
  const int g4 = t >> 6;
  const float s3 = sc3[c], b3 = sh3[c];
  for (int es = g4; es < 40; es += 4) {
    int eg = p0 * KNN + es;
    int pt = p0 + es / KNN;
    int jr = ((pt >> 12) << 12) + (idx[eg] & (NN - 1));
    float v = A[(size_t)jr * 64 + c] + Bm[(size_t)pt * 64 + c];
    h3s[es][c] = lrelu(fmaf(s3, v, b3));
  }
  __syncthreads();
  const int point = g4 & 1, khalf = g4 >> 1;
  const float s4 = sc4[c], b4 = sh4[c];
  float acc[10];
#pragma unroll
  for (int k = 0; k < 10; ++k) acc[k] = 0.f;
  for (int d0 = 0; d0 < 64; d0 += 4) {
    float4 wv = *(const float4*)&W4[c * 64 + d0];
#pragma unroll
    for (int k = 0; k < 10; ++k) {
      float4 hv = *(const float4*)&h3s[point * 20 + khalf * 10 + k][d0];
      acc[k] = fmaf(hv.x, wv.x, acc[k]);
      acc[k] = fmaf(hv.y, wv.y, acc[k]);
      acc[k] = fmaf(hv.z, wv.z, acc[k]);
      acc[k] = fmaf(hv.w, wv.w, acc[k]);
    }
  }
  float m = -3.4e38f;
#pragma unroll
  for (int k = 0; k < 10; ++k) {
    float v = lrelu(fmaf(s4, acc[k], b4));
    m = fmaxf(m, v);
  }
  pmax[khalf][point][c] = m;
  __syncthreads();
  if (t < 128) {
    int pp = t >> 6, cc = t & 63;
    x2out[(p0 + pp) * 64 + cc] = fmaxf(pmax[0][pp][cc], pmax[1][pp][cc]);
  }
}

// ==== stage-3 final: x3 = max_k lrelu(BN5(A5[j]+B5[i])) — no K-loop ====
__global__ __launch_bounds__(256) void e3c_k(const float* __restrict__ A,
    const float* __restrict__ Bm, const int* __restrict__ idx,
    const float* __restrict__ sc5, const float* __restrict__ sh5,
    float* __restrict__ x3out) {
  const int t = threadIdx.x;
  const int p0 = blockIdx.x * 4;
  const int c = t & 63, g4 = t >> 6;
  const int pt = p0 + g4;
  const float s5 = sc5[c], b5 = sh5[c];
  const float bb = Bm[(size_t)pt * 64 + c];
  const int* ip = idx + (size_t)pt * KNN;
  const int bbase = (pt >> 12) << 12;
  float m = -3.4e38f;
#pragma unroll 4
  for (int k = 0; k < KNN; ++k) {
    int jr = bbase + (ip[k] & (NN - 1));
    float v = A[(size_t)jr * 64 + c] + bb;
    m = fmaxf(m, lrelu(fmaf(s5, v, b5)));
  }
  x3out[(size_t)pt * 64 + c] = m;
}

// ==== fused h6 stats + per-column max/min of pre-BN h6 ====
__global__ __launch_bounds__(256) void g6stats_k(
    const float* __restrict__ x1p, const float* __restrict__ x2p,
    const float* __restrict__ x3p, const float* __restrict__ W6,
    double* __restrict__ st, float* __restrict__ gpmax, float* __restrict__ gpmin) {
  __shared__ float As[16][68];
  __shared__ float Ws[16][68];
  __shared__ float rP[16][64];
  const int t = threadIdx.x;
  const int m0 = blockIdx.x * 64, n0 = blockIdx.y * 64;
  const int tx = t & 15, ty = t >> 4;
  const int lm = t >> 2, lk = (t & 3) * 4;
  const int m = m0 + lm, wn = n0 + lm;
  float acc[4][4];
#pragma unroll
  for (int i = 0; i < 4; ++i)
#pragma unroll
    for (int j = 0; j < 4; ++j) acc[i][j] = 0.f;
  for (int k0 = 0; k0 < 192; k0 += 16) {
    const int c = k0 + lk;
    const float* src = (c < 64)  ? &x1p[(size_t)m * 64 + c]
                     : (c < 128) ? &x2p[(size_t)m * 64 + (c - 64)]
                                 : &x3p[(size_t)m * 64 + (c - 128)];
    float4 av = *(const float4*)src;
    As[lk + 0][lm] = av.x; As[lk + 1][lm] = av.y;
    As[lk + 2][lm] = av.z; As[lk + 3][lm] = av.w;
    float4 wv = *(const float4*)&W6[(size_t)wn * 192 + c];
    Ws[lk + 0][lm] = wv.x; Ws[lk + 1][lm] = wv.y;
    Ws[lk + 2][lm] = wv.z; Ws[lk + 3][lm] = wv.w;
    __syncthreads();
#pragma unroll
    for (int kk = 0; kk < 16; ++kk) {
      float4 a4 = *(const float4*)&As[kk][ty * 4];
      float4 b4 = *(const float4*)&Ws[kk][tx * 4];
      const float* aa = (const float*)&a4;
      const float* bb = (const float*)&b4;
#pragma unroll
      for (int i = 0; i < 4; ++i)
#pragma unroll
        for (int j = 0; j < 4; ++j)
          acc[i][j] = fmaf(aa[i], bb[j], acc[i][j]);
    }
    __syncthreads();
  }
#pragma unroll
  for (int j = 0; j < 4; ++j)
    rP[ty][tx * 4 + j] = acc[0][j] + acc[1][j] + acc[2][j] + acc[3][j];
  __syncthreads();
  if (t < 64) {
    float ssum = 0.f;
#pragma unroll
    for (int w = 0; w < 16; ++w) ssum += rP[w][t];
    atomicAdd(&st[n0 + t], (double)ssum);
  }
  __syncthreads();
#pragma unroll
  for (int j = 0; j < 4; ++j)
    rP[ty][tx * 4 + j] = acc[0][j] * acc[0][j] + acc[1][j] * acc[1][j]
                       + acc[2][j] * acc[2][j] + acc[3][j] * acc[3][j];
  __syncthreads();
  if (t < 64) {
    float qsum = 0.f;
#pragma unroll
    for (int w = 0; w < 16; ++w) qsum += rP[w][t];
    atomicAdd(&st[1024 + n0 + t], (double)qsum);
  }
  __syncthreads();
#pragma unroll
  for (int j = 0; j < 4; ++j)
    rP[ty][tx * 4 + j] = fmaxf(fmaxf(acc[0][j], acc[1][j]), fmaxf(acc[2][j], acc[3][j]));
  __syncthreads();
  if (t < 64) {
    float mx = -3.4e38f;
#pragma unroll
    for (int w = 0; w < 16; ++w) mx = fmaxf(mx, rP[w][t]);
    gpmax[(size_t)blockIdx.x * 1024 + n0 + t] = mx;
  }
  __syncthreads();
#pragma unroll
  for (int j = 0; j < 4; ++j)
    rP[ty][tx * 4 + j] = fminf(fminf(acc[0][j], acc[1][j]), fminf(acc[2][j], acc[3][j]));
  __syncthreads();
  if (t < 64) {
    float mn = 3.4e38f;
#pragma unroll
    for (int w = 0; w < 16; ++w) mn = fminf(mn, rP[w][t]);
    gpmin[(size_t)blockIdx.x * 1024 + n0 + t] = mn;
  }
}

__global__ void gmax_red2_k(const float* __restrict__ gpmax, const float* __restrict__ gpmin,
                            const float* __restrict__ sc6, const float* __restrict__ sh6,
                            float* __restrict__ gm) {
  const int b = blockIdx.x;
  const int c = blockIdx.y * 256 + threadIdx.x;
  float mx = -3.4e38f, mn = 3.4e38f;
  for (int rb = 0; rb < 64; ++rb) {
    mx = fmaxf(mx, gpmax[(size_t)(b * 64 + rb) * 1024 + c]);
    mn = fminf(mn, gpmin[(size_t)(b * 64 + rb) * 1024 + c]);
  }
  float s6 = sc6[c], b6 = sh6[c];
  float h = (s6 >= 0.f) ? mx : mn;
  gm[b * 1024 + c] = lrelu(s6 * h + b6);
}

__global__ void wpack_k(const float* __restrict__ W7, float* __restrict__ W7r) {
  int i = blockIdx.x * 256 + threadIdx.x;
  if (i < 512 * 192) {
    int n = i / 192, c = i - n * 192;
    W7r[i] = W7[(size_t)n * 1216 + 1024 + c];
  }
}

__global__ __launch_bounds__(256) void gw_k(const float* __restrict__ gm,
                                            const float* __restrict__ W7,
                                            float* __restrict__ gW) {
  int idx = blockIdx.x * 256 + threadIdx.x;
  int b = idx >> 9, n = idx & 511;
  const float* g = gm + b * 1024;
  const float* w = W7 + (size_t)n * 1216;
  float s0 = 0.f, s1 = 0.f, s2 = 0.f, s3 = 0.f;
  for (int c = 0; c < 1024; c += 4) {
    float4 gv = *(const float4*)&g[c];
    float4 wv = *(const float4*)&w[c];
    s0 = fmaf(gv.x, wv.x, s0); s1 = fmaf(gv.y, wv.y, s1);
    s2 = fmaf(gv.z, wv.z, s2); s3 = fmaf(gv.w, wv.w, s3);
  }
  gW[idx] = (s0 + s1) + (s2 + s3);
}

// ==== h7 = gW + x123 . W7r^T : K=192 GEMM, stats + store ====
template <int H7F32>
__global__ __launch_bounds__(256) void g7stats_k(
    const float* __restrict__ x1p, const float* __restrict__ x2p,
    const float* __restrict__ x3p, const float* __restrict__ W7r,
    const float* __restrict__ gW, void* __restrict__ Hout, double* __restrict__ st) {
  __shared__ float As[16][68];
  __shared__ float Ws[16][68];
  __shared__ float rP[16][64];
  const int t = threadIdx.x;
  const int m0 = blockIdx.x * 64, n0 = blockIdx.y * 64;
  const int tx = t & 15, ty = t >> 4;
  const int lm = t >> 2, lk = (t & 3) * 4;
  const int m = m0 + lm, wn = n0 + lm;
  const int b = m0 >> 12;
  float acc[4][4];
#pragma unroll
  for (int j = 0; j < 4; ++j) {
    float g0 = gW[b * 512 + n0 + tx * 4 + j];
#pragma unroll
    for (int i = 0; i < 4; ++i) acc[i][j] = g0;
  }
  for (int k0 = 0; k0 < 192; k0 += 16) {
    const int c = k0 + lk;
    const float* src = (c < 64)  ? &x1p[(size_t)m * 64 + c]
                     : (c < 128) ? &x2p[(size_t)m * 64 + (c - 64)]
                                 : &x3p[(size_t)m * 64 + (c - 128)];
    float4 av = *(const float4*)src;
    As[lk + 0][lm] = av.x; As[lk + 1][lm] = av.y;
    As[lk + 2][lm] = av.z; As[lk + 3][lm] = av.w;
    float4 wv = *(const float4*)&W7r[(size_t)wn * 192 + c];
    Ws[lk + 0][lm] = wv.x; Ws[lk + 1][lm] = wv.y;
    Ws[lk + 2][lm] = wv.z; Ws[lk + 3][lm] = wv.w;
    __syncthreads();
#pragma unroll
    for (int kk = 0; kk < 16; ++kk) {
      float4 a4 = *(const float4*)&As[kk][ty * 4];
      float4 b4 = *(const float4*)&Ws[kk][tx * 4];
      const float* aa = (const float*)&a4;
      const float* bb = (const float*)&b4;
#pragma unroll
      for (int i = 0; i < 4; ++i)
#pragma unroll
        for (int j = 0; j < 4; ++j)
          acc[i][j] = fmaf(aa[i], bb[j], acc[i][j]);
    }
    __syncthreads();
  }
#pragma unroll
  for (int j = 0; j < 4; ++j)
    rP[ty][tx * 4 + j] = acc[0][j] + acc[1][j] + acc[2][j] + acc[3][j];
  __syncthreads();
  if (t < 64) {
    float ssum = 0.f;
#pragma unroll
    for (int w = 0; w < 16; ++w) ssum += rP[w][t];
    atomicAdd(&st[n0 + t], (double)ssum);
  }
  __syncthreads();
#pragma unroll
  for (int j = 0; j < 4; ++j)
    rP[ty][tx * 4 + j] = acc[0][j] * acc[0][j] + acc[1][j] * acc[1][j]
                       + acc[2][j] * acc[2][j] + acc[3][j] * acc[3][j];
  __syncthreads();
  if (t < 64) {
    float qsum = 0.f;
#pragma unroll
    for (int w = 0; w < 16; ++w) qsum += rP[w][t];
    atomicAdd(&st[1024 + n0 + t], (double)qsum);
  }
#pragma unroll
  for (int i = 0; i < 4; ++i) {
    int r = m0 + ty * 4 + i;
#pragma unroll
    for (int j = 0; j < 4; ++j) {
      if (H7F32)
        ((float*)Hout)[(size_t)r * 512 + n0 + tx * 4 + j] = acc[i][j];
      else
        ((u16*)Hout)[(size_t)r * 512 + n0 + tx * 4 + j] = f2bf_rne(acc[i][j]);
    }
  }
}

// =================== tile GEMM + fused BN-stats (h7 -> h8 stats; AMODE 4 path) ===================
template <int AMODE, int STORE, int H7F32>
__global__ __launch_bounds__(256) void gstats_k(
    const void* __restrict__ Ain, const float* __restrict__ Wp, const int K, const int Nout,
    const float* __restrict__ x1p, const float* __restrict__ x2p,
    const float* __restrict__ x3p, const float* __restrict__ gmp,
    const float* __restrict__ scA, const float* __restrict__ shA,
    void* __restrict__ Hout, double* __restrict__ st) {
  __shared__ float As[16][68];
  __shared__ float Ws[16][68];
  __shared__ float rP[16][64];
  const int t = threadIdx.x;
  const int m0 = blockIdx.x * 64, n0 = blockIdx.y * 64;
  const int tx = t & 15, ty = t >> 4;
  const int lm = t >> 2, lk = (t & 3) * 4;
  const int m = m0 + lm, wn = n0 + lm;
  float acc[4][4];
#pragma unroll
  for (int i = 0; i < 4; ++i)
#pragma unroll
    for (int j = 0; j < 4; ++j) acc[i][j] = 0.f;

  for (int k0 = 0; k0 < K; k0 += 16) {
    const int c = k0 + lk;
    float4 av;
    if (AMODE == 2) {
      const float* src = (c < 64)  ? &x1p[(size_t)m * 64 + c]
                       : (c < 128) ? &x2p[(size_t)m * 64 + (c - 64)]
                                   : &x3p[(size_t)m * 64 + (c - 128)];
      av = *(const float4*)src;
    } else if (AMODE == 3) {
      if (c < 1024) {
        av = *(const float4*)&gmp[(size_t)(m >> 12) * 1024 + c];
      } else {
        int cc = c - 1024;
        const float* src = (cc < 64)  ? &x1p[(size_t)m * 64 + cc]
                         : (cc < 128) ? &x2p[(size_t)m * 64 + (cc - 64)]
                                      : &x3p[(size_t)m * 64 + (cc - 128)];
        av = *(const float4*)src;
      }
    } else {
      if (H7F32) {
        av = *(const float4*)&((const float*)Ain)[(size_t)m * K + c];
      } else {
        ushort4 u4 = *(const ushort4*)&((const u16*)Ain)[(size_t)m * K + c];
        av = make_float4(bf2f(u4.x), bf2f(u4.y), bf2f(u4.z), bf2f(u4.w));
      }
      av.x = lrelu(scA[c + 0] * av.x + shA[c + 0]);
      av.y = lrelu(scA[c + 1] * av.y + shA[c + 1]);
      av.z = lrelu(scA[c + 2] * av.z + shA[c + 2]);
      av.w = lrelu(scA[c + 3] * av.w + shA[c + 3]);
    }
    As[lk + 0][lm] = av.x; As[lk + 1][lm] = av.y;
    As[lk + 2][lm] = av.z; As[lk + 3][lm] = av.w;
    float4 wv = *(const float4*)&Wp[(size_t)wn * K + c];
    Ws[lk + 0][lm] = wv.x; Ws[lk + 1][lm] = wv.y;
    Ws[lk + 2][lm] = wv.z; Ws[lk + 3][lm] = wv.w;
    __syncthreads();
#pragma unroll
    for (int kk = 0; kk < 16; ++kk) {
      float4 a4 = *(const float4*)&As[kk][ty * 4];
      float4 b4 = *(const float4*)&Ws[kk][tx * 4];
      const float* aa = (const float*)&a4;
      const float* bb = (const float*)&b4;
#pragma unroll
      for (int i = 0; i < 4; ++i)
#pragma unroll
        for (int j = 0; j < 4; ++j)
          acc[i][j] = fmaf(aa[i], bb[j], acc[i][j]);
    }
    __syncthreads();
  }
#pragma unroll
  for (int j = 0; j < 4; ++j)
    rP[ty][tx * 4 + j] = acc[0][j] + acc[1][j] + acc[2][j] + acc[3][j];
  __syncthreads();
  if (t < 64) {
    float ssum = 0.f;
#pragma unroll
    for (int w = 0; w < 16; ++w) ssum += rP[w][t];
    atomicAdd(&st[n0 + t], (double)ssum);
  }
  __syncthreads();
#pragma unroll
  for (int j = 0; j < 4; ++j)
    rP[ty][tx * 4 + j] = acc[0][j] * acc[0][j] + acc[1][j] * acc[1][j]
                       + acc[2][j] * acc[2][j] + acc[3][j] * acc[3][j];
  __syncthreads();
  if (t < 64) {
    float qsum = 0.f;
#pragma unroll
    for (int w = 0; w < 16; ++w) qsum += rP[w][t];
    atomicAdd(&st[1024 + n0 + t], (double)qsum);
  }
  if (STORE) {
#pragma unroll
    for (int i = 0; i < 4; ++i) {
      int r = m0 + ty * 4 + i;
#pragma unroll
      for (int j = 0; j < 4; ++j) {
        if (H7F32)
          ((float*)Hout)[(size_t)r * Nout + n0 + tx * 4 + j] = acc[i][j];
        else
          ((u16*)Hout)[(size_t)r * Nout + n0 + tx * 4 + j] = f2bf_rne(acc[i][j]);
      }
    }
  }
}

// =================== final: h7'->h8 -> BN -> xW9^T -> out (rP padded: 585) ===================
template <int H7F32>
__global__ __launch_bounds__(256) void final_k(
    const void* __restrict__ h7, const float* __restrict__ sc7, const float* __restrict__ sh7,
    const float* __restrict__ W8, const float* __restrict__ sc8, const float* __restrict__ sh8,
    const float* __restrict__ W9, void* __restrict__ outp_raw,
    const int* __restrict__ flag) {
  __shared__ float As[16][68];
  __shared__ float Ws[16][68];
  __shared__ float w9s[9][256];
  __shared__ float rP[16][585];
  const int t = threadIdx.x;
  const int m0 = blockIdx.x * 64;
  const int tx = t & 15, ty = t >> 4;
  const int lm = t >> 2, lk = (t & 3) * 4;
  for (int l = t; l < 2304; l += 256) w9s[l >> 8][l & 255] = W9[l];
  float outp[4][9];
#pragma unroll
  for (int i = 0; i < 4; ++i)
#pragma unroll
    for (int o = 0; o < 9; ++o) outp[i][o] = 0.f;
  for (int nt = 0; nt < 4; ++nt) {
    const int n0 = nt * 64;
    float acc[4][4];
#pragma unroll
    for (int i = 0; i < 4; ++i)
#pragma unroll
      for (int j = 0; j < 4; ++j) acc[i][j] = 0.f;
    for (int k0 = 0; k0 < 512; k0 += 16) {
      const int c = k0 + lk;
      float4 hv;
      if (H7F32) {
        hv = *(const float4*)&((const float*)h7)[(size_t)(m0 + lm) * 512 + c];
      } else {
        ushort4 u4 = *(const ushort4*)&((const u16*)h7)[(size_t)(m0 + lm) * 512 + c];
        hv = make_float4(bf2f(u4.x), bf2f(u4.y), bf2f(u4.z), bf2f(u4.w));
      }
      As[lk + 0][lm] = lrelu(sc7[c + 0] * hv.x + sh7[c + 0]);
      As[lk + 1][lm] = lrelu(sc7[c + 1] * hv.y + sh7[c + 1]);
      As[lk + 2][lm] = lrelu(sc7[c + 2] * hv.z + sh7[c + 2]);
      As[lk + 3][lm] = lrelu(sc7[c + 3] * hv.w + sh7[c + 3]);
      float4 wv = *(const float4*)&W8[(size_t)(n0 + lm) * 512 + c];
      Ws[lk + 0][lm] = wv.x; Ws[lk + 1][lm] = wv.y;
      Ws[lk + 2][lm] = wv.z; Ws[lk + 3][lm] = wv.w;
      __syncthreads();
#pragma unroll
      for (int kk = 0; kk < 16; ++kk) {
        float4 a4 = *(const float4*)&As[kk][ty * 4];
        float4 b4 = *(const float4*)&Ws[kk][tx * 4];
        const float* aa = (const float*)&a4;
        const float* bb = (const float*)&b4;
#pragma unroll
        for (int i = 0; i < 4; ++i)
#pragma unroll
          for (int j = 0; j < 4; ++j)
            acc[i][j] = fmaf(aa[i], bb[j], acc[i][j]);
      }
      __syncthreads();
    }
#pragma unroll
    for (int j = 0; j < 4; ++j) {
      int c = n0 + tx * 4 + j;
      float s8 = sc8[c], b8 = sh8[c];
#pragma unroll
      for (int i = 0; i < 4; ++i) {
        float v = lrelu(s8 * acc[i][j] + b8);
#pragma unroll
        for (int o = 0; o < 9; ++o) outp[i][o] += v * w9s[o][c];
      }
    }
  }
#pragma unroll
  for (int i = 0; i < 4; ++i)
#pragma unroll
    for (int o = 0; o < 9; ++o) rP[tx][(ty * 4 + i) * 9 + o] = outp[i][o];
  __syncthreads();
  const int mode = flag[0];
  for (int l = t; l < 576; l += 256) {
    float sum = 0.f;
#pragma unroll
    for (int w = 0; w < 16; ++w) sum += rP[w][l];
    if (mode) {
      ((__hip_bfloat16*)outp_raw)[(size_t)m0 * 9 + l] = __float2bfloat16(sum);
    } else {
      ((float*)outp_raw)[(size_t)m0 * 9 + l] = sum;
    }
  }
}

// =================== host ===================
extern "C" void kernel_launch(void* const* d_in, const int* in_sizes, int n_in,
                              void* d_out, int out_size, void* d_ws, size_t ws_size,
                              hipStream_t stream) {
  (void)in_sizes; (void)out_size;
  if (n_in < 27) return;

  char* p = (char*)d_ws;
  size_t used = 0;
  auto alloc = [&](size_t bytes) {
    char* r = p;
    size_t rb = (bytes + 255) & ~(size_t)255;
    p += rb; used += rb;
    return r;
  };
  int* flag    = (int*)alloc(256);
  float* xF    = (float*)alloc((size_t)98304 * 4);
  float* W1f   = (float*)alloc((size_t)384 * 4);
  float* W2f   = (float*)alloc((size_t)4096 * 4);
  float* W3f   = (float*)alloc((size_t)8192 * 4);
  float* W4f   = (float*)alloc((size_t)4096 * 4);
  float* W5f   = (float*)alloc((size_t)8192 * 4);
  float* W6f   = (float*)alloc((size_t)196608 * 4);
  float* W7f   = (float*)alloc((size_t)622592 * 4);
  float* W8f   = (float*)alloc((size_t)131072 * 4);
  float* W9f   = (float*)alloc((size_t)2304 * 4);
  float* gF    = (float*)alloc((size_t)2112 * 4);
  float* bF    = (float*)alloc((size_t)2112 * 4);
  int* idxb    = (int*)alloc((size_t)NEDGE * 4);
  double* xx   = (double*)alloc((size_t)NPTS * 8);
  float* xxfb  = (float*)alloc((size_t)NPTS * 4);
  u16* Xhi     = (u16*)alloc((size_t)NPTS * 64 * 2);
  u16* Xlo     = (u16*)alloc((size_t)NPTS * 64 * 2);
  float* x1    = (float*)alloc((size_t)NPTS * 64 * 4);
  float* x2    = (float*)alloc((size_t)NPTS * 64 * 4);
  float* x3    = (float*)alloc((size_t)NPTS * 64 * 4);
  float* Ab    = (float*)alloc((size_t)NPTS * 64 * 4);   // A = x·W[:, :64]^T
  float* Bb    = (float*)alloc((size_t)NPTS * 64 * 4);   // B = x·(W[:,64:]-W[:, :64])^T
  float* Wd    = (float*)alloc((size_t)4096 * 4);        // 64x64 diff weights
  float* gm    = (float*)alloc((size_t)BB * 1024 * 4);
  float* gpmax = (float*)alloc((size_t)512 * 1024 * 4);
  float* gpmin = (float*)alloc((size_t)512 * 1024 * 4);
  float* gW    = (float*)alloc((size_t)4096 * 4);
  float* W7r   = (float*)alloc((size_t)98304 * 4);
  double* st   = (double*)alloc((size_t)2048 * 8);
  double* stm  = (double*)alloc((size_t)32 * 8);
  float* scb   = (float*)alloc((size_t)8 * 1024 * 4);
  float* shb   = (float*)alloc((size_t)8 * 1024 * 4);
  const int h7f32 = (ws_size >= used + (size_t)NPTS * 512 * 4 + 256) ? 1 : 0;
  void* h7 = alloc((size_t)NPTS * 512 * (h7f32 ? 4 : 2));
  if (ws_size < used) return;
  // kNN scratch overlays h7 (consumed before h7's real use):
  //   pkey : 4 segs x NPTS x 20 u64 = 21.0 MB (3-D knn partials)
  //   pcand: NPTS x 48 u64 = 12.6 MB          (screen candidates)
  u64* pkey  = (u64*)h7;
  u64* pcand = (u64*)h7;

  // ---- canonicalize all inputs to f32 ----
  det_k<<<1, 1, 0, stream>>>(d_in[11], flag);
  auto conv = [&](const void* src, float* dst, int n) {
    conv_k<<<(n + 255) / 256, 256, 0, stream>>>(src, dst, n, flag);
  };
  conv(d_in[0], xF, 98304);
  conv(d_in[2], W1f, 384);    conv(d_in[3], W2f, 4096);
  conv(d_in[4], W3f, 8192);   conv(d_in[5], W4f, 4096);
  conv(d_in[6], W5f, 8192);   conv(d_in[7], W6f, 196608);
  conv(d_in[8], W7f, 622592); conv(d_in[9], W8f, 131072);
  conv(d_in[10], W9f, 2304);
  const int gsz[8] = {64, 64, 64, 64, 64, 1024, 512, 256};
  int goff[8]; int acc_ = 0;
  for (int i = 0; i < 8; ++i) { goff[i] = acc_; acc_ += gsz[i]; }
  for (int i = 0; i < 8; ++i) {
    conv(d_in[11 + 2 * i], gF + goff[i], gsz[i]);
    conv(d_in[12 + 2 * i], bF + goff[i], gsz[i]);
  }
  wpack_k<<<384, 256, 0, stream>>>(W7f, W7r);
  auto SC = [&](int l) { return scb + (size_t)(l - 1) * 1024; };
  auto SH = [&](int l) { return shb + (size_t)(l - 1) * 1024; };
  auto G  = [&](int l) { return gF + goff[l - 1]; };
  auto Bt = [&](int l) { return bF + goff[l - 1]; };

  // ---- stage 1 ----
  knn1p_k<<<dim3(BB, 16, 4), 256, 0, stream>>>(xF, pkey);
  tmerge_k<<<NPTS / 256, 256, 0, stream>>>(pkey, idxb);
  zero_k<<<1, 256, 0, stream>>>(stm, 32);
  f1mom_k<<<320, 256, 0, stream>>>(xF, idxb, stm);
  fin1_k<<<1, 64, 0, stream>>>(stm, W1f, G(1), Bt(1), SC(1), SH(1), 1.0 / NEDGE);
  zero_k<<<8, 256, 0, stream>>>(st, 2048);
  e1b_k<<<NEDGE / 1024, 256, 0, stream>>>(xF, idxb, W1f, SC(1), SH(1), W2f, st);
  fin_k<<<1, 256, 0, stream>>>(st, G(2), Bt(2), SC(2), SH(2), 64, 1.0 / NEDGE);
  e1c_k<<<NPTS / 4, 256, 0, stream>>>(xF, idxb, W1f, SC(1), SH(1), W2f, SC(2), SH(2), x1);

  // ---- knn on x1: barrier-free MFMA split-bf16 screen + exact f64 rescore ----
  xx_k<<<NPTS, 64, 0, stream>>>(x1, xx, xxfb);
  xsplit_k<<<NPTS * 64 / 256, 256, 0, stream>>>(x1, Xhi, Xlo);
  knnsm_k<<<dim3(NN / 16, BB), 256, 0, stream>>>(Xhi, Xlo, xxfb, pcand);
  resc_k<<<NPTS / 4, 256, 0, stream>>>(x1, xx, pcand, idxb);

  // ---- stage 2 (edge-conv decomposition: h3 = A[j] + B[i]) ----
  wd_k<<<16, 256, 0, stream>>>(W3f, Wd);
  pgemm_k<<<NPTS / 64, 256, 0, stream>>>(x1, W3f, 128, Ab);
  pgemm_k<<<NPTS / 64, 256, 0, stream>>>(x1, Wd, 64, Bb);
  zero_k<<<8, 256, 0, stream>>>(st, 2048);
  eastats_k<<<NEDGE / 2048, 256, 0, stream>>>(Ab, Bb, idxb, st);
  fin_k<<<1, 256, 0, stream>>>(st, G(3), Bt(3), SC(3), SH(3), 64, 1.0 / NEDGE);
  zero_k<<<8, 256, 0, stream>>>(st, 2048);
  ebstats_k<<<NEDGE / 1024, 256, 0, stream>>>(Ab, Bb, idxb, SC(3), SH(3), W4f, st);
  fin_k<<<1, 256, 0, stream>>>(st, G(4), Bt(4), SC(4), SH(4), 64, 1.0 / NEDGE);
  e2c_k<<<NPTS / 2, 256, 0, stream>>>(Ab, Bb, idxb, SC(3), SH(3), W4f, SC(4), SH(4), x2);

  // ---- knn on x2: barrier-free MFMA split-bf16 screen + exact f64 rescore ----
  xx_k<<<NPTS, 64, 0, stream>>>(x2, xx, xxfb);
  xsplit_k<<<NPTS * 64 / 256, 256, 0, stream>>>(x2, Xhi, Xlo);
  knnsm_k<<<dim3(NN / 16, BB), 256, 0, stream>>>(Xhi, Xlo, xxfb, pcand);
  resc_k<<<NPTS / 4, 256, 0, stream>>>(x2, xx, pcand, idxb);

  // ---- stage 3 (decomposed: h5 = A5[j] + B5[i], no K-loop in e3c) ----
  wd_k<<<16, 256, 0, stream>>>(W5f, Wd);
  pgemm_k<<<NPTS / 64, 256, 0, stream>>>(x2, W5f, 128, Ab);
  pgemm_k<<<NPTS / 64, 256, 0, stream>>>(x2, Wd, 64, Bb);
  zero_k<<<8, 256, 0, stream>>>(st, 2048);
  eastats_k<<<NEDGE / 2048, 256, 0, stream>>>(Ab, Bb, idxb, st);
  fin_k<<<1, 256, 0, stream>>>(st, G(5), Bt(5), SC(5), SH(5), 64, 1.0 / NEDGE);
  e3c_k<<<NPTS / 4, 256, 0, stream>>>(Ab, Bb, idxb, SC(5), SH(5), x3);

  // ---- point pipeline ----
  zero_k<<<8, 256, 0, stream>>>(st, 2048);
  g6stats_k<<<dim3(NPTS / 64, 16), 256, 0, stream>>>(x1, x2, x3, W6f, st, gpmax, gpmin);
  fin_k<<<4, 256, 0, stream>>>(st, G(6), Bt(6), SC(6), SH(6), 1024, 1.0 / NPTS);
  gmax_red2_k<<<dim3(BB, 4), 256, 0, stream>>>(gpmax, gpmin, SC(6), SH(6), gm);

  gw_k<<<16, 256, 0, stream>>>(gm, W7f, gW);
  zero_k<<<8, 256, 0, stream>>>(st, 2048);
  if (h7f32) {
    g7stats_k<1><<<dim3(NPTS / 64, 8), 256, 0, stream>>>(x1, x2, x3, W7r, gW, h7, st);
  } else {
    g7stats_k<0><<<dim3(NPTS / 64, 8), 256, 0, stream>>>(x1, x2, x3, W7r, gW, h7, st);
  }
  fin_k<<<2, 256, 0, stream>>>(st, G(7), Bt(7), SC(7), SH(7), 512, 1.0 / NPTS);

  zero_k<<<8, 256, 0, stream>>>(st, 2048);
  if (h7f32) {
    gstats_k<4, 0, 1><<<dim3(NPTS / 64, 4), 256, 0, stream>>>(
        h7, W8f, 512, 256, nullptr, nullptr, nullptr, nullptr, SC(7), SH(7), nullptr, st);
  } else {
    gstats_k<4, 0, 0><<<dim3(NPTS / 64, 4), 256, 0, stream>>>(
        h7, W8f, 512, 256, nullptr, nullptr, nullptr, nullptr, SC(7), SH(7), nullptr, st);
  }
  fin_k<<<1, 256, 0, stream>>>(st, G(8), Bt(8), SC(8), SH(8), 256, 1.0 / NPTS);

  if (h7f32) {
    final_k<1><<<NPTS / 64, 256, 0, stream>>>(h7, SC(7), SH(7), W8f, SC(8), SH(8), W9f,
                                              d_out, flag);
  } else {
    final_k<0><<<NPTS / 64, 256, 0, stream>>>(h7, SC(7), SH(7), W8f, SC(8), SH(8), W9f,
                                              d_out, flag);
  }
}